// Round 1
// baseline (2675.687 us; speedup 1.0000x reference)
//
#include <hip/hip_runtime.h>
#include <cstddef>
#include <cstdint>

#define T_U   12800   // user tokens B*S
#define T_I   1024    // item tokens B*Nc
#define CAP_U 25856   // 2*T_U + 4*64 slot capacity (64-aligned per expert)
#define CAP_I 2560    // 2*T_I + 8*64

__device__ __forceinline__ float gelu_f(float x) {
  return 0.5f * x * (1.0f + erff(x * 0.7071067811865476f));
}

#define FMA16(a, b, acc)                                                        \
  acc[0][0] += a.x * b.x; acc[0][1] += a.x * b.y; acc[0][2] += a.x * b.z; acc[0][3] += a.x * b.w; \
  acc[1][0] += a.y * b.x; acc[1][1] += a.y * b.y; acc[1][2] += a.y * b.z; acc[1][3] += a.y * b.w; \
  acc[2][0] += a.z * b.x; acc[2][1] += a.z * b.y; acc[2][2] += a.z * b.z; acc[2][3] += a.z * b.w; \
  acc[3][0] += a.w * b.x; acc[3][1] += a.w * b.y; acc[3][2] += a.w * b.z; acc[3][3] += a.w * b.w;

// ---------------- sentinel (ws too small) ----------------
__global__ void k_sentinel(float* out) { out[0] = 1.0e9f; }

// ---------------- embedding + (faithful) RoPE ----------------
__global__ __launch_bounds__(256) void k_embed_rope(
    const int* __restrict__ hist, const float* __restrict__ emb, float* __restrict__ X)
{
  int t = blockIdx.x;            // b*200 + s
  int s = t % 200;
  int d = threadIdx.x;           // 0..255
  const float* row = emb + (size_t)hist[t] * 256;
  float x0 = row[d];
  float x1 = row[(d + 1) & 255];           // roll(x,-1)
  int fi = d & 127;
  float inv = expf(-9.210340371976184f * ((float)fi * (1.0f / 128.0f)));
  float ang = (float)s * inv;
  X[(size_t)t * 256 + d] = x0 * cosf(ang) + x1 * sinf(ang);
}

// ---------------- item embedding sum ----------------
__global__ __launch_bounds__(256) void k_item_embed(
    const int* __restrict__ cand, const int* __restrict__ catid,
    const float* __restrict__ item_emb, const float* __restrict__ cat_emb,
    float* __restrict__ IE)
{
  int t = blockIdx.x, d = threadIdx.x;
  IE[(size_t)t * 256 + d] =
      item_emb[(size_t)cand[t] * 256 + d] + cat_emb[(size_t)catid[t] * 256 + d];
}

// ---------------- generic GEMM: C[M,N] = act(A[M,K] @ W[N,K]^T + bias) ----------------
__global__ __launch_bounds__(256) void k_gemm(
    const float* __restrict__ A, const float* __restrict__ Wm,
    const float* __restrict__ bias, float* __restrict__ C,
    int M, int N, int K, int act)
{
  __shared__ float As[16][68];
  __shared__ float Ws[16][68];
  int tid = threadIdx.x;
  int row0 = blockIdx.y << 6;
  int col0 = blockIdx.x << 6;
  int lr = tid >> 2, lk = (tid & 3) << 2;
  int tx = tid & 15, ty = tid >> 4;
  const float* Aload = A + (size_t)(row0 + lr) * K + lk;
  const float* Wload = Wm + (size_t)(col0 + lr) * K + lk;
  float acc[4][4] = {};
  for (int k0 = 0; k0 < K; k0 += 16) {
    float4 av = *(const float4*)(Aload + k0);
    float4 wv = *(const float4*)(Wload + k0);
    As[lk][lr] = av.x; As[lk + 1][lr] = av.y; As[lk + 2][lr] = av.z; As[lk + 3][lr] = av.w;
    Ws[lk][lr] = wv.x; Ws[lk + 1][lr] = wv.y; Ws[lk + 2][lr] = wv.z; Ws[lk + 3][lr] = wv.w;
    __syncthreads();
#pragma unroll
    for (int k = 0; k < 16; ++k) {
      float4 a = *(const float4*)&As[k][ty << 2];
      float4 b = *(const float4*)&Ws[k][tx << 2];
      FMA16(a, b, acc);
    }
    __syncthreads();
  }
#pragma unroll
  for (int i = 0; i < 4; ++i) {
    int r = row0 + (ty << 2) + i;
    int c0 = col0 + (tx << 2);
    float4 v;
    v.x = acc[i][0]; v.y = acc[i][1]; v.z = acc[i][2]; v.w = acc[i][3];
    if (bias) { v.x += bias[c0]; v.y += bias[c0 + 1]; v.z += bias[c0 + 2]; v.w += bias[c0 + 3]; }
    if (act) { v.x = gelu_f(v.x); v.y = gelu_f(v.y); v.z = gelu_f(v.z); v.w = gelu_f(v.w); }
    *(float4*)(C + (size_t)r * N + c0) = v;
  }
}

// ---------------- MoE GEMM1: H[slot,512] = gelu(Xg[slot,256] @ W1_e^T + b1_e) ----------------
__global__ __launch_bounds__(256) void k_moe_gemm1(
    const float* __restrict__ Xsrc, const int* __restrict__ tok,
    const int* __restrict__ offs, int E,
    const float* __restrict__ W1, const float* __restrict__ b1,
    float* __restrict__ H)
{
  const int N = 512, K = 256;
  int row0 = blockIdx.y << 6;
  if (row0 >= offs[E]) return;
  int e = E - 1;
  while (e > 0 && offs[e] > row0) --e;
  const float* Wp = W1 + (size_t)e * N * K;
  const float* bp = b1 + (size_t)e * N;
  __shared__ float As[16][68];
  __shared__ float Ws[16][68];
  int tid = threadIdx.x;
  int col0 = blockIdx.x << 6;
  int lr = tid >> 2, lk = (tid & 3) << 2;
  int tx = tid & 15, ty = tid >> 4;
  int t = tok[row0 + lr];
  const float* Aload = (t >= 0) ? (Xsrc + (size_t)t * K + lk) : nullptr;
  const float* Wload = Wp + (size_t)(col0 + lr) * K + lk;
  float acc[4][4] = {};
  for (int k0 = 0; k0 < K; k0 += 16) {
    float4 av = Aload ? *(const float4*)(Aload + k0) : make_float4(0.f, 0.f, 0.f, 0.f);
    float4 wv = *(const float4*)(Wload + k0);
    As[lk][lr] = av.x; As[lk + 1][lr] = av.y; As[lk + 2][lr] = av.z; As[lk + 3][lr] = av.w;
    Ws[lk][lr] = wv.x; Ws[lk + 1][lr] = wv.y; Ws[lk + 2][lr] = wv.z; Ws[lk + 3][lr] = wv.w;
    __syncthreads();
#pragma unroll
    for (int k = 0; k < 16; ++k) {
      float4 a = *(const float4*)&As[k][ty << 2];
      float4 b = *(const float4*)&Ws[k][tx << 2];
      FMA16(a, b, acc);
    }
    __syncthreads();
  }
#pragma unroll
  for (int i = 0; i < 4; ++i) {
    int r = row0 + (ty << 2) + i;
    int c0 = col0 + (tx << 2);
    float4 v;
    v.x = gelu_f(acc[i][0] + bp[c0]);
    v.y = gelu_f(acc[i][1] + bp[c0 + 1]);
    v.z = gelu_f(acc[i][2] + bp[c0 + 2]);
    v.w = gelu_f(acc[i][3] + bp[c0 + 3]);
    *(float4*)(H + (size_t)r * N + c0) = v;
  }
}

// ---------------- MoE GEMM2: OUT[t,256] += w_slot * (H[slot,512] @ W2_e^T + b2_e) ----------------
__global__ __launch_bounds__(256) void k_moe_gemm2(
    const float* __restrict__ Hsrc, const int* __restrict__ tok,
    const float* __restrict__ wslot, const int* __restrict__ offs, int E,
    const float* __restrict__ W2, const float* __restrict__ b2,
    float* __restrict__ OUT)
{
  const int N = 256, K = 512;
  int row0 = blockIdx.y << 6;
  if (row0 >= offs[E]) return;
  int e = E - 1;
  while (e > 0 && offs[e] > row0) --e;
  const float* Wp = W2 + (size_t)e * N * K;
  const float* bp = b2 + (size_t)e * N;
  __shared__ float As[16][68];
  __shared__ float Ws[16][68];
  int tid = threadIdx.x;
  int col0 = blockIdx.x << 6;
  int lr = tid >> 2, lk = (tid & 3) << 2;
  int tx = tid & 15, ty = tid >> 4;
  const float* Aload = Hsrc + (size_t)(row0 + lr) * K + lk;
  const float* Wload = Wp + (size_t)(col0 + lr) * K + lk;
  float acc[4][4] = {};
  for (int k0 = 0; k0 < K; k0 += 16) {
    float4 av = *(const float4*)(Aload + k0);
    float4 wv = *(const float4*)(Wload + k0);
    As[lk][lr] = av.x; As[lk + 1][lr] = av.y; As[lk + 2][lr] = av.z; As[lk + 3][lr] = av.w;
    Ws[lk][lr] = wv.x; Ws[lk + 1][lr] = wv.y; Ws[lk + 2][lr] = wv.z; Ws[lk + 3][lr] = wv.w;
    __syncthreads();
#pragma unroll
    for (int k = 0; k < 16; ++k) {
      float4 a = *(const float4*)&As[k][ty << 2];
      float4 b = *(const float4*)&Ws[k][tx << 2];
      FMA16(a, b, acc);
    }
    __syncthreads();
  }
#pragma unroll
  for (int i = 0; i < 4; ++i) {
    int r = row0 + (ty << 2) + i;
    int t = tok[r];
    if (t < 0) continue;
    float wgt = wslot[r];
    int c0 = col0 + (tx << 2);
    float* orow = OUT + (size_t)t * N + c0;
    atomicAdd(orow + 0, wgt * (acc[i][0] + bp[c0]));
    atomicAdd(orow + 1, wgt * (acc[i][1] + bp[c0 + 1]));
    atomicAdd(orow + 2, wgt * (acc[i][2] + bp[c0 + 2]));
    atomicAdd(orow + 3, wgt * (acc[i][3] + bp[c0 + 3]));
  }
}

// ---------------- self-attention, one block per (b,h) ----------------
__global__ __launch_bounds__(256) void k_attn(const float* __restrict__ qkv, float* __restrict__ ao)
{
  __shared__ float Ks[6400];
  __shared__ float Vs[6400];
  int bh = blockIdx.x;
  int b = bh >> 3, h = bh & 7;
  const float* base = qkv + (size_t)b * 200 * 768;
  int tid = threadIdx.x;
  for (int i = tid; i < 6400; i += 256) {
    int s = i >> 5, d = i & 31;
    Ks[i] = base[s * 768 + 256 + h * 32 + d];
    Vs[i] = base[s * 768 + 512 + h * 32 + d];
  }
  __syncthreads();
  int q = tid;
  if (q >= 200) return;
  float qr[32];
  const float* qrow = base + q * 768 + h * 32;
#pragma unroll
  for (int d = 0; d < 32; ++d) qr[d] = qrow[d];
  const float scale = 0.17677669529663687f;   // 1/sqrt(32)
  float m = -1e30f;
  for (int s = 0; s < 200; ++s) {
    float acc = 0.f;
#pragma unroll
    for (int d = 0; d < 32; ++d) acc += qr[d] * Ks[s * 32 + d];
    m = fmaxf(m, acc * scale);
  }
  float l = 0.f;
  float ov[32] = {};
  for (int s = 0; s < 200; ++s) {
    float acc = 0.f;
#pragma unroll
    for (int d = 0; d < 32; ++d) acc += qr[d] * Ks[s * 32 + d];
    float p = expf(acc * scale - m);
    l += p;
#pragma unroll
    for (int d = 0; d < 32; ++d) ov[d] += p * Vs[s * 32 + d];
  }
  float inv = 1.f / l;
  float* orow = ao + (size_t)(b * 200 + q) * 256 + h * 32;
#pragma unroll
  for (int d = 0; d < 32; ++d) orow[d] = ov[d] * inv;
}

// ---------------- cross-attention, one block per (b,h), 16 queries ----------------
__global__ __launch_bounds__(256) void k_xattn(
    const float* __restrict__ Q, const float* __restrict__ Kb,
    const float* __restrict__ Vb, float* __restrict__ O)
{
  __shared__ float Ks[6400];
  __shared__ float Vs[6400];
  int bh = blockIdx.x;
  int b = bh >> 3, h = bh & 7;
  int tid = threadIdx.x;
  for (int i = tid; i < 6400; i += 256) {
    int s = i >> 5, d = i & 31;
    Ks[i] = Kb[(size_t)(b * 200 + s) * 256 + h * 32 + d];
    Vs[i] = Vb[(size_t)(b * 200 + s) * 256 + h * 32 + d];
  }
  __syncthreads();
  int q = tid;
  if (q >= 16) return;
  float qr[32];
  const float* qrow = Q + (size_t)(b * 16 + q) * 256 + h * 32;
#pragma unroll
  for (int d = 0; d < 32; ++d) qr[d] = qrow[d];
  const float scale = 0.17677669529663687f;
  float m = -1e30f;
  for (int s = 0; s < 200; ++s) {
    float acc = 0.f;
#pragma unroll
    for (int d = 0; d < 32; ++d) acc += qr[d] * Ks[s * 32 + d];
    m = fmaxf(m, acc * scale);
  }
  float l = 0.f;
  float ov[32] = {};
  for (int s = 0; s < 200; ++s) {
    float acc = 0.f;
#pragma unroll
    for (int d = 0; d < 32; ++d) acc += qr[d] * Ks[s * 32 + d];
    float p = expf(acc * scale - m);
    l += p;
#pragma unroll
    for (int d = 0; d < 32; ++d) ov[d] += p * Vs[s * 32 + d];
  }
  float inv = 1.f / l;
  float* orow = O + (size_t)(b * 16 + q) * 256 + h * 32;
#pragma unroll
  for (int d = 0; d < 32; ++d) orow[d] = ov[d] * inv;
}

// ---------------- LayerNorm (optional residual), one block per token ----------------
__global__ __launch_bounds__(256) void k_ln(
    const float* __restrict__ Xin, const float* __restrict__ R,
    const float* __restrict__ sc, const float* __restrict__ bi, float* __restrict__ Y)
{
  int t = blockIdx.x, d = threadIdx.x;
  size_t idx = (size_t)t * 256 + d;
  float v = Xin[idx];
  if (R) v += R[idx];
  __shared__ float red[8];
  int lane = d & 63, wid = d >> 6;
  float s = v;
#pragma unroll
  for (int off = 32; off > 0; off >>= 1) s += __shfl_xor(s, off, 64);
  if (lane == 0) red[wid] = s;
  __syncthreads();
  float mean = (red[0] + red[1] + red[2] + red[3]) * 0.00390625f;
  float dv = v - mean;
  float s2 = dv * dv;
#pragma unroll
  for (int off = 32; off > 0; off >>= 1) s2 += __shfl_xor(s2, off, 64);
  if (lane == 0) red[4 + wid] = s2;
  __syncthreads();
  float var = (red[4] + red[5] + red[6] + red[7]) * 0.00390625f;
  Y[idx] = dv * (1.0f / sqrtf(var + 1e-5f)) * sc[d] + bi[d];
}

// ---------------- router: one wave per token ----------------
template <int E>
__global__ __launch_bounds__(256) void k_router(
    const float* __restrict__ X, int T,
    const float* __restrict__ gw, const float* __restrict__ gb,
    float* __restrict__ probs, int* __restrict__ ti, float* __restrict__ tw,
    int* __restrict__ counts)
{
  int lane = threadIdx.x & 63, wid = threadIdx.x >> 6;
  int t = blockIdx.x * 4 + wid;
  if (t >= T) return;
  float4 x4 = *(const float4*)(X + (size_t)t * 256 + lane * 4);
  float p[E];
#pragma unroll
  for (int e = 0; e < E; ++e) {
    float4 g = *(const float4*)(gw + (size_t)e * 256 + lane * 4);
    float s = x4.x * g.x + x4.y * g.y + x4.z * g.z + x4.w * g.w;
#pragma unroll
    for (int off = 32; off > 0; off >>= 1) s += __shfl_xor(s, off, 64);
    p[e] = s + gb[e];
  }
  float m = p[0];
#pragma unroll
  for (int e = 1; e < E; ++e) m = fmaxf(m, p[e]);
  float sum = 0.f;
#pragma unroll
  for (int e = 0; e < E; ++e) { p[e] = expf(p[e] - m); sum += p[e]; }
  float inv = 1.f / sum;
#pragma unroll
  for (int e = 0; e < E; ++e) p[e] *= inv;
  if (lane < E) probs[(size_t)t * E + lane] = p[lane];
  if (lane == 0) {
    float v1 = p[0]; int i1 = 0;
#pragma unroll
    for (int e = 1; e < E; ++e) if (p[e] > v1) { v1 = p[e]; i1 = e; }
    float v2 = -1.f; int i2 = 0;
#pragma unroll
    for (int e = 0; e < E; ++e) if (e != i1 && p[e] > v2) { v2 = p[e]; i2 = e; }
    float s2 = v1 + v2;
    ti[t * 2] = i1; ti[t * 2 + 1] = i2;
    tw[t * 2] = v1 / s2; tw[t * 2 + 1] = v2 / s2;
    atomicAdd(&counts[i1], 1);
    atomicAdd(&counts[i2], 1);
  }
}

// ---------------- 64-aligned exclusive scan over expert counts ----------------
__global__ void k_scan(const int* __restrict__ counts, int E, int* __restrict__ offs)
{
  if (threadIdx.x == 0 && blockIdx.x == 0) {
    int o = 0;
    for (int e = 0; e < E; ++e) { offs[e] = o; o += (counts[e] + 63) & ~63; }
    offs[E] = o;
  }
}

// ---------------- fill expert slot lists ----------------
__global__ __launch_bounds__(256) void k_fill(
    const int* __restrict__ ti, const float* __restrict__ tw, int T,
    const int* __restrict__ offs, int* __restrict__ cnt2,
    int* __restrict__ tok, float* __restrict__ ws)
{
  int t = blockIdx.x * 256 + threadIdx.x;
  if (t >= T) return;
  for (int j = 0; j < 2; ++j) {
    int e = ti[t * 2 + j];
    int pos = atomicAdd(&cnt2[e], 1);
    int slot = offs[e] + pos;
    tok[slot] = t;
    ws[slot] = tw[t * 2 + j];
  }
}

// ---------------- concat [taw | item] ----------------
__global__ __launch_bounds__(256) void k_concat(
    const float* __restrict__ A, const float* __restrict__ B, float* __restrict__ O, int total)
{
  int i = blockIdx.x * 256 + threadIdx.x;
  if (i >= total) return;
  int t = i >> 9, c = i & 511;
  O[i] = (c < 256) ? A[(size_t)t * 256 + c] : B[(size_t)t * 256 + c - 256];
}

// ---------------- final logits: dot(FH[t], fm_w2) + b ----------------
__global__ __launch_bounds__(256) void k_final(
    const float* __restrict__ FH, const float* __restrict__ w2,
    const float* __restrict__ b2, float* __restrict__ out, int T)
{
  int lane = threadIdx.x & 63, wid = threadIdx.x >> 6;
  int t = blockIdx.x * 4 + wid;
  if (t >= T) return;
  float4 h = *(const float4*)(FH + (size_t)t * 256 + lane * 4);
  float4 w = *(const float4*)(w2 + lane * 4);
  float s = h.x * w.x + h.y * w.y + h.z * w.z + h.w * w.w;
#pragma unroll
  for (int off = 32; off > 0; off >>= 1) s += __shfl_xor(s, off, 64);
  if (lane == 0) out[t] = s + b2[0];
}

// ---------------- aux load-balance loss (single block) ----------------
__global__ __launch_bounds__(256) void k_aux(
    const float* __restrict__ p0, const float* __restrict__ p1,
    const float* __restrict__ pi, float* __restrict__ out_aux)
{
  __shared__ float red[256];
  int tid = threadIdx.x;
  float aux = 0.f;
  for (int r = 0; r < 2; ++r) {
    const float* P = (r == 0) ? p0 : p1;
    float loc[4] = {0.f, 0.f, 0.f, 0.f};
    for (int t = tid; t < T_U; t += 256) {
#pragma unroll
      for (int e = 0; e < 4; ++e) loc[e] += P[t * 4 + e];
    }
    float contrib = 0.f;
    for (int e = 0; e < 4; ++e) {
      red[tid] = loc[e];
      __syncthreads();
      for (int s = 128; s > 0; s >>= 1) { if (tid < s) red[tid] += red[tid + s]; __syncthreads(); }
      if (tid == 0) { float d = red[0] * (1.f / T_U) - 0.125f; contrib += d * d; }
      __syncthreads();
    }
    if (tid == 0) aux += contrib * 0.25f;
  }
  {
    float loc[8] = {};
    for (int t = tid; t < T_I; t += 256) {
#pragma unroll
      for (int e = 0; e < 8; ++e) loc[e] += pi[t * 8 + e];
    }
    float contrib = 0.f;
    for (int e = 0; e < 8; ++e) {
      red[tid] = loc[e];
      __syncthreads();
      for (int s = 128; s > 0; s >>= 1) { if (tid < s) red[tid] += red[tid + s]; __syncthreads(); }
      if (tid == 0) { float d = red[0] * (1.f / T_I) - 0.125f; contrib += d * d; }
      __syncthreads();
    }
    if (tid == 0) aux += contrib * 0.125f;
  }
  if (tid == 0) *out_aux = aux;
}

// =======================================================================
extern "C" void kernel_launch(void* const* d_in, const int* in_sizes, int n_in,
                              void* d_out, int out_size, void* d_ws, size_t ws_size,
                              hipStream_t stream)
{
  (void)in_sizes; (void)n_in; (void)out_size;
  const int*   history  = (const int*)d_in[0];
  const int*   cand     = (const int*)d_in[1];
  const int*   catid    = (const int*)d_in[2];
  const float* item_emb = (const float*)d_in[3];
  const float* cat_emb  = (const float*)d_in[4];
  const float* ub_in_w  = (const float*)d_in[5];
  const float* ub_in_b  = (const float*)d_in[6];
  const float* ub_out_w = (const float*)d_in[7];
  const float* ub_out_b = (const float*)d_in[8];
  const float* ub_n1_s  = (const float*)d_in[9];
  const float* ub_n1_b  = (const float*)d_in[10];
  const float* ub_n2_s  = (const float*)d_in[11];
  const float* ub_n2_b  = (const float*)d_in[12];
  const float* ub_gate_w= (const float*)d_in[13];
  const float* ub_gate_b= (const float*)d_in[14];
  const float* ub_e_w1  = (const float*)d_in[15];
  const float* ub_e_b1  = (const float*)d_in[16];
  const float* ub_e_w2  = (const float*)d_in[17];
  const float* ub_e_b2  = (const float*)d_in[18];
  const float* un_s     = (const float*)d_in[19];
  const float* un_b     = (const float*)d_in[20];
  const float* im_gate_w= (const float*)d_in[21];
  const float* im_gate_b= (const float*)d_in[22];
  const float* im_e_w1  = (const float*)d_in[23];
  const float* im_e_b1  = (const float*)d_in[24];
  const float* im_e_w2  = (const float*)d_in[25];
  const float* im_e_b2  = (const float*)d_in[26];
  const float* in_s     = (const float*)d_in[27];
  const float* in_b     = (const float*)d_in[28];
  const float* ca_in_w  = (const float*)d_in[29];
  const float* ca_in_b  = (const float*)d_in[30];
  const float* ca_out_w = (const float*)d_in[31];
  const float* ca_out_b = (const float*)d_in[32];
  const float* fm_w1    = (const float*)d_in[33];
  const float* fm_b1    = (const float*)d_in[34];
  const float* fm_w2    = (const float*)d_in[35];
  const float* fm_b2    = (const float*)d_in[36];
  float* out = (float*)d_out;

  float* W = (float*)d_ws;
  size_t o = 0;
  auto alloc = [&](size_t n) { size_t r = o; o += (n + 63) & ~(size_t)63; return r; };
  const size_t oX    = alloc((size_t)T_U * 256);
  const size_t oQKV  = alloc((size_t)T_U * 768);   // region A (reused: Hbuf / Kbuf,Vbuf,HbufI)
  const size_t oAO   = alloc((size_t)T_U * 256);   // region B (Hbuf spillover)
  const size_t oEXT  = alloc(131072 + 64);         // region C (Hbuf tail)
  const size_t oTMP  = alloc((size_t)T_U * 256);
  const size_t oP0   = alloc((size_t)T_U * 4);
  const size_t oP1   = alloc((size_t)T_U * 4);
  const size_t oPI   = alloc((size_t)T_I * 8);
  const size_t oTW   = alloc((size_t)T_U * 2);
  const size_t oWS   = alloc(CAP_U);
  const size_t oTI   = alloc((size_t)T_U * 2);     // int
  const size_t oTOK  = alloc(CAP_U);               // int
  const size_t oCNT  = alloc(64);                  // int: counts[8]|cnt2[8]|offs[9]
  const size_t oIE   = alloc((size_t)T_I * 256);
  const size_t oMOI  = alloc((size_t)T_I * 256);
  const size_t oITEM = alloc((size_t)T_I * 256);
  const size_t oQB   = alloc((size_t)T_I * 256);
  const size_t oOB   = alloc((size_t)T_I * 256);
  const size_t oTAW  = alloc((size_t)T_I * 256);
  const size_t oFUS  = alloc((size_t)T_I * 512);
  const size_t oFH   = alloc((size_t)T_I * 256);
  (void)oEXT;
  if (ws_size < o * sizeof(float)) {
    k_sentinel<<<1, 1, 0, stream>>>(out);
    return;
  }

  float* X    = W + oX;
  float* QKV  = W + oQKV;
  float* AO   = W + oAO;
  float* TMP  = W + oTMP;
  float* Hbuf = QKV;                               // spans A+B+C (>= CAP_U*512 floats)
  float* P0   = W + oP0;
  float* P1   = W + oP1;
  float* PI   = W + oPI;
  float* TWb  = W + oTW;
  float* WSb  = W + oWS;
  int*   TIb  = (int*)(W + oTI);
  int*   TOKb = (int*)(W + oTOK);
  int*   CNT  = (int*)(W + oCNT);
  int*   CNT2 = CNT + 8;
  int*   OFFS = CNT + 16;
  float* IE   = W + oIE;
  float* MOI  = W + oMOI;
  float* ITEM = W + oITEM;
  float* QB   = W + oQB;
  float* OB   = W + oOB;
  float* TAW  = W + oTAW;
  float* FUS  = W + oFUS;
  float* FH   = W + oFH;
  float* Kbuf  = QKV;
  float* Vbuf  = QKV + (size_t)T_U * 256;
  float* HbufI = QKV + (size_t)2 * T_U * 256;

  // 1) embedding + rope
  k_embed_rope<<<T_U, 256, 0, stream>>>(history, item_emb, X);

  // 2) user transformer layers
  for (int l = 0; l < 2; ++l) {
    k_gemm<<<dim3(12, 200), 256, 0, stream>>>(X, ub_in_w + (size_t)l * 768 * 256,
        ub_in_b + (size_t)l * 768, QKV, T_U, 768, 256, 0);
    k_attn<<<512, 256, 0, stream>>>(QKV, AO);
    k_gemm<<<dim3(4, 200), 256, 0, stream>>>(AO, ub_out_w + (size_t)l * 256 * 256,
        ub_out_b + (size_t)l * 256, TMP, T_U, 256, 256, 0);
    k_ln<<<T_U, 256, 0, stream>>>(X, TMP, ub_n1_s + l * 256, ub_n1_b + l * 256, X);
    hipMemsetAsync(CNT, 0, 128, stream);
    k_router<4><<<T_U / 4, 256, 0, stream>>>(X, T_U, ub_gate_w + (size_t)l * 4 * 256,
        ub_gate_b + l * 4, (l == 0) ? P0 : P1, TIb, TWb, CNT);
    k_scan<<<1, 1, 0, stream>>>(CNT, 4, OFFS);
    hipMemsetAsync(TOKb, 0xFF, (size_t)CAP_U * 4, stream);
    k_fill<<<T_U / 256, 256, 0, stream>>>(TIb, TWb, T_U, OFFS, CNT2, TOKb, WSb);
    k_moe_gemm1<<<dim3(8, CAP_U / 64), 256, 0, stream>>>(X, TOKb, OFFS, 4,
        ub_e_w1 + (size_t)l * 4 * 512 * 256, ub_e_b1 + (size_t)l * 4 * 512, Hbuf);
    hipMemsetAsync(TMP, 0, (size_t)T_U * 256 * 4, stream);
    k_moe_gemm2<<<dim3(4, CAP_U / 64), 256, 0, stream>>>(Hbuf, TOKb, WSb, OFFS, 4,
        ub_e_w2 + (size_t)l * 4 * 256 * 512, ub_e_b2 + (size_t)l * 4 * 256, TMP);
    k_ln<<<T_U, 256, 0, stream>>>(X, TMP, ub_n2_s + l * 256, ub_n2_b + l * 256, X);
  }

  // 3) history final LN
  k_ln<<<T_U, 256, 0, stream>>>(X, nullptr, un_s, un_b, X);

  // 4) item tower
  k_item_embed<<<T_I, 256, 0, stream>>>(cand, catid, item_emb, cat_emb, IE);
  hipMemsetAsync(CNT, 0, 128, stream);
  k_router<8><<<T_I / 4, 256, 0, stream>>>(IE, T_I, im_gate_w, im_gate_b, PI, TIb, TWb, CNT);
  k_scan<<<1, 1, 0, stream>>>(CNT, 8, OFFS);
  hipMemsetAsync(TOKb, 0xFF, (size_t)CAP_I * 4, stream);
  k_fill<<<T_I / 256, 256, 0, stream>>>(TIb, TWb, T_I, OFFS, CNT2, TOKb, WSb);
  k_moe_gemm1<<<dim3(8, CAP_I / 64), 256, 0, stream>>>(IE, TOKb, OFFS, 8,
      im_e_w1, im_e_b1, HbufI);
  hipMemsetAsync(MOI, 0, (size_t)T_I * 256 * 4, stream);
  k_moe_gemm2<<<dim3(4, CAP_I / 64), 256, 0, stream>>>(HbufI, TOKb, WSb, OFFS, 8,
      im_e_w2, im_e_b2, MOI);
  k_ln<<<T_I, 256, 0, stream>>>(MOI, nullptr, in_s, in_b, ITEM);

  // 5) cross attention
  k_gemm<<<dim3(4, 16), 256, 0, stream>>>(ITEM, ca_in_w, ca_in_b, QB, T_I, 256, 256, 0);
  k_gemm<<<dim3(4, 200), 256, 0, stream>>>(X, ca_in_w + 256 * 256, ca_in_b + 256, Kbuf,
      T_U, 256, 256, 0);
  k_gemm<<<dim3(4, 200), 256, 0, stream>>>(X, ca_in_w + 512 * 256, ca_in_b + 512, Vbuf,
      T_U, 256, 256, 0);
  k_xattn<<<512, 256, 0, stream>>>(QB, Kbuf, Vbuf, OB);
  k_gemm<<<dim3(4, 16), 256, 0, stream>>>(OB, ca_out_w, ca_out_b, TAW, T_I, 256, 256, 0);

  // 6) fusion MLP + logits
  k_concat<<<(T_I * 512) / 256, 256, 0, stream>>>(TAW, ITEM, FUS, T_I * 512);
  k_gemm<<<dim3(4, 16), 256, 0, stream>>>(FUS, fm_w1, fm_b1, FH, T_I, 256, 512, 1);
  k_final<<<T_I / 4, 256, 0, stream>>>(FH, fm_w2, fm_b2, out, T_I);

  // 7) aux loss
  k_aux<<<1, 256, 0, stream>>>(P0, P1, PI, out + 1024);
}

// Round 2
// 1866.908 us; speedup vs baseline: 1.4332x; 1.4332x over previous
//
#include <hip/hip_runtime.h>
#include <cstddef>
#include <cstdint>

#define T_U   12800   // user tokens B*S
#define T_I   1024    // item tokens B*Nc
#define CAP_U 25856   // 2*T_U + 4*64 slot capacity (64-aligned per expert)
#define CAP_I 2560    // 2*T_I + 8*64

__device__ __forceinline__ float gelu_f(float x) {
  return 0.5f * x * (1.0f + erff(x * 0.7071067811865476f));
}

#define FMA16(a, b, acc)                                                        \
  acc[0][0] += a.x * b.x; acc[0][1] += a.x * b.y; acc[0][2] += a.x * b.z; acc[0][3] += a.x * b.w; \
  acc[1][0] += a.y * b.x; acc[1][1] += a.y * b.y; acc[1][2] += a.y * b.z; acc[1][3] += a.y * b.w; \
  acc[2][0] += a.z * b.x; acc[2][1] += a.z * b.y; acc[2][2] += a.z * b.z; acc[2][3] += a.z * b.w; \
  acc[3][0] += a.w * b.x; acc[3][1] += a.w * b.y; acc[3][2] += a.w * b.z; acc[3][3] += a.w * b.w;

// ---------------- sentinel (ws too small) ----------------
__global__ void k_sentinel(float* out) { out[0] = 1.0e9f; }

// ---------------- embedding + (faithful) RoPE ----------------
__global__ __launch_bounds__(256) void k_embed_rope(
    const int* __restrict__ hist, const float* __restrict__ emb, float* __restrict__ X)
{
  int t = blockIdx.x;            // b*200 + s
  int s = t % 200;
  int d = threadIdx.x;           // 0..255
  const float* row = emb + (size_t)hist[t] * 256;
  float x0 = row[d];
  float x1 = row[(d + 1) & 255];           // roll(x,-1)
  int fi = d & 127;
  float inv = expf(-9.210340371976184f * ((float)fi * (1.0f / 128.0f)));
  float ang = (float)s * inv;
  X[(size_t)t * 256 + d] = x0 * cosf(ang) + x1 * sinf(ang);
}

// ---------------- item embedding sum ----------------
__global__ __launch_bounds__(256) void k_item_embed(
    const int* __restrict__ cand, const int* __restrict__ catid,
    const float* __restrict__ item_emb, const float* __restrict__ cat_emb,
    float* __restrict__ IE)
{
  int t = blockIdx.x, d = threadIdx.x;
  IE[(size_t)t * 256 + d] =
      item_emb[(size_t)cand[t] * 256 + d] + cat_emb[(size_t)catid[t] * 256 + d];
}

// ---------------- generic GEMM: C[M,N] = act(A[M,K] @ W[N,K]^T + bias) ----------------
__global__ __launch_bounds__(256) void k_gemm(
    const float* __restrict__ A, const float* __restrict__ Wm,
    const float* __restrict__ bias, float* __restrict__ C,
    int M, int N, int K, int act)
{
  __shared__ float As[16][68];
  __shared__ float Ws[16][68];
  int tid = threadIdx.x;
  int row0 = blockIdx.y << 6;
  int col0 = blockIdx.x << 6;
  int lr = tid >> 2, lk = (tid & 3) << 2;
  int tx = tid & 15, ty = tid >> 4;
  const float* Aload = A + (size_t)(row0 + lr) * K + lk;
  const float* Wload = Wm + (size_t)(col0 + lr) * K + lk;
  float acc[4][4] = {};
  for (int k0 = 0; k0 < K; k0 += 16) {
    float4 av = *(const float4*)(Aload + k0);
    float4 wv = *(const float4*)(Wload + k0);
    As[lk][lr] = av.x; As[lk + 1][lr] = av.y; As[lk + 2][lr] = av.z; As[lk + 3][lr] = av.w;
    Ws[lk][lr] = wv.x; Ws[lk + 1][lr] = wv.y; Ws[lk + 2][lr] = wv.z; Ws[lk + 3][lr] = wv.w;
    __syncthreads();
#pragma unroll
    for (int k = 0; k < 16; ++k) {
      float4 a = *(const float4*)&As[k][ty << 2];
      float4 b = *(const float4*)&Ws[k][tx << 2];
      FMA16(a, b, acc);
    }
    __syncthreads();
  }
#pragma unroll
  for (int i = 0; i < 4; ++i) {
    int r = row0 + (ty << 2) + i;
    int c0 = col0 + (tx << 2);
    float4 v;
    v.x = acc[i][0]; v.y = acc[i][1]; v.z = acc[i][2]; v.w = acc[i][3];
    if (bias) { v.x += bias[c0]; v.y += bias[c0 + 1]; v.z += bias[c0 + 2]; v.w += bias[c0 + 3]; }
    if (act) { v.x = gelu_f(v.x); v.y = gelu_f(v.y); v.z = gelu_f(v.z); v.w = gelu_f(v.w); }
    *(float4*)(C + (size_t)r * N + c0) = v;
  }
}

// ---------------- MoE GEMM1: H[slot,512] = gelu(Xg[slot,256] @ W1_e^T + b1_e) ----------------
__global__ __launch_bounds__(256) void k_moe_gemm1(
    const float* __restrict__ Xsrc, const int* __restrict__ tok,
    const int* __restrict__ offs, int E,
    const float* __restrict__ W1, const float* __restrict__ b1,
    float* __restrict__ H)
{
  const int N = 512, K = 256;
  int row0 = blockIdx.y << 6;
  if (row0 >= offs[E]) return;
  int e = E - 1;
  while (e > 0 && offs[e] > row0) --e;
  const float* Wp = W1 + (size_t)e * N * K;
  const float* bp = b1 + (size_t)e * N;
  __shared__ float As[16][68];
  __shared__ float Ws[16][68];
  int tid = threadIdx.x;
  int col0 = blockIdx.x << 6;
  int lr = tid >> 2, lk = (tid & 3) << 2;
  int tx = tid & 15, ty = tid >> 4;
  int t = tok[row0 + lr];
  const float* Aload = (t >= 0) ? (Xsrc + (size_t)t * K + lk) : nullptr;
  const float* Wload = Wp + (size_t)(col0 + lr) * K + lk;
  float acc[4][4] = {};
  for (int k0 = 0; k0 < K; k0 += 16) {
    float4 av = Aload ? *(const float4*)(Aload + k0) : make_float4(0.f, 0.f, 0.f, 0.f);
    float4 wv = *(const float4*)(Wload + k0);
    As[lk][lr] = av.x; As[lk + 1][lr] = av.y; As[lk + 2][lr] = av.z; As[lk + 3][lr] = av.w;
    Ws[lk][lr] = wv.x; Ws[lk + 1][lr] = wv.y; Ws[lk + 2][lr] = wv.z; Ws[lk + 3][lr] = wv.w;
    __syncthreads();
#pragma unroll
    for (int k = 0; k < 16; ++k) {
      float4 a = *(const float4*)&As[k][ty << 2];
      float4 b = *(const float4*)&Ws[k][tx << 2];
      FMA16(a, b, acc);
    }
    __syncthreads();
  }
#pragma unroll
  for (int i = 0; i < 4; ++i) {
    int r = row0 + (ty << 2) + i;
    int c0 = col0 + (tx << 2);
    float4 v;
    v.x = gelu_f(acc[i][0] + bp[c0]);
    v.y = gelu_f(acc[i][1] + bp[c0 + 1]);
    v.z = gelu_f(acc[i][2] + bp[c0 + 2]);
    v.w = gelu_f(acc[i][3] + bp[c0 + 3]);
    *(float4*)(H + (size_t)r * N + c0) = v;
  }
}

// ---------------- MoE GEMM2: OUT[t,256] += w_slot * (H[slot,512] @ W2_e^T + b2_e) ----------------
__global__ __launch_bounds__(256) void k_moe_gemm2(
    const float* __restrict__ Hsrc, const int* __restrict__ tok,
    const float* __restrict__ wslot, const int* __restrict__ offs, int E,
    const float* __restrict__ W2, const float* __restrict__ b2,
    float* __restrict__ OUT)
{
  const int N = 256, K = 512;
  int row0 = blockIdx.y << 6;
  if (row0 >= offs[E]) return;
  int e = E - 1;
  while (e > 0 && offs[e] > row0) --e;
  const float* Wp = W2 + (size_t)e * N * K;
  const float* bp = b2 + (size_t)e * N;
  __shared__ float As[16][68];
  __shared__ float Ws[16][68];
  int tid = threadIdx.x;
  int col0 = blockIdx.x << 6;
  int lr = tid >> 2, lk = (tid & 3) << 2;
  int tx = tid & 15, ty = tid >> 4;
  const float* Aload = Hsrc + (size_t)(row0 + lr) * K + lk;
  const float* Wload = Wp + (size_t)(col0 + lr) * K + lk;
  float acc[4][4] = {};
  for (int k0 = 0; k0 < K; k0 += 16) {
    float4 av = *(const float4*)(Aload + k0);
    float4 wv = *(const float4*)(Wload + k0);
    As[lk][lr] = av.x; As[lk + 1][lr] = av.y; As[lk + 2][lr] = av.z; As[lk + 3][lr] = av.w;
    Ws[lk][lr] = wv.x; Ws[lk + 1][lr] = wv.y; Ws[lk + 2][lr] = wv.z; Ws[lk + 3][lr] = wv.w;
    __syncthreads();
#pragma unroll
    for (int k = 0; k < 16; ++k) {
      float4 a = *(const float4*)&As[k][ty << 2];
      float4 b = *(const float4*)&Ws[k][tx << 2];
      FMA16(a, b, acc);
    }
    __syncthreads();
  }
#pragma unroll
  for (int i = 0; i < 4; ++i) {
    int r = row0 + (ty << 2) + i;
    int t = tok[r];
    if (t < 0) continue;
    float wgt = wslot[r];
    int c0 = col0 + (tx << 2);
    float* orow = OUT + (size_t)t * N + c0;
    atomicAdd(orow + 0, wgt * (acc[i][0] + bp[c0]));
    atomicAdd(orow + 1, wgt * (acc[i][1] + bp[c0 + 1]));
    atomicAdd(orow + 2, wgt * (acc[i][2] + bp[c0 + 2]));
    atomicAdd(orow + 3, wgt * (acc[i][3] + bp[c0 + 3]));
  }
}

// ---------------- self-attention, one block per (b,h), float4 LDS ----------------
__global__ __launch_bounds__(256) void k_attn(const float* __restrict__ qkv, float* __restrict__ ao)
{
  __shared__ float4 Ks[1600];   // 200 x 8
  __shared__ float4 Vs[1600];
  int bh = blockIdx.x;
  int b = bh >> 3, h = bh & 7;
  const float* base = qkv + (size_t)b * 200 * 768;
  int tid = threadIdx.x;
  for (int i = tid; i < 1600; i += 256) {
    int s = i >> 3, d = i & 7;
    Ks[i] = *(const float4*)(base + s * 768 + 256 + h * 32 + d * 4);
    Vs[i] = *(const float4*)(base + s * 768 + 512 + h * 32 + d * 4);
  }
  __syncthreads();
  int q = tid;
  if (q >= 200) return;
  float4 qr[8];
  const float* qrow = base + q * 768 + h * 32;
#pragma unroll
  for (int d = 0; d < 8; ++d) qr[d] = *(const float4*)(qrow + d * 4);
  const float scale = 0.17677669529663687f;   // 1/sqrt(32)
  float m = -1e30f;
  for (int s = 0; s < 200; ++s) {
    float acc = 0.f;
#pragma unroll
    for (int d = 0; d < 8; ++d) {
      float4 kk = Ks[s * 8 + d];
      acc += qr[d].x * kk.x + qr[d].y * kk.y + qr[d].z * kk.z + qr[d].w * kk.w;
    }
    m = fmaxf(m, acc * scale);
  }
  float l = 0.f;
  float4 ov[8] = {};
  for (int s = 0; s < 200; ++s) {
    float acc = 0.f;
#pragma unroll
    for (int d = 0; d < 8; ++d) {
      float4 kk = Ks[s * 8 + d];
      acc += qr[d].x * kk.x + qr[d].y * kk.y + qr[d].z * kk.z + qr[d].w * kk.w;
    }
    float p = expf(acc * scale - m);
    l += p;
#pragma unroll
    for (int d = 0; d < 8; ++d) {
      float4 vv = Vs[s * 8 + d];
      ov[d].x += p * vv.x; ov[d].y += p * vv.y; ov[d].z += p * vv.z; ov[d].w += p * vv.w;
    }
  }
  float inv = 1.f / l;
  float* orow = ao + (size_t)(b * 200 + q) * 256 + h * 32;
#pragma unroll
  for (int d = 0; d < 8; ++d) {
    float4 v;
    v.x = ov[d].x * inv; v.y = ov[d].y * inv; v.z = ov[d].z * inv; v.w = ov[d].w * inv;
    *(float4*)(orow + d * 4) = v;
  }
}

// ---------------- cross-attention, one block per (b,h), 16 queries ----------------
__global__ __launch_bounds__(256) void k_xattn(
    const float* __restrict__ Q, const float* __restrict__ Kb,
    const float* __restrict__ Vb, float* __restrict__ O)
{
  __shared__ float4 Ks[1600];
  __shared__ float4 Vs[1600];
  int bh = blockIdx.x;
  int b = bh >> 3, h = bh & 7;
  int tid = threadIdx.x;
  for (int i = tid; i < 1600; i += 256) {
    int s = i >> 3, d = i & 7;
    Ks[i] = *(const float4*)(Kb + (size_t)(b * 200 + s) * 256 + h * 32 + d * 4);
    Vs[i] = *(const float4*)(Vb + (size_t)(b * 200 + s) * 256 + h * 32 + d * 4);
  }
  __syncthreads();
  int q = tid;
  if (q >= 16) return;
  float4 qr[8];
  const float* qrow = Q + (size_t)(b * 16 + q) * 256 + h * 32;
#pragma unroll
  for (int d = 0; d < 8; ++d) qr[d] = *(const float4*)(qrow + d * 4);
  const float scale = 0.17677669529663687f;
  float m = -1e30f;
  for (int s = 0; s < 200; ++s) {
    float acc = 0.f;
#pragma unroll
    for (int d = 0; d < 8; ++d) {
      float4 kk = Ks[s * 8 + d];
      acc += qr[d].x * kk.x + qr[d].y * kk.y + qr[d].z * kk.z + qr[d].w * kk.w;
    }
    m = fmaxf(m, acc * scale);
  }
  float l = 0.f;
  float4 ov[8] = {};
  for (int s = 0; s < 200; ++s) {
    float acc = 0.f;
#pragma unroll
    for (int d = 0; d < 8; ++d) {
      float4 kk = Ks[s * 8 + d];
      acc += qr[d].x * kk.x + qr[d].y * kk.y + qr[d].z * kk.z + qr[d].w * kk.w;
    }
    float p = expf(acc * scale - m);
    l += p;
#pragma unroll
    for (int d = 0; d < 8; ++d) {
      float4 vv = Vs[s * 8 + d];
      ov[d].x += p * vv.x; ov[d].y += p * vv.y; ov[d].z += p * vv.z; ov[d].w += p * vv.w;
    }
  }
  float inv = 1.f / l;
  float* orow = O + (size_t)(b * 16 + q) * 256 + h * 32;
#pragma unroll
  for (int d = 0; d < 8; ++d) {
    float4 v;
    v.x = ov[d].x * inv; v.y = ov[d].y * inv; v.z = ov[d].z * inv; v.w = ov[d].w * inv;
    *(float4*)(orow + d * 4) = v;
  }
}

// ---------------- LayerNorm (optional residual), one block per token ----------------
__global__ __launch_bounds__(256) void k_ln(
    const float* __restrict__ Xin, const float* __restrict__ R,
    const float* __restrict__ sc, const float* __restrict__ bi, float* __restrict__ Y)
{
  int t = blockIdx.x, d = threadIdx.x;
  size_t idx = (size_t)t * 256 + d;
  float v = Xin[idx];
  if (R) v += R[idx];
  __shared__ float red[8];
  int lane = d & 63, wid = d >> 6;
  float s = v;
#pragma unroll
  for (int off = 32; off > 0; off >>= 1) s += __shfl_xor(s, off, 64);
  if (lane == 0) red[wid] = s;
  __syncthreads();
  float mean = (red[0] + red[1] + red[2] + red[3]) * 0.00390625f;
  float dv = v - mean;
  float s2 = dv * dv;
#pragma unroll
  for (int off = 32; off > 0; off >>= 1) s2 += __shfl_xor(s2, off, 64);
  if (lane == 0) red[4 + wid] = s2;
  __syncthreads();
  float var = (red[4] + red[5] + red[6] + red[7]) * 0.00390625f;
  Y[idx] = dv * (1.0f / sqrtf(var + 1e-5f)) * sc[d] + bi[d];
}

// ---------------- router: one wave per token (NO global atomics) ----------------
template <int E>
__global__ __launch_bounds__(256) void k_router(
    const float* __restrict__ X, int T,
    const float* __restrict__ gw, const float* __restrict__ gb,
    float* __restrict__ probs, int* __restrict__ ti, float* __restrict__ tw)
{
  int lane = threadIdx.x & 63, wid = threadIdx.x >> 6;
  int t = blockIdx.x * 4 + wid;
  if (t >= T) return;
  float4 x4 = *(const float4*)(X + (size_t)t * 256 + lane * 4);
  float p[E];
#pragma unroll
  for (int e = 0; e < E; ++e) {
    float4 g = *(const float4*)(gw + (size_t)e * 256 + lane * 4);
    float s = x4.x * g.x + x4.y * g.y + x4.z * g.z + x4.w * g.w;
#pragma unroll
    for (int off = 32; off > 0; off >>= 1) s += __shfl_xor(s, off, 64);
    p[e] = s + gb[e];
  }
  float m = p[0];
#pragma unroll
  for (int e = 1; e < E; ++e) m = fmaxf(m, p[e]);
  float sum = 0.f;
#pragma unroll
  for (int e = 0; e < E; ++e) { p[e] = expf(p[e] - m); sum += p[e]; }
  float inv = 1.f / sum;
#pragma unroll
  for (int e = 0; e < E; ++e) p[e] *= inv;
  if (lane < E) probs[(size_t)t * E + lane] = p[lane];
  if (lane == 0) {
    float v1 = p[0]; int i1 = 0;
#pragma unroll
    for (int e = 1; e < E; ++e) if (p[e] > v1) { v1 = p[e]; i1 = e; }
    float v2 = -1.f; int i2 = 0;
#pragma unroll
    for (int e = 0; e < E; ++e) if (e != i1 && p[e] > v2) { v2 = p[e]; i2 = e; }
    float s2 = v1 + v2;
    ti[t * 2] = i1; ti[t * 2 + 1] = i2;
    tw[t * 2] = v1 / s2; tw[t * 2 + 1] = v2 / s2;
  }
}

// ---------------- fused count + 64-aligned scan + padding init (one block) ----------------
template <int E>
__global__ __launch_bounds__(256) void k_count_scan(
    const int* __restrict__ ti, int T,
    int* __restrict__ offs, int* __restrict__ cnt2, int* __restrict__ tok)
{
  __shared__ int sc[8];
  __shared__ int soffs[9];
  __shared__ int scnt[8];
  int tid = threadIdx.x;
  if (tid < 8) { sc[tid] = 0; cnt2[tid] = 0; }
  __syncthreads();
  int c[E];
#pragma unroll
  for (int k = 0; k < E; ++k) c[k] = 0;
  for (int i = tid; i < 2 * T; i += 256) {
    int e = ti[i];
#pragma unroll
    for (int k = 0; k < E; ++k) c[k] += (e == k) ? 1 : 0;
  }
#pragma unroll
  for (int k = 0; k < E; ++k) {
    int v = c[k];
#pragma unroll
    for (int off = 32; off > 0; off >>= 1) v += __shfl_xor(v, off, 64);
    if ((tid & 63) == 0) atomicAdd(&sc[k], v);
  }
  __syncthreads();
  if (tid == 0) {
    int o = 0;
    for (int e = 0; e < E; ++e) {
      soffs[e] = o; scnt[e] = sc[e];
      o += (sc[e] + 63) & ~63;
    }
    soffs[E] = o;
  }
  __syncthreads();
  if (tid <= E) offs[tid] = soffs[tid];
  // -1 padding in the roundup tail of each expert region
  for (int e = 0; e < E; ++e) {
    int s0 = soffs[e] + scnt[e], s1 = soffs[e + 1];
    for (int i = s0 + tid; i < s1; i += 256) tok[i] = -1;
  }
}

// ---------------- fill expert slot lists (hierarchical, low-contention) ----------------
__global__ __launch_bounds__(256) void k_fill(
    const int* __restrict__ ti, const float* __restrict__ tw, int T,
    const int* __restrict__ offs, int* __restrict__ cnt2,
    int* __restrict__ tok, float* __restrict__ ws)
{
  __shared__ int lcnt[8];
  __shared__ int lbase[8];
  int tid = threadIdx.x;
  if (tid < 8) lcnt[tid] = 0;
  __syncthreads();
  int t = blockIdx.x * 256 + tid;
  int e0 = 0, e1 = 0, p0 = 0, p1 = 0;
  bool act = (t < T);
  if (act) {
    e0 = ti[t * 2]; e1 = ti[t * 2 + 1];
    p0 = atomicAdd(&lcnt[e0], 1);       // LDS atomic: cheap
    p1 = atomicAdd(&lcnt[e1], 1);
  }
  __syncthreads();
  if (tid < 8) lbase[tid] = atomicAdd(&cnt2[tid], lcnt[tid]);  // <=8 global atomics/block
  __syncthreads();
  if (act) {
    int s0 = offs[e0] + lbase[e0] + p0;
    tok[s0] = t; ws[s0] = tw[t * 2];
    int s1 = offs[e1] + lbase[e1] + p1;
    tok[s1] = t; ws[s1] = tw[t * 2 + 1];
  }
}

// ---------------- concat [taw | item] ----------------
__global__ __launch_bounds__(256) void k_concat(
    const float* __restrict__ A, const float* __restrict__ B, float* __restrict__ O, int total)
{
  int i = blockIdx.x * 256 + threadIdx.x;
  if (i >= total) return;
  int t = i >> 9, c = i & 511;
  O[i] = (c < 256) ? A[(size_t)t * 256 + c] : B[(size_t)t * 256 + c - 256];
}

// ---------------- final logits: dot(FH[t], fm_w2) + b ----------------
__global__ __launch_bounds__(256) void k_final(
    const float* __restrict__ FH, const float* __restrict__ w2,
    const float* __restrict__ b2, float* __restrict__ out, int T)
{
  int lane = threadIdx.x & 63, wid = threadIdx.x >> 6;
  int t = blockIdx.x * 4 + wid;
  if (t >= T) return;
  float4 h = *(const float4*)(FH + (size_t)t * 256 + lane * 4);
  float4 w = *(const float4*)(w2 + lane * 4);
  float s = h.x * w.x + h.y * w.y + h.z * w.z + h.w * w.w;
#pragma unroll
  for (int off = 32; off > 0; off >>= 1) s += __shfl_xor(s, off, 64);
  if (lane == 0) out[t] = s + b2[0];
}

// ---------------- aux load-balance loss (single block) ----------------
__global__ __launch_bounds__(256) void k_aux(
    const float* __restrict__ p0, const float* __restrict__ p1,
    const float* __restrict__ pi, float* __restrict__ out_aux)
{
  __shared__ float red[256];
  int tid = threadIdx.x;
  float aux = 0.f;
  for (int r = 0; r < 2; ++r) {
    const float* P = (r == 0) ? p0 : p1;
    float loc[4] = {0.f, 0.f, 0.f, 0.f};
    for (int t = tid; t < T_U; t += 256) {
#pragma unroll
      for (int e = 0; e < 4; ++e) loc[e] += P[t * 4 + e];
    }
    float contrib = 0.f;
    for (int e = 0; e < 4; ++e) {
      red[tid] = loc[e];
      __syncthreads();
      for (int s = 128; s > 0; s >>= 1) { if (tid < s) red[tid] += red[tid + s]; __syncthreads(); }
      if (tid == 0) { float d = red[0] * (1.f / T_U) - 0.125f; contrib += d * d; }
      __syncthreads();
    }
    if (tid == 0) aux += contrib * 0.25f;
  }
  {
    float loc[8] = {};
    for (int t = tid; t < T_I; t += 256) {
#pragma unroll
      for (int e = 0; e < 8; ++e) loc[e] += pi[t * 8 + e];
    }
    float contrib = 0.f;
    for (int e = 0; e < 8; ++e) {
      red[tid] = loc[e];
      __syncthreads();
      for (int s = 128; s > 0; s >>= 1) { if (tid < s) red[tid] += red[tid + s]; __syncthreads(); }
      if (tid == 0) { float d = red[0] * (1.f / T_I) - 0.125f; contrib += d * d; }
      __syncthreads();
    }
    if (tid == 0) aux += contrib * 0.125f;
  }
  if (tid == 0) *out_aux = aux;
}

// =======================================================================
extern "C" void kernel_launch(void* const* d_in, const int* in_sizes, int n_in,
                              void* d_out, int out_size, void* d_ws, size_t ws_size,
                              hipStream_t stream)
{
  (void)in_sizes; (void)n_in; (void)out_size;
  const int*   history  = (const int*)d_in[0];
  const int*   cand     = (const int*)d_in[1];
  const int*   catid    = (const int*)d_in[2];
  const float* item_emb = (const float*)d_in[3];
  const float* cat_emb  = (const float*)d_in[4];
  const float* ub_in_w  = (const float*)d_in[5];
  const float* ub_in_b  = (const float*)d_in[6];
  const float* ub_out_w = (const float*)d_in[7];
  const float* ub_out_b = (const float*)d_in[8];
  const float* ub_n1_s  = (const float*)d_in[9];
  const float* ub_n1_b  = (const float*)d_in[10];
  const float* ub_n2_s  = (const float*)d_in[11];
  const float* ub_n2_b  = (const float*)d_in[12];
  const float* ub_gate_w= (const float*)d_in[13];
  const float* ub_gate_b= (const float*)d_in[14];
  const float* ub_e_w1  = (const float*)d_in[15];
  const float* ub_e_b1  = (const float*)d_in[16];
  const float* ub_e_w2  = (const float*)d_in[17];
  const float* ub_e_b2  = (const float*)d_in[18];
  const float* un_s     = (const float*)d_in[19];
  const float* un_b     = (const float*)d_in[20];
  const float* im_gate_w= (const float*)d_in[21];
  const float* im_gate_b= (const float*)d_in[22];
  const float* im_e_w1  = (const float*)d_in[23];
  const float* im_e_b1  = (const float*)d_in[24];
  const float* im_e_w2  = (const float*)d_in[25];
  const float* im_e_b2  = (const float*)d_in[26];
  const float* in_s     = (const float*)d_in[27];
  const float* in_b     = (const float*)d_in[28];
  const float* ca_in_w  = (const float*)d_in[29];
  const float* ca_in_b  = (const float*)d_in[30];
  const float* ca_out_w = (const float*)d_in[31];
  const float* ca_out_b = (const float*)d_in[32];
  const float* fm_w1    = (const float*)d_in[33];
  const float* fm_b1    = (const float*)d_in[34];
  const float* fm_w2    = (const float*)d_in[35];
  const float* fm_b2    = (const float*)d_in[36];
  float* out = (float*)d_out;

  float* W = (float*)d_ws;
  size_t o = 0;
  auto alloc = [&](size_t n) { size_t r = o; o += (n + 63) & ~(size_t)63; return r; };
  const size_t oX    = alloc((size_t)T_U * 256);
  const size_t oQKV  = alloc((size_t)T_U * 768);   // region A (reused: Hbuf / Kbuf,Vbuf,HbufI)
  const size_t oAO   = alloc((size_t)T_U * 256);   // region B (Hbuf spillover)
  const size_t oEXT  = alloc(131072 + 64);         // region C (Hbuf tail)
  const size_t oTMP  = alloc((size_t)T_U * 256);
  const size_t oP0   = alloc((size_t)T_U * 4);
  const size_t oP1   = alloc((size_t)T_U * 4);
  const size_t oPI   = alloc((size_t)T_I * 8);
  const size_t oTW   = alloc((size_t)T_U * 2);
  const size_t oWS   = alloc(CAP_U);
  const size_t oTI   = alloc((size_t)T_U * 2);     // int
  const size_t oTOK  = alloc(CAP_U);               // int
  const size_t oCNT  = alloc(64);                  // int: cnt2[8]|offs[9]
  const size_t oIE   = alloc((size_t)T_I * 256);
  const size_t oMOI  = alloc((size_t)T_I * 256);
  const size_t oITEM = alloc((size_t)T_I * 256);
  const size_t oQB   = alloc((size_t)T_I * 256);
  const size_t oOB   = alloc((size_t)T_I * 256);
  const size_t oTAW  = alloc((size_t)T_I * 256);
  const size_t oFUS  = alloc((size_t)T_I * 512);
  const size_t oFH   = alloc((size_t)T_I * 256);
  (void)oEXT;
  if (ws_size < o * sizeof(float)) {
    k_sentinel<<<1, 1, 0, stream>>>(out);
    return;
  }

  float* X    = W + oX;
  float* QKV  = W + oQKV;
  float* AO   = W + oAO;
  float* TMP  = W + oTMP;
  float* Hbuf = QKV;                               // spans A+B+C (>= CAP_U*512 floats)
  float* P0   = W + oP0;
  float* P1   = W + oP1;
  float* PI   = W + oPI;
  float* TWb  = W + oTW;
  float* WSb  = W + oWS;
  int*   TIb  = (int*)(W + oTI);
  int*   TOKb = (int*)(W + oTOK);
  int*   CNT  = (int*)(W + oCNT);
  int*   CNT2 = CNT;          // [0..7]
  int*   OFFS = CNT + 8;      // [8..16]
  float* IE   = W + oIE;
  float* MOI  = W + oMOI;
  float* ITEM = W + oITEM;
  float* QB   = W + oQB;
  float* OB   = W + oOB;
  float* TAW  = W + oTAW;
  float* FUS  = W + oFUS;
  float* FH   = W + oFH;
  float* Kbuf  = QKV;
  float* Vbuf  = QKV + (size_t)T_U * 256;
  float* HbufI = QKV + (size_t)2 * T_U * 256;

  // 1) embedding + rope
  k_embed_rope<<<T_U, 256, 0, stream>>>(history, item_emb, X);

  // 2) user transformer layers
  for (int l = 0; l < 2; ++l) {
    k_gemm<<<dim3(12, 200), 256, 0, stream>>>(X, ub_in_w + (size_t)l * 768 * 256,
        ub_in_b + (size_t)l * 768, QKV, T_U, 768, 256, 0);
    k_attn<<<512, 256, 0, stream>>>(QKV, AO);
    k_gemm<<<dim3(4, 200), 256, 0, stream>>>(AO, ub_out_w + (size_t)l * 256 * 256,
        ub_out_b + (size_t)l * 256, TMP, T_U, 256, 256, 0);
    k_ln<<<T_U, 256, 0, stream>>>(X, TMP, ub_n1_s + l * 256, ub_n1_b + l * 256, X);
    k_router<4><<<T_U / 4, 256, 0, stream>>>(X, T_U, ub_gate_w + (size_t)l * 4 * 256,
        ub_gate_b + l * 4, (l == 0) ? P0 : P1, TIb, TWb);
    k_count_scan<4><<<1, 256, 0, stream>>>(TIb, T_U, OFFS, CNT2, TOKb);
    k_fill<<<T_U / 256, 256, 0, stream>>>(TIb, TWb, T_U, OFFS, CNT2, TOKb, WSb);
    k_moe_gemm1<<<dim3(8, CAP_U / 64), 256, 0, stream>>>(X, TOKb, OFFS, 4,
        ub_e_w1 + (size_t)l * 4 * 512 * 256, ub_e_b1 + (size_t)l * 4 * 512, Hbuf);
    hipMemsetAsync(TMP, 0, (size_t)T_U * 256 * 4, stream);
    k_moe_gemm2<<<dim3(4, CAP_U / 64), 256, 0, stream>>>(Hbuf, TOKb, WSb, OFFS, 4,
        ub_e_w2 + (size_t)l * 4 * 256 * 512, ub_e_b2 + (size_t)l * 4 * 256, TMP);
    k_ln<<<T_U, 256, 0, stream>>>(X, TMP, ub_n2_s + l * 256, ub_n2_b + l * 256, X);
  }

  // 3) history final LN
  k_ln<<<T_U, 256, 0, stream>>>(X, nullptr, un_s, un_b, X);

  // 4) item tower
  k_item_embed<<<T_I, 256, 0, stream>>>(cand, catid, item_emb, cat_emb, IE);
  k_router<8><<<T_I / 4, 256, 0, stream>>>(IE, T_I, im_gate_w, im_gate_b, PI, TIb, TWb);
  k_count_scan<8><<<1, 256, 0, stream>>>(TIb, T_I, OFFS, CNT2, TOKb);
  k_fill<<<T_I / 256, 256, 0, stream>>>(TIb, TWb, T_I, OFFS, CNT2, TOKb, WSb);
  k_moe_gemm1<<<dim3(8, CAP_I / 64), 256, 0, stream>>>(IE, TOKb, OFFS, 8,
      im_e_w1, im_e_b1, HbufI);
  hipMemsetAsync(MOI, 0, (size_t)T_I * 256 * 4, stream);
  k_moe_gemm2<<<dim3(4, CAP_I / 64), 256, 0, stream>>>(HbufI, TOKb, WSb, OFFS, 8,
      im_e_w2, im_e_b2, MOI);
  k_ln<<<T_I, 256, 0, stream>>>(MOI, nullptr, in_s, in_b, ITEM);

  // 5) cross attention
  k_gemm<<<dim3(4, 16), 256, 0, stream>>>(ITEM, ca_in_w, ca_in_b, QB, T_I, 256, 256, 0);
  k_gemm<<<dim3(4, 200), 256, 0, stream>>>(X, ca_in_w + 256 * 256, ca_in_b + 256, Kbuf,
      T_U, 256, 256, 0);
  k_gemm<<<dim3(4, 200), 256, 0, stream>>>(X, ca_in_w + 512 * 256, ca_in_b + 512, Vbuf,
      T_U, 256, 256, 0);
  k_xattn<<<512, 256, 0, stream>>>(QB, Kbuf, Vbuf, OB);
  k_gemm<<<dim3(4, 16), 256, 0, stream>>>(OB, ca_out_w, ca_out_b, TAW, T_I, 256, 256, 0);

  // 6) fusion MLP + logits
  k_concat<<<(T_I * 512) / 256, 256, 0, stream>>>(TAW, ITEM, FUS, T_I * 512);
  k_gemm<<<dim3(4, 16), 256, 0, stream>>>(FUS, fm_w1, fm_b1, FH, T_I, 256, 512, 1);
  k_final<<<T_I / 4, 256, 0, stream>>>(FH, fm_w2, fm_b2, out, T_I);

  // 7) aux loss
  k_aux<<<1, 256, 0, stream>>>(P0, P1, PI, out + 1024);
}

// Round 3
// 1638.819 us; speedup vs baseline: 1.6327x; 1.1392x over previous
//
#include <hip/hip_runtime.h>
#include <cstddef>
#include <cstdint>

#define T_U   12800   // user tokens B*S
#define T_I   1024    // item tokens B*Nc
#define CAP_U 25856   // 2*T_U + 4*64 slot capacity (64-aligned per expert)
#define CAP_I 2560    // 2*T_I + 8*64

__device__ __forceinline__ float gelu_f(float x) {
  return 0.5f * x * (1.0f + erff(x * 0.7071067811865476f));
}

#define FMA16(a, b, acc)                                                        \
  acc[0][0] += a.x * b.x; acc[0][1] += a.x * b.y; acc[0][2] += a.x * b.z; acc[0][3] += a.x * b.w; \
  acc[1][0] += a.y * b.x; acc[1][1] += a.y * b.y; acc[1][2] += a.y * b.z; acc[1][3] += a.y * b.w; \
  acc[2][0] += a.z * b.x; acc[2][1] += a.z * b.y; acc[2][2] += a.z * b.z; acc[2][3] += a.z * b.w; \
  acc[3][0] += a.w * b.x; acc[3][1] += a.w * b.y; acc[3][2] += a.w * b.z; acc[3][3] += a.w * b.w;

// ---------------- sentinel (ws too small) ----------------
__global__ void k_sentinel(float* out) { out[0] = 1.0e9f; }

// ---------------- embedding + (faithful) RoPE ----------------
__global__ __launch_bounds__(256) void k_embed_rope(
    const int* __restrict__ hist, const float* __restrict__ emb, float* __restrict__ X)
{
  int t = blockIdx.x;            // b*200 + s
  int s = t % 200;
  int d = threadIdx.x;           // 0..255
  const float* row = emb + (size_t)hist[t] * 256;
  float x0 = row[d];
  float x1 = row[(d + 1) & 255];           // roll(x,-1)
  int fi = d & 127;
  float inv = expf(-9.210340371976184f * ((float)fi * (1.0f / 128.0f)));
  float ang = (float)s * inv;
  X[(size_t)t * 256 + d] = x0 * cosf(ang) + x1 * sinf(ang);
}

// ---------------- item embedding sum ----------------
__global__ __launch_bounds__(256) void k_item_embed(
    const int* __restrict__ cand, const int* __restrict__ catid,
    const float* __restrict__ item_emb, const float* __restrict__ cat_emb,
    float* __restrict__ IE)
{
  int t = blockIdx.x, d = threadIdx.x;
  IE[(size_t)t * 256 + d] =
      item_emb[(size_t)cand[t] * 256 + d] + cat_emb[(size_t)catid[t] * 256 + d];
}

// ---------------- generic GEMM: C[M,N] = act(A[M,K] @ W[N,K]^T + bias) ----------------
__global__ __launch_bounds__(256) void k_gemm(
    const float* __restrict__ A, const float* __restrict__ Wm,
    const float* __restrict__ bias, float* __restrict__ C,
    int M, int N, int K, int act)
{
  __shared__ float As[16][68];
  __shared__ float Ws[16][68];
  int tid = threadIdx.x;
  int row0 = blockIdx.y << 6;
  int col0 = blockIdx.x << 6;
  int lr = tid >> 2, lk = (tid & 3) << 2;
  int tx = tid & 15, ty = tid >> 4;
  const float* Aload = A + (size_t)(row0 + lr) * K + lk;
  const float* Wload = Wm + (size_t)(col0 + lr) * K + lk;
  float acc[4][4] = {};
  for (int k0 = 0; k0 < K; k0 += 16) {
    float4 av = *(const float4*)(Aload + k0);
    float4 wv = *(const float4*)(Wload + k0);
    As[lk][lr] = av.x; As[lk + 1][lr] = av.y; As[lk + 2][lr] = av.z; As[lk + 3][lr] = av.w;
    Ws[lk][lr] = wv.x; Ws[lk + 1][lr] = wv.y; Ws[lk + 2][lr] = wv.z; Ws[lk + 3][lr] = wv.w;
    __syncthreads();
#pragma unroll
    for (int k = 0; k < 16; ++k) {
      float4 a = *(const float4*)&As[k][ty << 2];
      float4 b = *(const float4*)&Ws[k][tx << 2];
      FMA16(a, b, acc);
    }
    __syncthreads();
  }
#pragma unroll
  for (int i = 0; i < 4; ++i) {
    int r = row0 + (ty << 2) + i;
    int c0 = col0 + (tx << 2);
    float4 v;
    v.x = acc[i][0]; v.y = acc[i][1]; v.z = acc[i][2]; v.w = acc[i][3];
    if (bias) { v.x += bias[c0]; v.y += bias[c0 + 1]; v.z += bias[c0 + 2]; v.w += bias[c0 + 3]; }
    if (act) { v.x = gelu_f(v.x); v.y = gelu_f(v.y); v.z = gelu_f(v.z); v.w = gelu_f(v.w); }
    *(float4*)(C + (size_t)r * N + c0) = v;
  }
}

// ---------------- MoE GEMM1: H[slot,512] = gelu(Xg[slot,256] @ W1_e^T + b1_e) ----------------
__global__ __launch_bounds__(256) void k_moe_gemm1(
    const float* __restrict__ Xsrc, const int* __restrict__ tok,
    const int* __restrict__ offs, int E,
    const float* __restrict__ W1, const float* __restrict__ b1,
    float* __restrict__ H)
{
  const int N = 512, K = 256;
  int row0 = blockIdx.y << 6;
  if (row0 >= offs[E]) return;
  int e = E - 1;
  while (e > 0 && offs[e] > row0) --e;
  const float* Wp = W1 + (size_t)e * N * K;
  const float* bp = b1 + (size_t)e * N;
  __shared__ float As[16][68];
  __shared__ float Ws[16][68];
  int tid = threadIdx.x;
  int col0 = blockIdx.x << 6;
  int lr = tid >> 2, lk = (tid & 3) << 2;
  int tx = tid & 15, ty = tid >> 4;
  int t = tok[row0 + lr];
  const float* Aload = (t >= 0) ? (Xsrc + (size_t)t * K + lk) : nullptr;
  const float* Wload = Wp + (size_t)(col0 + lr) * K + lk;
  float acc[4][4] = {};
  for (int k0 = 0; k0 < K; k0 += 16) {
    float4 av = Aload ? *(const float4*)(Aload + k0) : make_float4(0.f, 0.f, 0.f, 0.f);
    float4 wv = *(const float4*)(Wload + k0);
    As[lk][lr] = av.x; As[lk + 1][lr] = av.y; As[lk + 2][lr] = av.z; As[lk + 3][lr] = av.w;
    Ws[lk][lr] = wv.x; Ws[lk + 1][lr] = wv.y; Ws[lk + 2][lr] = wv.z; Ws[lk + 3][lr] = wv.w;
    __syncthreads();
#pragma unroll
    for (int k = 0; k < 16; ++k) {
      float4 a = *(const float4*)&As[k][ty << 2];
      float4 b = *(const float4*)&Ws[k][tx << 2];
      FMA16(a, b, acc);
    }
    __syncthreads();
  }
#pragma unroll
  for (int i = 0; i < 4; ++i) {
    int r = row0 + (ty << 2) + i;
    int c0 = col0 + (tx << 2);
    float4 v;
    v.x = gelu_f(acc[i][0] + bp[c0]);
    v.y = gelu_f(acc[i][1] + bp[c0 + 1]);
    v.z = gelu_f(acc[i][2] + bp[c0 + 2]);
    v.w = gelu_f(acc[i][3] + bp[c0 + 3]);
    *(float4*)(H + (size_t)r * N + c0) = v;
  }
}

// ---------------- MoE GEMM2: OUT[t,256] += w_slot * (H[slot,512] @ W2_e^T + b2_e) ----------------
__global__ __launch_bounds__(256) void k_moe_gemm2(
    const float* __restrict__ Hsrc, const int* __restrict__ tok,
    const float* __restrict__ wslot, const int* __restrict__ offs, int E,
    const float* __restrict__ W2, const float* __restrict__ b2,
    float* __restrict__ OUT)
{
  const int N = 256, K = 512;
  int row0 = blockIdx.y << 6;
  if (row0 >= offs[E]) return;
  int e = E - 1;
  while (e > 0 && offs[e] > row0) --e;
  const float* Wp = W2 + (size_t)e * N * K;
  const float* bp = b2 + (size_t)e * N;
  __shared__ float As[16][68];
  __shared__ float Ws[16][68];
  int tid = threadIdx.x;
  int col0 = blockIdx.x << 6;
  int lr = tid >> 2, lk = (tid & 3) << 2;
  int tx = tid & 15, ty = tid >> 4;
  const float* Aload = Hsrc + (size_t)(row0 + lr) * K + lk;
  const float* Wload = Wp + (size_t)(col0 + lr) * K + lk;
  float acc[4][4] = {};
  for (int k0 = 0; k0 < K; k0 += 16) {
    float4 av = *(const float4*)(Aload + k0);
    float4 wv = *(const float4*)(Wload + k0);
    As[lk][lr] = av.x; As[lk + 1][lr] = av.y; As[lk + 2][lr] = av.z; As[lk + 3][lr] = av.w;
    Ws[lk][lr] = wv.x; Ws[lk + 1][lr] = wv.y; Ws[lk + 2][lr] = wv.z; Ws[lk + 3][lr] = wv.w;
    __syncthreads();
#pragma unroll
    for (int k = 0; k < 16; ++k) {
      float4 a = *(const float4*)&As[k][ty << 2];
      float4 b = *(const float4*)&Ws[k][tx << 2];
      FMA16(a, b, acc);
    }
    __syncthreads();
  }
#pragma unroll
  for (int i = 0; i < 4; ++i) {
    int r = row0 + (ty << 2) + i;
    int t = tok[r];
    if (t < 0) continue;
    float wgt = wslot[r];
    int c0 = col0 + (tx << 2);
    float* orow = OUT + (size_t)t * N + c0;
    atomicAdd(orow + 0, wgt * (acc[i][0] + bp[c0]));
    atomicAdd(orow + 1, wgt * (acc[i][1] + bp[c0 + 1]));
    atomicAdd(orow + 2, wgt * (acc[i][2] + bp[c0 + 2]));
    atomicAdd(orow + 3, wgt * (acc[i][3] + bp[c0 + 3]));
  }
}

// ---------------- self-attention, one block per (b,h), float4 LDS ----------------
__global__ __launch_bounds__(256) void k_attn(const float* __restrict__ qkv, float* __restrict__ ao)
{
  __shared__ float4 Ks[1600];   // 200 x 8
  __shared__ float4 Vs[1600];
  int bh = blockIdx.x;
  int b = bh >> 3, h = bh & 7;
  const float* base = qkv + (size_t)b * 200 * 768;
  int tid = threadIdx.x;
  for (int i = tid; i < 1600; i += 256) {
    int s = i >> 3, d = i & 7;
    Ks[i] = *(const float4*)(base + s * 768 + 256 + h * 32 + d * 4);
    Vs[i] = *(const float4*)(base + s * 768 + 512 + h * 32 + d * 4);
  }
  __syncthreads();
  int q = tid;
  if (q >= 200) return;
  float4 qr[8];
  const float* qrow = base + q * 768 + h * 32;
#pragma unroll
  for (int d = 0; d < 8; ++d) qr[d] = *(const float4*)(qrow + d * 4);
  const float scale = 0.17677669529663687f;   // 1/sqrt(32)
  float m = -1e30f;
  for (int s = 0; s < 200; ++s) {
    float acc = 0.f;
#pragma unroll
    for (int d = 0; d < 8; ++d) {
      float4 kk = Ks[s * 8 + d];
      acc += qr[d].x * kk.x + qr[d].y * kk.y + qr[d].z * kk.z + qr[d].w * kk.w;
    }
    m = fmaxf(m, acc * scale);
  }
  float l = 0.f;
  float4 ov[8] = {};
  for (int s = 0; s < 200; ++s) {
    float acc = 0.f;
#pragma unroll
    for (int d = 0; d < 8; ++d) {
      float4 kk = Ks[s * 8 + d];
      acc += qr[d].x * kk.x + qr[d].y * kk.y + qr[d].z * kk.z + qr[d].w * kk.w;
    }
    float p = expf(acc * scale - m);
    l += p;
#pragma unroll
    for (int d = 0; d < 8; ++d) {
      float4 vv = Vs[s * 8 + d];
      ov[d].x += p * vv.x; ov[d].y += p * vv.y; ov[d].z += p * vv.z; ov[d].w += p * vv.w;
    }
  }
  float inv = 1.f / l;
  float* orow = ao + (size_t)(b * 200 + q) * 256 + h * 32;
#pragma unroll
  for (int d = 0; d < 8; ++d) {
    float4 v;
    v.x = ov[d].x * inv; v.y = ov[d].y * inv; v.z = ov[d].z * inv; v.w = ov[d].w * inv;
    *(float4*)(orow + d * 4) = v;
  }
}

// ---------------- cross-attention v2: phased, all 256 threads active ----------------
// block per (b,h). Phase1: 256 threads = (q, s-slice) compute 16x200 scores into LDS.
// Phase2: 16-wide max/sum reductions. Phase3: 128 threads = (q,d4) compute O = P.V.
__global__ __launch_bounds__(256) void k_xattn(
    const float* __restrict__ Q, const float* __restrict__ Kb,
    const float* __restrict__ Vb, float* __restrict__ O)
{
  __shared__ float4 Ks[200 * 9];      // row stride 9 float4 (anti-bank-conflict pad)
  __shared__ float4 Vs[200 * 9];
  __shared__ float4 Qs[16 * 9];
  __shared__ float  Sc[16 * 209];     // scores, row stride 209
  __shared__ float  red[16 * 16];
  __shared__ float  mq_s[16], linv_s[16];
  int bh = blockIdx.x;
  int b = bh >> 3, h = bh & 7;
  int tid = threadIdx.x;
  for (int i = tid; i < 1600; i += 256) {
    int s = i >> 3, d = i & 7;
    Ks[s * 9 + d] = *(const float4*)(Kb + (size_t)(b * 200 + s) * 256 + h * 32 + d * 4);
    Vs[s * 9 + d] = *(const float4*)(Vb + (size_t)(b * 200 + s) * 256 + h * 32 + d * 4);
  }
  if (tid < 128) {
    int q = tid >> 3, d = tid & 7;
    Qs[q * 9 + d] = *(const float4*)(Q + (size_t)(b * 16 + q) * 256 + h * 32 + d * 4);
  }
  __syncthreads();

  const float scale = 0.17677669529663687f;   // 1/sqrt(32)
  int q = tid >> 4, si = tid & 15;
  float4 qr[8];
#pragma unroll
  for (int d = 0; d < 8; ++d) qr[d] = Qs[q * 9 + d];
  float sc[13];
  float lm = -1e30f;
#pragma unroll
  for (int j = 0; j < 13; ++j) {
    int s = si + 16 * j;
    if (s < 200) {
      float acc = 0.f;
#pragma unroll
      for (int d = 0; d < 8; ++d) {
        float4 kk = Ks[s * 9 + d];
        acc += qr[d].x * kk.x + qr[d].y * kk.y + qr[d].z * kk.z + qr[d].w * kk.w;
      }
      float v = acc * scale;
      sc[j] = v;
      lm = fmaxf(lm, v);
    }
  }
  red[q * 16 + si] = lm;
  __syncthreads();
  if (tid < 16) {
    float m = red[tid * 16];
#pragma unroll
    for (int k = 1; k < 16; ++k) m = fmaxf(m, red[tid * 16 + k]);
    mq_s[tid] = m;
  }
  __syncthreads();
  float mq = mq_s[q];
  float ls = 0.f;
#pragma unroll
  for (int j = 0; j < 13; ++j) {
    int s = si + 16 * j;
    if (s < 200) {
      float e = expf(sc[j] - mq);
      Sc[q * 209 + s] = e;
      ls += e;
    }
  }
  red[q * 16 + si] = ls;
  __syncthreads();
  if (tid < 16) {
    float s = 0.f;
#pragma unroll
    for (int k = 0; k < 16; ++k) s += red[tid * 16 + k];
    linv_s[tid] = 1.f / s;
  }
  __syncthreads();
  if (tid < 128) {
    int qq = tid >> 3, dd = tid & 7;
    float4 o = make_float4(0.f, 0.f, 0.f, 0.f);
    const float* prow = &Sc[qq * 209];
    for (int s = 0; s < 200; ++s) {
      float p = prow[s];
      float4 vv = Vs[s * 9 + dd];
      o.x += p * vv.x; o.y += p * vv.y; o.z += p * vv.z; o.w += p * vv.w;
    }
    float inv = linv_s[qq];
    o.x *= inv; o.y *= inv; o.z *= inv; o.w *= inv;
    *(float4*)(O + (size_t)(b * 16 + qq) * 256 + h * 32 + dd * 4) = o;
  }
}

// ---------------- LayerNorm (optional residual), one block per token ----------------
__global__ __launch_bounds__(256) void k_ln(
    const float* __restrict__ Xin, const float* __restrict__ R,
    const float* __restrict__ sc, const float* __restrict__ bi, float* __restrict__ Y)
{
  int t = blockIdx.x, d = threadIdx.x;
  size_t idx = (size_t)t * 256 + d;
  float v = Xin[idx];
  if (R) v += R[idx];
  __shared__ float red[8];
  int lane = d & 63, wid = d >> 6;
  float s = v;
#pragma unroll
  for (int off = 32; off > 0; off >>= 1) s += __shfl_xor(s, off, 64);
  if (lane == 0) red[wid] = s;
  __syncthreads();
  float mean = (red[0] + red[1] + red[2] + red[3]) * 0.00390625f;
  float dv = v - mean;
  float s2 = dv * dv;
#pragma unroll
  for (int off = 32; off > 0; off >>= 1) s2 += __shfl_xor(s2, off, 64);
  if (lane == 0) red[4 + wid] = s2;
  __syncthreads();
  float var = (red[4] + red[5] + red[6] + red[7]) * 0.00390625f;
  Y[idx] = dv * (1.0f / sqrtf(var + 1e-5f)) * sc[d] + bi[d];
}

// ---------------- router: one wave per token (NO global atomics) ----------------
template <int E>
__global__ __launch_bounds__(256) void k_router(
    const float* __restrict__ X, int T,
    const float* __restrict__ gw, const float* __restrict__ gb,
    float* __restrict__ probs, int* __restrict__ ti, float* __restrict__ tw)
{
  int lane = threadIdx.x & 63, wid = threadIdx.x >> 6;
  int t = blockIdx.x * 4 + wid;
  if (t >= T) return;
  float4 x4 = *(const float4*)(X + (size_t)t * 256 + lane * 4);
  float p[E];
#pragma unroll
  for (int e = 0; e < E; ++e) {
    float4 g = *(const float4*)(gw + (size_t)e * 256 + lane * 4);
    float s = x4.x * g.x + x4.y * g.y + x4.z * g.z + x4.w * g.w;
#pragma unroll
    for (int off = 32; off > 0; off >>= 1) s += __shfl_xor(s, off, 64);
    p[e] = s + gb[e];
  }
  float m = p[0];
#pragma unroll
  for (int e = 1; e < E; ++e) m = fmaxf(m, p[e]);
  float sum = 0.f;
#pragma unroll
  for (int e = 0; e < E; ++e) { p[e] = expf(p[e] - m); sum += p[e]; }
  float inv = 1.f / sum;
#pragma unroll
  for (int e = 0; e < E; ++e) p[e] *= inv;
  if (lane < E) probs[(size_t)t * E + lane] = p[lane];
  if (lane == 0) {
    float v1 = p[0]; int i1 = 0;
#pragma unroll
    for (int e = 1; e < E; ++e) if (p[e] > v1) { v1 = p[e]; i1 = e; }
    float v2 = -1.f; int i2 = 0;
#pragma unroll
    for (int e = 0; e < E; ++e) if (e != i1 && p[e] > v2) { v2 = p[e]; i2 = e; }
    float s2 = v1 + v2;
    ti[t * 2] = i1; ti[t * 2 + 1] = i2;
    tw[t * 2] = v1 / s2; tw[t * 2 + 1] = v2 / s2;
  }
}

// ---------------- fused count + 64-aligned scan + padding init (one block) ----------------
template <int E>
__global__ __launch_bounds__(256) void k_count_scan(
    const int* __restrict__ ti, int T,
    int* __restrict__ offs, int* __restrict__ cnt2, int* __restrict__ tok)
{
  __shared__ int sc[8];
  __shared__ int soffs[9];
  __shared__ int scnt[8];
  int tid = threadIdx.x;
  if (tid < 8) { sc[tid] = 0; cnt2[tid] = 0; }
  __syncthreads();
  int c[E];
#pragma unroll
  for (int k = 0; k < E; ++k) c[k] = 0;
  for (int i = tid; i < 2 * T; i += 256) {
    int e = ti[i];
#pragma unroll
    for (int k = 0; k < E; ++k) c[k] += (e == k) ? 1 : 0;
  }
#pragma unroll
  for (int k = 0; k < E; ++k) {
    int v = c[k];
#pragma unroll
    for (int off = 32; off > 0; off >>= 1) v += __shfl_xor(v, off, 64);
    if ((tid & 63) == 0) atomicAdd(&sc[k], v);
  }
  __syncthreads();
  if (tid == 0) {
    int o = 0;
    for (int e = 0; e < E; ++e) {
      soffs[e] = o; scnt[e] = sc[e];
      o += (sc[e] + 63) & ~63;
    }
    soffs[E] = o;
  }
  __syncthreads();
  if (tid <= E) offs[tid] = soffs[tid];
  // -1 padding in the roundup tail of each expert region
  for (int e = 0; e < E; ++e) {
    int s0 = soffs[e] + scnt[e], s1 = soffs[e + 1];
    for (int i = s0 + tid; i < s1; i += 256) tok[i] = -1;
  }
}

// ---------------- fill expert slot lists (hierarchical, low-contention) ----------------
__global__ __launch_bounds__(256) void k_fill(
    const int* __restrict__ ti, const float* __restrict__ tw, int T,
    const int* __restrict__ offs, int* __restrict__ cnt2,
    int* __restrict__ tok, float* __restrict__ ws)
{
  __shared__ int lcnt[8];
  __shared__ int lbase[8];
  int tid = threadIdx.x;
  if (tid < 8) lcnt[tid] = 0;
  __syncthreads();
  int t = blockIdx.x * 256 + tid;
  int e0 = 0, e1 = 0, p0 = 0, p1 = 0;
  bool act = (t < T);
  if (act) {
    e0 = ti[t * 2]; e1 = ti[t * 2 + 1];
    p0 = atomicAdd(&lcnt[e0], 1);       // LDS atomic: cheap
    p1 = atomicAdd(&lcnt[e1], 1);
  }
  __syncthreads();
  if (tid < 8) lbase[tid] = atomicAdd(&cnt2[tid], lcnt[tid]);  // <=8 global atomics/block
  __syncthreads();
  if (act) {
    int s0 = offs[e0] + lbase[e0] + p0;
    tok[s0] = t; ws[s0] = tw[t * 2];
    int s1 = offs[e1] + lbase[e1] + p1;
    tok[s1] = t; ws[s1] = tw[t * 2 + 1];
  }
}

// ---------------- concat [taw | item] ----------------
__global__ __launch_bounds__(256) void k_concat(
    const float* __restrict__ A, const float* __restrict__ B, float* __restrict__ O, int total)
{
  int i = blockIdx.x * 256 + threadIdx.x;
  if (i >= total) return;
  int t = i >> 9, c = i & 511;
  O[i] = (c < 256) ? A[(size_t)t * 256 + c] : B[(size_t)t * 256 + c - 256];
}

// ---------------- final logits: dot(FH[t], fm_w2) + b ----------------
__global__ __launch_bounds__(256) void k_final(
    const float* __restrict__ FH, const float* __restrict__ w2,
    const float* __restrict__ b2, float* __restrict__ out, int T)
{
  int lane = threadIdx.x & 63, wid = threadIdx.x >> 6;
  int t = blockIdx.x * 4 + wid;
  if (t >= T) return;
  float4 h = *(const float4*)(FH + (size_t)t * 256 + lane * 4);
  float4 w = *(const float4*)(w2 + lane * 4);
  float s = h.x * w.x + h.y * w.y + h.z * w.z + h.w * w.w;
#pragma unroll
  for (int off = 32; off > 0; off >>= 1) s += __shfl_xor(s, off, 64);
  if (lane == 0) out[t] = s + b2[0];
}

// ---------------- aux load-balance loss (single block) ----------------
__global__ __launch_bounds__(256) void k_aux(
    const float* __restrict__ p0, const float* __restrict__ p1,
    const float* __restrict__ pi, float* __restrict__ out_aux)
{
  __shared__ float red[256];
  int tid = threadIdx.x;
  float aux = 0.f;
  for (int r = 0; r < 2; ++r) {
    const float* P = (r == 0) ? p0 : p1;
    float loc[4] = {0.f, 0.f, 0.f, 0.f};
    for (int t = tid; t < T_U; t += 256) {
#pragma unroll
      for (int e = 0; e < 4; ++e) loc[e] += P[t * 4 + e];
    }
    float contrib = 0.f;
    for (int e = 0; e < 4; ++e) {
      red[tid] = loc[e];
      __syncthreads();
      for (int s = 128; s > 0; s >>= 1) { if (tid < s) red[tid] += red[tid + s]; __syncthreads(); }
      if (tid == 0) { float d = red[0] * (1.f / T_U) - 0.125f; contrib += d * d; }
      __syncthreads();
    }
    if (tid == 0) aux += contrib * 0.25f;
  }
  {
    float loc[8] = {};
    for (int t = tid; t < T_I; t += 256) {
#pragma unroll
      for (int e = 0; e < 8; ++e) loc[e] += pi[t * 8 + e];
    }
    float contrib = 0.f;
    for (int e = 0; e < 8; ++e) {
      red[tid] = loc[e];
      __syncthreads();
      for (int s = 128; s > 0; s >>= 1) { if (tid < s) red[tid] += red[tid + s]; __syncthreads(); }
      if (tid == 0) { float d = red[0] * (1.f / T_I) - 0.125f; contrib += d * d; }
      __syncthreads();
    }
    if (tid == 0) aux += contrib * 0.125f;
  }
  if (tid == 0) *out_aux = aux;
}

// =======================================================================
extern "C" void kernel_launch(void* const* d_in, const int* in_sizes, int n_in,
                              void* d_out, int out_size, void* d_ws, size_t ws_size,
                              hipStream_t stream)
{
  (void)in_sizes; (void)n_in; (void)out_size;
  const int*   history  = (const int*)d_in[0];
  const int*   cand     = (const int*)d_in[1];
  const int*   catid    = (const int*)d_in[2];
  const float* item_emb = (const float*)d_in[3];
  const float* cat_emb  = (const float*)d_in[4];
  const float* ub_in_w  = (const float*)d_in[5];
  const float* ub_in_b  = (const float*)d_in[6];
  const float* ub_out_w = (const float*)d_in[7];
  const float* ub_out_b = (const float*)d_in[8];
  const float* ub_n1_s  = (const float*)d_in[9];
  const float* ub_n1_b  = (const float*)d_in[10];
  const float* ub_n2_s  = (const float*)d_in[11];
  const float* ub_n2_b  = (const float*)d_in[12];
  const float* ub_gate_w= (const float*)d_in[13];
  const float* ub_gate_b= (const float*)d_in[14];
  const float* ub_e_w1  = (const float*)d_in[15];
  const float* ub_e_b1  = (const float*)d_in[16];
  const float* ub_e_w2  = (const float*)d_in[17];
  const float* ub_e_b2  = (const float*)d_in[18];
  const float* un_s     = (const float*)d_in[19];
  const float* un_b     = (const float*)d_in[20];
  const float* im_gate_w= (const float*)d_in[21];
  const float* im_gate_b= (const float*)d_in[22];
  const float* im_e_w1  = (const float*)d_in[23];
  const float* im_e_b1  = (const float*)d_in[24];
  const float* im_e_w2  = (const float*)d_in[25];
  const float* im_e_b2  = (const float*)d_in[26];
  const float* in_s     = (const float*)d_in[27];
  const float* in_b     = (const float*)d_in[28];
  const float* ca_in_w  = (const float*)d_in[29];
  const float* ca_in_b  = (const float*)d_in[30];
  const float* ca_out_w = (const float*)d_in[31];
  const float* ca_out_b = (const float*)d_in[32];
  const float* fm_w1    = (const float*)d_in[33];
  const float* fm_b1    = (const float*)d_in[34];
  const float* fm_w2    = (const float*)d_in[35];
  const float* fm_b2    = (const float*)d_in[36];
  float* out = (float*)d_out;

  float* W = (float*)d_ws;
  size_t o = 0;
  auto alloc = [&](size_t n) { size_t r = o; o += (n + 63) & ~(size_t)63; return r; };
  const size_t oX    = alloc((size_t)T_U * 256);
  const size_t oQKV  = alloc((size_t)T_U * 768);   // region A (reused: Hbuf / Kbuf,Vbuf,HbufI)
  const size_t oAO   = alloc((size_t)T_U * 256);   // region B (Hbuf spillover)
  const size_t oEXT  = alloc(131072 + 64);         // region C (Hbuf tail)
  const size_t oTMP  = alloc((size_t)T_U * 256);
  const size_t oP0   = alloc((size_t)T_U * 4);
  const size_t oP1   = alloc((size_t)T_U * 4);
  const size_t oPI   = alloc((size_t)T_I * 8);
  const size_t oTW   = alloc((size_t)T_U * 2);
  const size_t oWS   = alloc(CAP_U);
  const size_t oTI   = alloc((size_t)T_U * 2);     // int
  const size_t oTOK  = alloc(CAP_U);               // int
  const size_t oCNT  = alloc(64);                  // int: cnt2[8]|offs[9]
  const size_t oIE   = alloc((size_t)T_I * 256);
  const size_t oMOI  = alloc((size_t)T_I * 256);
  const size_t oITEM = alloc((size_t)T_I * 256);
  const size_t oQB   = alloc((size_t)T_I * 256);
  const size_t oOB   = alloc((size_t)T_I * 256);
  const size_t oTAW  = alloc((size_t)T_I * 256);
  const size_t oFUS  = alloc((size_t)T_I * 512);
  const size_t oFH   = alloc((size_t)T_I * 256);
  (void)oEXT;
  if (ws_size < o * sizeof(float)) {
    k_sentinel<<<1, 1, 0, stream>>>(out);
    return;
  }

  float* X    = W + oX;
  float* QKV  = W + oQKV;
  float* AO   = W + oAO;
  float* TMP  = W + oTMP;
  float* Hbuf = QKV;                               // spans A+B+C (>= CAP_U*512 floats)
  float* P0   = W + oP0;
  float* P1   = W + oP1;
  float* PI   = W + oPI;
  float* TWb  = W + oTW;
  float* WSb  = W + oWS;
  int*   TIb  = (int*)(W + oTI);
  int*   TOKb = (int*)(W + oTOK);
  int*   CNT  = (int*)(W + oCNT);
  int*   CNT2 = CNT;          // [0..7]
  int*   OFFS = CNT + 8;      // [8..16]
  float* IE   = W + oIE;
  float* MOI  = W + oMOI;
  float* ITEM = W + oITEM;
  float* QB   = W + oQB;
  float* OB   = W + oOB;
  float* TAW  = W + oTAW;
  float* FUS  = W + oFUS;
  float* FH   = W + oFH;
  float* Kbuf  = QKV;
  float* Vbuf  = QKV + (size_t)T_U * 256;
  float* HbufI = QKV + (size_t)2 * T_U * 256;

  // 1) embedding + rope
  k_embed_rope<<<T_U, 256, 0, stream>>>(history, item_emb, X);

  // 2) user transformer layers
  for (int l = 0; l < 2; ++l) {
    k_gemm<<<dim3(12, 200), 256, 0, stream>>>(X, ub_in_w + (size_t)l * 768 * 256,
        ub_in_b + (size_t)l * 768, QKV, T_U, 768, 256, 0);
    k_attn<<<512, 256, 0, stream>>>(QKV, AO);
    k_gemm<<<dim3(4, 200), 256, 0, stream>>>(AO, ub_out_w + (size_t)l * 256 * 256,
        ub_out_b + (size_t)l * 256, TMP, T_U, 256, 256, 0);
    k_ln<<<T_U, 256, 0, stream>>>(X, TMP, ub_n1_s + l * 256, ub_n1_b + l * 256, X);
    k_router<4><<<T_U / 4, 256, 0, stream>>>(X, T_U, ub_gate_w + (size_t)l * 4 * 256,
        ub_gate_b + l * 4, (l == 0) ? P0 : P1, TIb, TWb);
    k_count_scan<4><<<1, 256, 0, stream>>>(TIb, T_U, OFFS, CNT2, TOKb);
    k_fill<<<T_U / 256, 256, 0, stream>>>(TIb, TWb, T_U, OFFS, CNT2, TOKb, WSb);
    k_moe_gemm1<<<dim3(8, CAP_U / 64), 256, 0, stream>>>(X, TOKb, OFFS, 4,
        ub_e_w1 + (size_t)l * 4 * 512 * 256, ub_e_b1 + (size_t)l * 4 * 512, Hbuf);
    hipMemsetAsync(TMP, 0, (size_t)T_U * 256 * 4, stream);
    k_moe_gemm2<<<dim3(4, CAP_U / 64), 256, 0, stream>>>(Hbuf, TOKb, WSb, OFFS, 4,
        ub_e_w2 + (size_t)l * 4 * 256 * 512, ub_e_b2 + (size_t)l * 4 * 256, TMP);
    k_ln<<<T_U, 256, 0, stream>>>(X, TMP, ub_n2_s + l * 256, ub_n2_b + l * 256, X);
  }

  // 3) history final LN
  k_ln<<<T_U, 256, 0, stream>>>(X, nullptr, un_s, un_b, X);

  // 4) item tower
  k_item_embed<<<T_I, 256, 0, stream>>>(cand, catid, item_emb, cat_emb, IE);
  k_router<8><<<T_I / 4, 256, 0, stream>>>(IE, T_I, im_gate_w, im_gate_b, PI, TIb, TWb);
  k_count_scan<8><<<1, 256, 0, stream>>>(TIb, T_I, OFFS, CNT2, TOKb);
  k_fill<<<T_I / 256, 256, 0, stream>>>(TIb, TWb, T_I, OFFS, CNT2, TOKb, WSb);
  k_moe_gemm1<<<dim3(8, CAP_I / 64), 256, 0, stream>>>(IE, TOKb, OFFS, 8,
      im_e_w1, im_e_b1, HbufI);
  hipMemsetAsync(MOI, 0, (size_t)T_I * 256 * 4, stream);
  k_moe_gemm2<<<dim3(4, CAP_I / 64), 256, 0, stream>>>(HbufI, TOKb, WSb, OFFS, 8,
      im_e_w2, im_e_b2, MOI);
  k_ln<<<T_I, 256, 0, stream>>>(MOI, nullptr, in_s, in_b, ITEM);

  // 5) cross attention
  k_gemm<<<dim3(4, 16), 256, 0, stream>>>(ITEM, ca_in_w, ca_in_b, QB, T_I, 256, 256, 0);
  k_gemm<<<dim3(4, 200), 256, 0, stream>>>(X, ca_in_w + 256 * 256, ca_in_b + 256, Kbuf,
      T_U, 256, 256, 0);
  k_gemm<<<dim3(4, 200), 256, 0, stream>>>(X, ca_in_w + 512 * 256, ca_in_b + 512, Vbuf,
      T_U, 256, 256, 0);
  k_xattn<<<512, 256, 0, stream>>>(QB, Kbuf, Vbuf, OB);
  k_gemm<<<dim3(4, 16), 256, 0, stream>>>(OB, ca_out_w, ca_out_b, TAW, T_I, 256, 256, 0);

  // 6) fusion MLP + logits
  k_concat<<<(T_I * 512) / 256, 256, 0, stream>>>(TAW, ITEM, FUS, T_I * 512);
  k_gemm<<<dim3(4, 16), 256, 0, stream>>>(FUS, fm_w1, fm_b1, FH, T_I, 256, 512, 1);
  k_final<<<T_I / 4, 256, 0, stream>>>(FH, fm_w2, fm_b2, out, T_I);

  // 7) aux loss
  k_aux<<<1, 256, 0, stream>>>(P0, P1, PI, out + 1024);
}

// Round 4
// 1603.660 us; speedup vs baseline: 1.6685x; 1.0219x over previous
//
#include <hip/hip_runtime.h>
#include <cstddef>
#include <cstdint>

#define T_U   12800   // user tokens B*S
#define T_I   1024    // item tokens B*Nc
#define CAP_U 25856   // 2*T_U + 4*64 slot capacity (64-aligned per expert)
#define CAP_I 2560    // 2*T_I + 8*64

__device__ __forceinline__ float gelu_f(float x) {
  return 0.5f * x * (1.0f + erff(x * 0.7071067811865476f));
}

#define FMA16(a, b, acc)                                                        \
  acc[0][0] += a.x * b.x; acc[0][1] += a.x * b.y; acc[0][2] += a.x * b.z; acc[0][3] += a.x * b.w; \
  acc[1][0] += a.y * b.x; acc[1][1] += a.y * b.y; acc[1][2] += a.y * b.z; acc[1][3] += a.y * b.w; \
  acc[2][0] += a.z * b.x; acc[2][1] += a.z * b.y; acc[2][2] += a.z * b.z; acc[2][3] += a.z * b.w; \
  acc[3][0] += a.w * b.x; acc[3][1] += a.w * b.y; acc[3][2] += a.w * b.z; acc[3][3] += a.w * b.w;

// ---------------- sentinel (ws too small) ----------------
__global__ void k_sentinel(float* out) { out[0] = 1.0e9f; }

// ---------------- embedding + (faithful) RoPE ----------------
__global__ __launch_bounds__(256) void k_embed_rope(
    const int* __restrict__ hist, const float* __restrict__ emb, float* __restrict__ X)
{
  int t = blockIdx.x;            // b*200 + s
  int s = t % 200;
  int d = threadIdx.x;           // 0..255
  const float* row = emb + (size_t)hist[t] * 256;
  float x0 = row[d];
  float x1 = row[(d + 1) & 255];           // roll(x,-1)
  int fi = d & 127;
  float inv = expf(-9.210340371976184f * ((float)fi * (1.0f / 128.0f)));
  float ang = (float)s * inv;
  X[(size_t)t * 256 + d] = x0 * cosf(ang) + x1 * sinf(ang);
}

// ---------------- item embedding sum ----------------
__global__ __launch_bounds__(256) void k_item_embed(
    const int* __restrict__ cand, const int* __restrict__ catid,
    const float* __restrict__ item_emb, const float* __restrict__ cat_emb,
    float* __restrict__ IE)
{
  int t = blockIdx.x, d = threadIdx.x;
  IE[(size_t)t * 256 + d] =
      item_emb[(size_t)cand[t] * 256 + d] + cat_emb[(size_t)catid[t] * 256 + d];
}

// ---------------- generic GEMM: C[M,N] = act(A[M,K] @ W[N,K]^T + bias) ----------------
__global__ __launch_bounds__(256) void k_gemm(
    const float* __restrict__ A, const float* __restrict__ Wm,
    const float* __restrict__ bias, float* __restrict__ C,
    int M, int N, int K, int act)
{
  __shared__ float As[16][68];
  __shared__ float Ws[16][68];
  int tid = threadIdx.x;
  int row0 = blockIdx.y << 6;
  int col0 = blockIdx.x << 6;
  int lr = tid >> 2, lk = (tid & 3) << 2;
  int tx = tid & 15, ty = tid >> 4;
  const float* Aload = A + (size_t)(row0 + lr) * K + lk;
  const float* Wload = Wm + (size_t)(col0 + lr) * K + lk;
  float acc[4][4] = {};
  for (int k0 = 0; k0 < K; k0 += 16) {
    float4 av = *(const float4*)(Aload + k0);
    float4 wv = *(const float4*)(Wload + k0);
    As[lk][lr] = av.x; As[lk + 1][lr] = av.y; As[lk + 2][lr] = av.z; As[lk + 3][lr] = av.w;
    Ws[lk][lr] = wv.x; Ws[lk + 1][lr] = wv.y; Ws[lk + 2][lr] = wv.z; Ws[lk + 3][lr] = wv.w;
    __syncthreads();
#pragma unroll
    for (int k = 0; k < 16; ++k) {
      float4 a = *(const float4*)&As[k][ty << 2];
      float4 b = *(const float4*)&Ws[k][tx << 2];
      FMA16(a, b, acc);
    }
    __syncthreads();
  }
#pragma unroll
  for (int i = 0; i < 4; ++i) {
    int r = row0 + (ty << 2) + i;
    int c0 = col0 + (tx << 2);
    float4 v;
    v.x = acc[i][0]; v.y = acc[i][1]; v.z = acc[i][2]; v.w = acc[i][3];
    if (bias) { v.x += bias[c0]; v.y += bias[c0 + 1]; v.z += bias[c0 + 2]; v.w += bias[c0 + 3]; }
    if (act) { v.x = gelu_f(v.x); v.y = gelu_f(v.y); v.z = gelu_f(v.z); v.w = gelu_f(v.w); }
    *(float4*)(C + (size_t)r * N + c0) = v;
  }
}

// ---------------- MoE GEMM, 64 rows x 256 cols per block ----------------
// Out[r, col0+c] = act(A[r or tok[r], :K] @ W_e[col,:K]^T + b_e[col]); plain stores.
// tok==nullptr -> dense row indexing (gemm2). outStride allows writing Y into H's
// col 0:256 (stride 512) after the K-loop consumed the row (row-block exclusive).
__global__ __launch_bounds__(256) void k_moe_mm(
    const float* __restrict__ A, const int* __restrict__ tok,
    const int* __restrict__ offs, int E,
    const float* __restrict__ Wm, const float* __restrict__ bias,
    float* __restrict__ Out, int N, int K, int outStride, int act)
{
  int row0 = blockIdx.y << 6;
  if (row0 >= offs[E]) return;
  int e = E - 1;
  while (e > 0 && offs[e] > row0) --e;
  const float* Wp = Wm + (size_t)e * N * K;
  const float* bp = bias + (size_t)e * N;
  int col0 = blockIdx.x << 8;
  __shared__ float As[16][68];
  __shared__ float Ws[16][260];
  int tid = threadIdx.x;
  int lr = tid >> 2, lk = (tid & 3) << 2;
  int tx = tid & 15, ty = tid >> 4;
  const float* Aload;
  if (tok) {
    int t = tok[row0 + lr];
    Aload = (t >= 0) ? (A + (size_t)t * K + lk) : nullptr;
  } else {
    Aload = A + (size_t)(row0 + lr) * K + lk;
  }
  const float* Wl = Wp + (size_t)(col0 + lr) * K + lk;
  float acc[4][4][4] = {};     // [colgroup j][row i][col c]
  for (int k0 = 0; k0 < K; k0 += 16) {
    float4 av = Aload ? *(const float4*)(Aload + k0) : make_float4(0.f, 0.f, 0.f, 0.f);
    float4 w0 = *(const float4*)(Wl + k0);
    float4 w1 = *(const float4*)(Wl + (size_t)64 * K + k0);
    float4 w2 = *(const float4*)(Wl + (size_t)128 * K + k0);
    float4 w3 = *(const float4*)(Wl + (size_t)192 * K + k0);
    As[lk][lr] = av.x; As[lk + 1][lr] = av.y; As[lk + 2][lr] = av.z; As[lk + 3][lr] = av.w;
    Ws[lk][lr]       = w0.x; Ws[lk + 1][lr]       = w0.y; Ws[lk + 2][lr]       = w0.z; Ws[lk + 3][lr]       = w0.w;
    Ws[lk][lr + 64]  = w1.x; Ws[lk + 1][lr + 64]  = w1.y; Ws[lk + 2][lr + 64]  = w1.z; Ws[lk + 3][lr + 64]  = w1.w;
    Ws[lk][lr + 128] = w2.x; Ws[lk + 1][lr + 128] = w2.y; Ws[lk + 2][lr + 128] = w2.z; Ws[lk + 3][lr + 128] = w2.w;
    Ws[lk][lr + 192] = w3.x; Ws[lk + 1][lr + 192] = w3.y; Ws[lk + 2][lr + 192] = w3.z; Ws[lk + 3][lr + 192] = w3.w;
    __syncthreads();
#pragma unroll
    for (int k = 0; k < 16; ++k) {
      float4 a  = *(const float4*)&As[k][ty << 2];
      float4 b0 = *(const float4*)&Ws[k][(tx << 2)];
      float4 b1 = *(const float4*)&Ws[k][(tx << 2) + 64];
      float4 b2 = *(const float4*)&Ws[k][(tx << 2) + 128];
      float4 b3 = *(const float4*)&Ws[k][(tx << 2) + 192];
      FMA16(a, b0, acc[0]);
      FMA16(a, b1, acc[1]);
      FMA16(a, b2, acc[2]);
      FMA16(a, b3, acc[3]);
    }
    __syncthreads();
  }
#pragma unroll
  for (int j = 0; j < 4; ++j) {
    int c0 = col0 + (tx << 2) + (j << 6);
#pragma unroll
    for (int i = 0; i < 4; ++i) {
      int r = row0 + (ty << 2) + i;
      float4 v;
      v.x = acc[j][i][0] + bp[c0];
      v.y = acc[j][i][1] + bp[c0 + 1];
      v.z = acc[j][i][2] + bp[c0 + 2];
      v.w = acc[j][i][3] + bp[c0 + 3];
      if (act) { v.x = gelu_f(v.x); v.y = gelu_f(v.y); v.z = gelu_f(v.z); v.w = gelu_f(v.w); }
      *(float4*)(Out + (size_t)r * outStride + c0) = v;
    }
  }
}

// ---------------- self-attention, one block per (b,h), float4 LDS ----------------
__global__ __launch_bounds__(256) void k_attn(const float* __restrict__ qkv, float* __restrict__ ao)
{
  __shared__ float4 Ks[1600];   // 200 x 8
  __shared__ float4 Vs[1600];
  int bh = blockIdx.x;
  int b = bh >> 3, h = bh & 7;
  const float* base = qkv + (size_t)b * 200 * 768;
  int tid = threadIdx.x;
  for (int i = tid; i < 1600; i += 256) {
    int s = i >> 3, d = i & 7;
    Ks[i] = *(const float4*)(base + s * 768 + 256 + h * 32 + d * 4);
    Vs[i] = *(const float4*)(base + s * 768 + 512 + h * 32 + d * 4);
  }
  __syncthreads();
  int q = tid;
  if (q >= 200) return;
  float4 qr[8];
  const float* qrow = base + q * 768 + h * 32;
#pragma unroll
  for (int d = 0; d < 8; ++d) qr[d] = *(const float4*)(qrow + d * 4);
  const float scale = 0.17677669529663687f;   // 1/sqrt(32)
  float m = -1e30f;
  for (int s = 0; s < 200; ++s) {
    float acc = 0.f;
#pragma unroll
    for (int d = 0; d < 8; ++d) {
      float4 kk = Ks[s * 8 + d];
      acc += qr[d].x * kk.x + qr[d].y * kk.y + qr[d].z * kk.z + qr[d].w * kk.w;
    }
    m = fmaxf(m, acc * scale);
  }
  float l = 0.f;
  float4 ov[8] = {};
  for (int s = 0; s < 200; ++s) {
    float acc = 0.f;
#pragma unroll
    for (int d = 0; d < 8; ++d) {
      float4 kk = Ks[s * 8 + d];
      acc += qr[d].x * kk.x + qr[d].y * kk.y + qr[d].z * kk.z + qr[d].w * kk.w;
    }
    float p = expf(acc * scale - m);
    l += p;
#pragma unroll
    for (int d = 0; d < 8; ++d) {
      float4 vv = Vs[s * 8 + d];
      ov[d].x += p * vv.x; ov[d].y += p * vv.y; ov[d].z += p * vv.z; ov[d].w += p * vv.w;
    }
  }
  float inv = 1.f / l;
  float* orow = ao + (size_t)(b * 200 + q) * 256 + h * 32;
#pragma unroll
  for (int d = 0; d < 8; ++d) {
    float4 v;
    v.x = ov[d].x * inv; v.y = ov[d].y * inv; v.z = ov[d].z * inv; v.w = ov[d].w * inv;
    *(float4*)(orow + d * 4) = v;
  }
}

// ---------------- cross-attention v2: phased, all 256 threads active ----------------
__global__ __launch_bounds__(256) void k_xattn(
    const float* __restrict__ Q, const float* __restrict__ Kb,
    const float* __restrict__ Vb, float* __restrict__ O)
{
  __shared__ float4 Ks[200 * 9];      // row stride 9 float4 (anti-bank-conflict pad)
  __shared__ float4 Vs[200 * 9];
  __shared__ float4 Qs[16 * 9];
  __shared__ float  Sc[16 * 209];     // scores, row stride 209
  __shared__ float  red[16 * 16];
  __shared__ float  mq_s[16], linv_s[16];
  int bh = blockIdx.x;
  int b = bh >> 3, h = bh & 7;
  int tid = threadIdx.x;
  for (int i = tid; i < 1600; i += 256) {
    int s = i >> 3, d = i & 7;
    Ks[s * 9 + d] = *(const float4*)(Kb + (size_t)(b * 200 + s) * 256 + h * 32 + d * 4);
    Vs[s * 9 + d] = *(const float4*)(Vb + (size_t)(b * 200 + s) * 256 + h * 32 + d * 4);
  }
  if (tid < 128) {
    int q = tid >> 3, d = tid & 7;
    Qs[q * 9 + d] = *(const float4*)(Q + (size_t)(b * 16 + q) * 256 + h * 32 + d * 4);
  }
  __syncthreads();

  const float scale = 0.17677669529663687f;   // 1/sqrt(32)
  int q = tid >> 4, si = tid & 15;
  float4 qr[8];
#pragma unroll
  for (int d = 0; d < 8; ++d) qr[d] = Qs[q * 9 + d];
  float sc[13];
  float lm = -1e30f;
#pragma unroll
  for (int j = 0; j < 13; ++j) {
    int s = si + 16 * j;
    if (s < 200) {
      float acc = 0.f;
#pragma unroll
      for (int d = 0; d < 8; ++d) {
        float4 kk = Ks[s * 9 + d];
        acc += qr[d].x * kk.x + qr[d].y * kk.y + qr[d].z * kk.z + qr[d].w * kk.w;
      }
      float v = acc * scale;
      sc[j] = v;
      lm = fmaxf(lm, v);
    }
  }
  red[q * 16 + si] = lm;
  __syncthreads();
  if (tid < 16) {
    float m = red[tid * 16];
#pragma unroll
    for (int k = 1; k < 16; ++k) m = fmaxf(m, red[tid * 16 + k]);
    mq_s[tid] = m;
  }
  __syncthreads();
  float mq = mq_s[q];
  float ls = 0.f;
#pragma unroll
  for (int j = 0; j < 13; ++j) {
    int s = si + 16 * j;
    if (s < 200) {
      float e = expf(sc[j] - mq);
      Sc[q * 209 + s] = e;
      ls += e;
    }
  }
  red[q * 16 + si] = ls;
  __syncthreads();
  if (tid < 16) {
    float s = 0.f;
#pragma unroll
    for (int k = 0; k < 16; ++k) s += red[tid * 16 + k];
    linv_s[tid] = 1.f / s;
  }
  __syncthreads();
  if (tid < 128) {
    int qq = tid >> 3, dd = tid & 7;
    float4 o = make_float4(0.f, 0.f, 0.f, 0.f);
    const float* prow = &Sc[qq * 209];
    for (int s = 0; s < 200; ++s) {
      float p = prow[s];
      float4 vv = Vs[s * 9 + dd];
      o.x += p * vv.x; o.y += p * vv.y; o.z += p * vv.z; o.w += p * vv.w;
    }
    float inv = linv_s[qq];
    o.x *= inv; o.y *= inv; o.z *= inv; o.w *= inv;
    *(float4*)(O + (size_t)(b * 16 + qq) * 256 + h * 32 + dd * 4) = o;
  }
}

// ---------------- LayerNorm (optional residual), one block per token ----------------
__global__ __launch_bounds__(256) void k_ln(
    const float* __restrict__ Xin, const float* __restrict__ R,
    const float* __restrict__ sc, const float* __restrict__ bi, float* __restrict__ Y)
{
  int t = blockIdx.x, d = threadIdx.x;
  size_t idx = (size_t)t * 256 + d;
  float v = Xin[idx];
  if (R) v += R[idx];
  __shared__ float red[8];
  int lane = d & 63, wid = d >> 6;
  float s = v;
#pragma unroll
  for (int off = 32; off > 0; off >>= 1) s += __shfl_xor(s, off, 64);
  if (lane == 0) red[wid] = s;
  __syncthreads();
  float mean = (red[0] + red[1] + red[2] + red[3]) * 0.00390625f;
  float dv = v - mean;
  float s2 = dv * dv;
#pragma unroll
  for (int off = 32; off > 0; off >>= 1) s2 += __shfl_xor(s2, off, 64);
  if (lane == 0) red[4 + wid] = s2;
  __syncthreads();
  float var = (red[4] + red[5] + red[6] + red[7]) * 0.00390625f;
  Y[idx] = dv * (1.0f / sqrtf(var + 1e-5f)) * sc[d] + bi[d];
}

// ---------------- fused MoE-combine + LayerNorm, one block per token ----------------
// v = (Xin? Xin[t,d]:0) + w0*Yb[s0*512+d] + w1*Yb[s1*512+d]; out = LN(v)
__global__ __launch_bounds__(256) void k_ln_comb(
    const float* __restrict__ Xin, const float* __restrict__ Yb,
    const int* __restrict__ slotmap, const float* __restrict__ tw,
    const float* __restrict__ sc, const float* __restrict__ bi, float* __restrict__ Y)
{
  int t = blockIdx.x, d = threadIdx.x;
  size_t idx = (size_t)t * 256 + d;
  int s0 = slotmap[2 * t], s1 = slotmap[2 * t + 1];
  float w0 = tw[2 * t], w1 = tw[2 * t + 1];
  float v = w0 * Yb[(size_t)s0 * 512 + d] + w1 * Yb[(size_t)s1 * 512 + d];
  if (Xin) v += Xin[idx];
  __shared__ float red[8];
  int lane = d & 63, wid = d >> 6;
  float s = v;
#pragma unroll
  for (int off = 32; off > 0; off >>= 1) s += __shfl_xor(s, off, 64);
  if (lane == 0) red[wid] = s;
  __syncthreads();
  float mean = (red[0] + red[1] + red[2] + red[3]) * 0.00390625f;
  float dv = v - mean;
  float s2 = dv * dv;
#pragma unroll
  for (int off = 32; off > 0; off >>= 1) s2 += __shfl_xor(s2, off, 64);
  if (lane == 0) red[4 + wid] = s2;
  __syncthreads();
  float var = (red[4] + red[5] + red[6] + red[7]) * 0.00390625f;
  Y[idx] = dv * (1.0f / sqrtf(var + 1e-5f)) * sc[d] + bi[d];
}

// ---------------- router: one wave per token (NO global atomics) ----------------
template <int E>
__global__ __launch_bounds__(256) void k_router(
    const float* __restrict__ X, int T,
    const float* __restrict__ gw, const float* __restrict__ gb,
    float* __restrict__ probs, int* __restrict__ ti, float* __restrict__ tw)
{
  int lane = threadIdx.x & 63, wid = threadIdx.x >> 6;
  int t = blockIdx.x * 4 + wid;
  if (t >= T) return;
  float4 x4 = *(const float4*)(X + (size_t)t * 256 + lane * 4);
  float p[E];
#pragma unroll
  for (int e = 0; e < E; ++e) {
    float4 g = *(const float4*)(gw + (size_t)e * 256 + lane * 4);
    float s = x4.x * g.x + x4.y * g.y + x4.z * g.z + x4.w * g.w;
#pragma unroll
    for (int off = 32; off > 0; off >>= 1) s += __shfl_xor(s, off, 64);
    p[e] = s + gb[e];
  }
  float m = p[0];
#pragma unroll
  for (int e = 1; e < E; ++e) m = fmaxf(m, p[e]);
  float sum = 0.f;
#pragma unroll
  for (int e = 0; e < E; ++e) { p[e] = expf(p[e] - m); sum += p[e]; }
  float inv = 1.f / sum;
#pragma unroll
  for (int e = 0; e < E; ++e) p[e] *= inv;
  if (lane < E) probs[(size_t)t * E + lane] = p[lane];
  if (lane == 0) {
    float v1 = p[0]; int i1 = 0;
#pragma unroll
    for (int e = 1; e < E; ++e) if (p[e] > v1) { v1 = p[e]; i1 = e; }
    float v2 = -1.f; int i2 = 0;
#pragma unroll
    for (int e = 0; e < E; ++e) if (e != i1 && p[e] > v2) { v2 = p[e]; i2 = e; }
    float s2 = v1 + v2;
    ti[t * 2] = i1; ti[t * 2 + 1] = i2;
    tw[t * 2] = v1 / s2; tw[t * 2 + 1] = v2 / s2;
  }
}

// ---------------- fused count + 64-aligned scan + padding init (one block) ----------------
template <int E>
__global__ __launch_bounds__(256) void k_count_scan(
    const int* __restrict__ ti, int T,
    int* __restrict__ offs, int* __restrict__ cnt2, int* __restrict__ tok)
{
  __shared__ int sc[8];
  __shared__ int soffs[9];
  __shared__ int scnt[8];
  int tid = threadIdx.x;
  if (tid < 8) { sc[tid] = 0; cnt2[tid] = 0; }
  __syncthreads();
  int c[E];
#pragma unroll
  for (int k = 0; k < E; ++k) c[k] = 0;
  for (int i = tid; i < 2 * T; i += 256) {
    int e = ti[i];
#pragma unroll
    for (int k = 0; k < E; ++k) c[k] += (e == k) ? 1 : 0;
  }
#pragma unroll
  for (int k = 0; k < E; ++k) {
    int v = c[k];
#pragma unroll
    for (int off = 32; off > 0; off >>= 1) v += __shfl_xor(v, off, 64);
    if ((tid & 63) == 0) atomicAdd(&sc[k], v);
  }
  __syncthreads();
  if (tid == 0) {
    int o = 0;
    for (int e = 0; e < E; ++e) {
      soffs[e] = o; scnt[e] = sc[e];
      o += (sc[e] + 63) & ~63;
    }
    soffs[E] = o;
  }
  __syncthreads();
  if (tid <= E) offs[tid] = soffs[tid];
  // -1 padding in the roundup tail of each expert region
  for (int e = 0; e < E; ++e) {
    int s0 = soffs[e] + scnt[e], s1 = soffs[e + 1];
    for (int i = s0 + tid; i < s1; i += 256) tok[i] = -1;
  }
}

// ---------------- fill expert slot lists + token->slot map ----------------
__global__ __launch_bounds__(256) void k_fill(
    const int* __restrict__ ti, int T,
    const int* __restrict__ offs, int* __restrict__ cnt2,
    int* __restrict__ tok, int* __restrict__ slotmap)
{
  __shared__ int lcnt[8];
  __shared__ int lbase[8];
  int tid = threadIdx.x;
  if (tid < 8) lcnt[tid] = 0;
  __syncthreads();
  int t = blockIdx.x * 256 + tid;
  int e0 = 0, e1 = 0, p0 = 0, p1 = 0;
  bool act = (t < T);
  if (act) {
    e0 = ti[t * 2]; e1 = ti[t * 2 + 1];
    p0 = atomicAdd(&lcnt[e0], 1);       // LDS atomic: cheap
    p1 = atomicAdd(&lcnt[e1], 1);
  }
  __syncthreads();
  if (tid < 8) lbase[tid] = atomicAdd(&cnt2[tid], lcnt[tid]);  // <=8 global atomics/block
  __syncthreads();
  if (act) {
    int s0 = offs[e0] + lbase[e0] + p0;
    tok[s0] = t; slotmap[t * 2] = s0;
    int s1 = offs[e1] + lbase[e1] + p1;
    tok[s1] = t; slotmap[t * 2 + 1] = s1;
  }
}

// ---------------- concat [taw | item] ----------------
__global__ __launch_bounds__(256) void k_concat(
    const float* __restrict__ A, const float* __restrict__ B, float* __restrict__ O, int total)
{
  int i = blockIdx.x * 256 + threadIdx.x;
  if (i >= total) return;
  int t = i >> 9, c = i & 511;
  O[i] = (c < 256) ? A[(size_t)t * 256 + c] : B[(size_t)t * 256 + c - 256];
}

// ---------------- final logits: dot(FH[t], fm_w2) + b ----------------
__global__ __launch_bounds__(256) void k_final(
    const float* __restrict__ FH, const float* __restrict__ w2,
    const float* __restrict__ b2, float* __restrict__ out, int T)
{
  int lane = threadIdx.x & 63, wid = threadIdx.x >> 6;
  int t = blockIdx.x * 4 + wid;
  if (t >= T) return;
  float4 h = *(const float4*)(FH + (size_t)t * 256 + lane * 4);
  float4 w = *(const float4*)(w2 + lane * 4);
  float s = h.x * w.x + h.y * w.y + h.z * w.z + h.w * w.w;
#pragma unroll
  for (int off = 32; off > 0; off >>= 1) s += __shfl_xor(s, off, 64);
  if (lane == 0) out[t] = s + b2[0];
}

// ---------------- aux load-balance loss (single block) ----------------
__global__ __launch_bounds__(256) void k_aux(
    const float* __restrict__ p0, const float* __restrict__ p1,
    const float* __restrict__ pi, float* __restrict__ out_aux)
{
  __shared__ float red[256];
  int tid = threadIdx.x;
  float aux = 0.f;
  for (int r = 0; r < 2; ++r) {
    const float* P = (r == 0) ? p0 : p1;
    float loc[4] = {0.f, 0.f, 0.f, 0.f};
    for (int t = tid; t < T_U; t += 256) {
#pragma unroll
      for (int e = 0; e < 4; ++e) loc[e] += P[t * 4 + e];
    }
    float contrib = 0.f;
    for (int e = 0; e < 4; ++e) {
      red[tid] = loc[e];
      __syncthreads();
      for (int s = 128; s > 0; s >>= 1) { if (tid < s) red[tid] += red[tid + s]; __syncthreads(); }
      if (tid == 0) { float d = red[0] * (1.f / T_U) - 0.125f; contrib += d * d; }
      __syncthreads();
    }
    if (tid == 0) aux += contrib * 0.25f;
  }
  {
    float loc[8] = {};
    for (int t = tid; t < T_I; t += 256) {
#pragma unroll
      for (int e = 0; e < 8; ++e) loc[e] += pi[t * 8 + e];
    }
    float contrib = 0.f;
    for (int e = 0; e < 8; ++e) {
      red[tid] = loc[e];
      __syncthreads();
      for (int s = 128; s > 0; s >>= 1) { if (tid < s) red[tid] += red[tid + s]; __syncthreads(); }
      if (tid == 0) { float d = red[0] * (1.f / T_I) - 0.125f; contrib += d * d; }
      __syncthreads();
    }
    if (tid == 0) aux += contrib * 0.125f;
  }
  if (tid == 0) *out_aux = aux;
}

// =======================================================================
extern "C" void kernel_launch(void* const* d_in, const int* in_sizes, int n_in,
                              void* d_out, int out_size, void* d_ws, size_t ws_size,
                              hipStream_t stream)
{
  (void)in_sizes; (void)n_in; (void)out_size;
  const int*   history  = (const int*)d_in[0];
  const int*   cand     = (const int*)d_in[1];
  const int*   catid    = (const int*)d_in[2];
  const float* item_emb = (const float*)d_in[3];
  const float* cat_emb  = (const float*)d_in[4];
  const float* ub_in_w  = (const float*)d_in[5];
  const float* ub_in_b  = (const float*)d_in[6];
  const float* ub_out_w = (const float*)d_in[7];
  const float* ub_out_b = (const float*)d_in[8];
  const float* ub_n1_s  = (const float*)d_in[9];
  const float* ub_n1_b  = (const float*)d_in[10];
  const float* ub_n2_s  = (const float*)d_in[11];
  const float* ub_n2_b  = (const float*)d_in[12];
  const float* ub_gate_w= (const float*)d_in[13];
  const float* ub_gate_b= (const float*)d_in[14];
  const float* ub_e_w1  = (const float*)d_in[15];
  const float* ub_e_b1  = (const float*)d_in[16];
  const float* ub_e_w2  = (const float*)d_in[17];
  const float* ub_e_b2  = (const float*)d_in[18];
  const float* un_s     = (const float*)d_in[19];
  const float* un_b     = (const float*)d_in[20];
  const float* im_gate_w= (const float*)d_in[21];
  const float* im_gate_b= (const float*)d_in[22];
  const float* im_e_w1  = (const float*)d_in[23];
  const float* im_e_b1  = (const float*)d_in[24];
  const float* im_e_w2  = (const float*)d_in[25];
  const float* im_e_b2  = (const float*)d_in[26];
  const float* in_s     = (const float*)d_in[27];
  const float* in_b     = (const float*)d_in[28];
  const float* ca_in_w  = (const float*)d_in[29];
  const float* ca_in_b  = (const float*)d_in[30];
  const float* ca_out_w = (const float*)d_in[31];
  const float* ca_out_b = (const float*)d_in[32];
  const float* fm_w1    = (const float*)d_in[33];
  const float* fm_b1    = (const float*)d_in[34];
  const float* fm_w2    = (const float*)d_in[35];
  const float* fm_b2    = (const float*)d_in[36];
  float* out = (float*)d_out;

  float* W = (float*)d_ws;
  size_t o = 0;
  auto alloc = [&](size_t n) { size_t r = o; o += (n + 63) & ~(size_t)63; return r; };
  const size_t oX    = alloc((size_t)T_U * 256);
  const size_t oQKV  = alloc((size_t)T_U * 768);   // region A (reused: Hbuf / Kbuf,Vbuf,HbufI)
  const size_t oAO   = alloc((size_t)T_U * 256);   // region B (Hbuf spillover)
  const size_t oEXT  = alloc(131072 + 64);         // region C (Hbuf tail)
  const size_t oTMP  = alloc((size_t)T_U * 256);
  const size_t oP0   = alloc((size_t)T_U * 4);
  const size_t oP1   = alloc((size_t)T_U * 4);
  const size_t oPI   = alloc((size_t)T_I * 8);
  const size_t oTW   = alloc((size_t)T_U * 2);
  const size_t oSM   = alloc((size_t)T_U * 2);     // int: token->slot map
  const size_t oTI   = alloc((size_t)T_U * 2);     // int
  const size_t oTOK  = alloc(CAP_U);               // int
  const size_t oCNT  = alloc(64);                  // int: cnt2[8]|offs[9]
  const size_t oIE   = alloc((size_t)T_I * 256);
  const size_t oITEM = alloc((size_t)T_I * 256);
  const size_t oQB   = alloc((size_t)T_I * 256);
  const size_t oOB   = alloc((size_t)T_I * 256);
  const size_t oTAW  = alloc((size_t)T_I * 256);
  const size_t oFUS  = alloc((size_t)T_I * 512);
  const size_t oFH   = alloc((size_t)T_I * 256);
  (void)oEXT;
  if (ws_size < o * sizeof(float)) {
    k_sentinel<<<1, 1, 0, stream>>>(out);
    return;
  }

  float* X    = W + oX;
  float* QKV  = W + oQKV;
  float* AO   = W + oAO;
  float* TMP  = W + oTMP;
  float* Hbuf = QKV;                               // spans A+B+C (>= CAP_U*512 floats)
  float* P0   = W + oP0;
  float* P1   = W + oP1;
  float* PI   = W + oPI;
  float* TWb  = W + oTW;
  int*   SLOT = (int*)(W + oSM);
  int*   TIb  = (int*)(W + oTI);
  int*   TOKb = (int*)(W + oTOK);
  int*   CNT  = (int*)(W + oCNT);
  int*   CNT2 = CNT;          // [0..7]
  int*   OFFS = CNT + 8;      // [8..16]
  float* IE   = W + oIE;
  float* ITEM = W + oITEM;
  float* QB   = W + oQB;
  float* OB   = W + oOB;
  float* TAW  = W + oTAW;
  float* FUS  = W + oFUS;
  float* FH   = W + oFH;
  float* Kbuf  = QKV;
  float* Vbuf  = QKV + (size_t)T_U * 256;
  float* HbufI = QKV + (size_t)2 * T_U * 256;
  (void)AO;

  // 1) embedding + rope
  k_embed_rope<<<T_U, 256, 0, stream>>>(history, item_emb, X);

  // 2) user transformer layers
  for (int l = 0; l < 2; ++l) {
    k_gemm<<<dim3(12, 200), 256, 0, stream>>>(X, ub_in_w + (size_t)l * 768 * 256,
        ub_in_b + (size_t)l * 768, QKV, T_U, 768, 256, 0);
    k_attn<<<512, 256, 0, stream>>>(QKV, W + oAO);
    k_gemm<<<dim3(4, 200), 256, 0, stream>>>(W + oAO, ub_out_w + (size_t)l * 256 * 256,
        ub_out_b + (size_t)l * 256, TMP, T_U, 256, 256, 0);
    k_ln<<<T_U, 256, 0, stream>>>(X, TMP, ub_n1_s + l * 256, ub_n1_b + l * 256, X);
    k_router<4><<<T_U / 4, 256, 0, stream>>>(X, T_U, ub_gate_w + (size_t)l * 4 * 256,
        ub_gate_b + l * 4, (l == 0) ? P0 : P1, TIb, TWb);
    k_count_scan<4><<<1, 256, 0, stream>>>(TIb, T_U, OFFS, CNT2, TOKb);
    k_fill<<<T_U / 256, 256, 0, stream>>>(TIb, T_U, OFFS, CNT2, TOKb, SLOT);
    // H[slot,0:512] = gelu(X[tok] @ W1^T + b1)
    k_moe_mm<<<dim3(2, CAP_U / 64), 256, 0, stream>>>(X, TOKb, OFFS, 4,
        ub_e_w1 + (size_t)l * 4 * 512 * 256, ub_e_b1 + (size_t)l * 4 * 512,
        Hbuf, 512, 256, 512, 1);
    // Y[slot,0:256] = H[slot] @ W2^T + b2  (stored into H cols 0:256, stride 512)
    k_moe_mm<<<dim3(1, CAP_U / 64), 256, 0, stream>>>(Hbuf, nullptr, OFFS, 4,
        ub_e_w2 + (size_t)l * 4 * 256 * 512, ub_e_b2 + (size_t)l * 4 * 256,
        Hbuf, 256, 512, 512, 0);
    k_ln_comb<<<T_U, 256, 0, stream>>>(X, Hbuf, SLOT, TWb,
        ub_n2_s + l * 256, ub_n2_b + l * 256, X);
  }

  // 3) history final LN
  k_ln<<<T_U, 256, 0, stream>>>(X, nullptr, un_s, un_b, X);

  // 4) item tower
  k_item_embed<<<T_I, 256, 0, stream>>>(cand, catid, item_emb, cat_emb, IE);
  k_router<8><<<T_I / 4, 256, 0, stream>>>(IE, T_I, im_gate_w, im_gate_b, PI, TIb, TWb);
  k_count_scan<8><<<1, 256, 0, stream>>>(TIb, T_I, OFFS, CNT2, TOKb);
  k_fill<<<T_I / 256, 256, 0, stream>>>(TIb, T_I, OFFS, CNT2, TOKb, SLOT);
  k_moe_mm<<<dim3(2, CAP_I / 64), 256, 0, stream>>>(IE, TOKb, OFFS, 8,
      im_e_w1, im_e_b1, HbufI, 512, 256, 512, 1);
  k_moe_mm<<<dim3(1, CAP_I / 64), 256, 0, stream>>>(HbufI, nullptr, OFFS, 8,
      im_e_w2, im_e_b2, HbufI, 256, 512, 512, 0);
  k_ln_comb<<<T_I, 256, 0, stream>>>(nullptr, HbufI, SLOT, TWb, in_s, in_b, ITEM);

  // 5) cross attention
  k_gemm<<<dim3(4, 16), 256, 0, stream>>>(ITEM, ca_in_w, ca_in_b, QB, T_I, 256, 256, 0);
  k_gemm<<<dim3(4, 200), 256, 0, stream>>>(X, ca_in_w + 256 * 256, ca_in_b + 256, Kbuf,
      T_U, 256, 256, 0);
  k_gemm<<<dim3(4, 200), 256, 0, stream>>>(X, ca_in_w + 512 * 256, ca_in_b + 512, Vbuf,
      T_U, 256, 256, 0);
  k_xattn<<<512, 256, 0, stream>>>(QB, Kbuf, Vbuf, OB);
  k_gemm<<<dim3(4, 16), 256, 0, stream>>>(OB, ca_out_w, ca_out_b, TAW, T_I, 256, 256, 0);

  // 6) fusion MLP + logits
  k_concat<<<(T_I * 512) / 256, 256, 0, stream>>>(TAW, ITEM, FUS, T_I * 512);
  k_gemm<<<dim3(4, 16), 256, 0, stream>>>(FUS, fm_w1, fm_b1, FH, T_I, 256, 512, 1);
  k_final<<<T_I / 4, 256, 0, stream>>>(FH, fm_w2, fm_b2, out, T_I);

  // 7) aux loss
  k_aux<<<1, 256, 0, stream>>>(P0, P1, PI, out + 1024);
}

// Round 5
// 1524.892 us; speedup vs baseline: 1.7547x; 1.0517x over previous
//
#include <hip/hip_runtime.h>
#include <cstddef>
#include <cstdint>

#define T_U   12800   // user tokens B*S
#define T_I   1024    // item tokens B*Nc
#define CAP_U 25856   // 2*T_U + 4*64 slot capacity (64-aligned per expert)
#define CAP_I 2560    // 2*T_I + 8*64

__device__ __forceinline__ float gelu_f(float x) {
  return 0.5f * x * (1.0f + erff(x * 0.7071067811865476f));
}

#define FMA16(a, b, acc)                                                        \
  acc[0][0] += a.x * b.x; acc[0][1] += a.x * b.y; acc[0][2] += a.x * b.z; acc[0][3] += a.x * b.w; \
  acc[1][0] += a.y * b.x; acc[1][1] += a.y * b.y; acc[1][2] += a.y * b.z; acc[1][3] += a.y * b.w; \
  acc[2][0] += a.z * b.x; acc[2][1] += a.z * b.y; acc[2][2] += a.z * b.z; acc[2][3] += a.z * b.w; \
  acc[3][0] += a.w * b.x; acc[3][1] += a.w * b.y; acc[3][2] += a.w * b.z; acc[3][3] += a.w * b.w;

// ---------------- sentinel (ws too small) ----------------
__global__ void k_sentinel(float* out) { out[0] = 1.0e9f; }

// ---------------- embedding + (faithful) RoPE ----------------
__global__ __launch_bounds__(256) void k_embed_rope(
    const int* __restrict__ hist, const float* __restrict__ emb, float* __restrict__ X)
{
  int t = blockIdx.x;            // b*200 + s
  int s = t % 200;
  int d = threadIdx.x;           // 0..255
  const float* row = emb + (size_t)hist[t] * 256;
  float x0 = row[d];
  float x1 = row[(d + 1) & 255];           // roll(x,-1)
  int fi = d & 127;
  float inv = expf(-9.210340371976184f * ((float)fi * (1.0f / 128.0f)));
  float ang = (float)s * inv;
  X[(size_t)t * 256 + d] = x0 * cosf(ang) + x1 * sinf(ang);
}

// ---------------- item embedding sum ----------------
__global__ __launch_bounds__(256) void k_item_embed(
    const int* __restrict__ cand, const int* __restrict__ catid,
    const float* __restrict__ item_emb, const float* __restrict__ cat_emb,
    float* __restrict__ IE)
{
  int t = blockIdx.x, d = threadIdx.x;
  IE[(size_t)t * 256 + d] =
      item_emb[(size_t)cand[t] * 256 + d] + cat_emb[(size_t)catid[t] * 256 + d];
}

// ---------------- generic GEMM: C[M,N] = act(A[M,K] @ W[N,K]^T + bias) ----------------
__global__ __launch_bounds__(256) void k_gemm(
    const float* __restrict__ A, const float* __restrict__ Wm,
    const float* __restrict__ bias, float* __restrict__ C,
    int M, int N, int K, int act)
{
  __shared__ float As[16][68];
  __shared__ float Ws[16][68];
  int tid = threadIdx.x;
  int row0 = blockIdx.y << 6;
  int col0 = blockIdx.x << 6;
  int lr = tid >> 2, lk = (tid & 3) << 2;
  int tx = tid & 15, ty = tid >> 4;
  const float* Aload = A + (size_t)(row0 + lr) * K + lk;
  const float* Wload = Wm + (size_t)(col0 + lr) * K + lk;
  float acc[4][4] = {};
  for (int k0 = 0; k0 < K; k0 += 16) {
    float4 av = *(const float4*)(Aload + k0);
    float4 wv = *(const float4*)(Wload + k0);
    As[lk][lr] = av.x; As[lk + 1][lr] = av.y; As[lk + 2][lr] = av.z; As[lk + 3][lr] = av.w;
    Ws[lk][lr] = wv.x; Ws[lk + 1][lr] = wv.y; Ws[lk + 2][lr] = wv.z; Ws[lk + 3][lr] = wv.w;
    __syncthreads();
#pragma unroll
    for (int k = 0; k < 16; ++k) {
      float4 a = *(const float4*)&As[k][ty << 2];
      float4 b = *(const float4*)&Ws[k][tx << 2];
      FMA16(a, b, acc);
    }
    __syncthreads();
  }
#pragma unroll
  for (int i = 0; i < 4; ++i) {
    int r = row0 + (ty << 2) + i;
    int c0 = col0 + (tx << 2);
    float4 v;
    v.x = acc[i][0]; v.y = acc[i][1]; v.z = acc[i][2]; v.w = acc[i][3];
    if (bias) { v.x += bias[c0]; v.y += bias[c0 + 1]; v.z += bias[c0 + 2]; v.w += bias[c0 + 3]; }
    if (act) { v.x = gelu_f(v.x); v.y = gelu_f(v.y); v.z = gelu_f(v.z); v.w = gelu_f(v.w); }
    *(float4*)(C + (size_t)r * N + c0) = v;
  }
}

// ---------------- MoE GEMM, 64 rows x 256 cols per block ----------------
__global__ __launch_bounds__(256) void k_moe_mm(
    const float* __restrict__ A, const int* __restrict__ tok,
    const int* __restrict__ offs, int E,
    const float* __restrict__ Wm, const float* __restrict__ bias,
    float* __restrict__ Out, int N, int K, int outStride, int act)
{
  int row0 = blockIdx.y << 6;
  if (row0 >= offs[E]) return;
  int e = E - 1;
  while (e > 0 && offs[e] > row0) --e;
  const float* Wp = Wm + (size_t)e * N * K;
  const float* bp = bias + (size_t)e * N;
  int col0 = blockIdx.x << 8;
  __shared__ float As[16][68];
  __shared__ float Ws[16][260];
  int tid = threadIdx.x;
  int lr = tid >> 2, lk = (tid & 3) << 2;
  int tx = tid & 15, ty = tid >> 4;
  const float* Aload;
  if (tok) {
    int t = tok[row0 + lr];
    Aload = (t >= 0) ? (A + (size_t)t * K + lk) : nullptr;
  } else {
    Aload = A + (size_t)(row0 + lr) * K + lk;
  }
  const float* Wl = Wp + (size_t)(col0 + lr) * K + lk;
  float acc[4][4][4] = {};     // [colgroup j][row i][col c]
  for (int k0 = 0; k0 < K; k0 += 16) {
    float4 av = Aload ? *(const float4*)(Aload + k0) : make_float4(0.f, 0.f, 0.f, 0.f);
    float4 w0 = *(const float4*)(Wl + k0);
    float4 w1 = *(const float4*)(Wl + (size_t)64 * K + k0);
    float4 w2 = *(const float4*)(Wl + (size_t)128 * K + k0);
    float4 w3 = *(const float4*)(Wl + (size_t)192 * K + k0);
    As[lk][lr] = av.x; As[lk + 1][lr] = av.y; As[lk + 2][lr] = av.z; As[lk + 3][lr] = av.w;
    Ws[lk][lr]       = w0.x; Ws[lk + 1][lr]       = w0.y; Ws[lk + 2][lr]       = w0.z; Ws[lk + 3][lr]       = w0.w;
    Ws[lk][lr + 64]  = w1.x; Ws[lk + 1][lr + 64]  = w1.y; Ws[lk + 2][lr + 64]  = w1.z; Ws[lk + 3][lr + 64]  = w1.w;
    Ws[lk][lr + 128] = w2.x; Ws[lk + 1][lr + 128] = w2.y; Ws[lk + 2][lr + 128] = w2.z; Ws[lk + 3][lr + 128] = w2.w;
    Ws[lk][lr + 192] = w3.x; Ws[lk + 1][lr + 192] = w3.y; Ws[lk + 2][lr + 192] = w3.z; Ws[lk + 3][lr + 192] = w3.w;
    __syncthreads();
#pragma unroll
    for (int k = 0; k < 16; ++k) {
      float4 a  = *(const float4*)&As[k][ty << 2];
      float4 b0 = *(const float4*)&Ws[k][(tx << 2)];
      float4 b1 = *(const float4*)&Ws[k][(tx << 2) + 64];
      float4 b2 = *(const float4*)&Ws[k][(tx << 2) + 128];
      float4 b3 = *(const float4*)&Ws[k][(tx << 2) + 192];
      FMA16(a, b0, acc[0]);
      FMA16(a, b1, acc[1]);
      FMA16(a, b2, acc[2]);
      FMA16(a, b3, acc[3]);
    }
    __syncthreads();
  }
#pragma unroll
  for (int j = 0; j < 4; ++j) {
    int c0 = col0 + (tx << 2) + (j << 6);
#pragma unroll
    for (int i = 0; i < 4; ++i) {
      int r = row0 + (ty << 2) + i;
      float4 v;
      v.x = acc[j][i][0] + bp[c0];
      v.y = acc[j][i][1] + bp[c0 + 1];
      v.z = acc[j][i][2] + bp[c0 + 2];
      v.w = acc[j][i][3] + bp[c0 + 3];
      if (act) { v.x = gelu_f(v.x); v.y = gelu_f(v.y); v.z = gelu_f(v.z); v.w = gelu_f(v.w); }
      *(float4*)(Out + (size_t)r * outStride + c0) = v;
    }
  }
}

// ---------------- self-attention v2: phased q-tiles, all 256 threads active ----------
// block per (b,h). 13 tiles of 16 queries. Phase1: (q,si) scores once into LDS;
// Phase2: 16-wide reductions; Phase3: (q,d4,s-half) PV with shfl combine.
__global__ __launch_bounds__(256) void k_attn(const float* __restrict__ qkv, float* __restrict__ ao)
{
  __shared__ float4 Ks[200 * 9];      // pad stride 9 float4
  __shared__ float4 Vs[200 * 9];
  __shared__ float4 Qs[16 * 9];
  __shared__ float  Sc[16 * 200];
  __shared__ float  red[16 * 16];
  __shared__ float  mq_s[16], linv_s[16];
  int bh = blockIdx.x;
  int b = bh >> 3, h = bh & 7;
  const float* base = qkv + (size_t)b * 200 * 768;
  int tid = threadIdx.x;
  for (int i = tid; i < 1600; i += 256) {
    int s = i >> 3, d = i & 7;
    Ks[s * 9 + d] = *(const float4*)(base + s * 768 + 256 + h * 32 + d * 4);
    Vs[s * 9 + d] = *(const float4*)(base + s * 768 + 512 + h * 32 + d * 4);
  }
  const float scale = 0.17677669529663687f;   // 1/sqrt(32)
  int ql = tid >> 4, si = tid & 15;
  int dd = (tid & 15) >> 1, sh = tid & 1;
  for (int tile = 0; tile < 13; ++tile) {
    __syncthreads();                     // staging done / Sc,Qs reuse fence
    if (tid < 128) {
      int q = tile * 16 + (tid >> 3), d = tid & 7;
      if (q < 200)
        Qs[(tid >> 3) * 9 + d] = *(const float4*)(base + q * 768 + h * 32 + d * 4);
    }
    __syncthreads();
    int qg = tile * 16 + ql;
    bool qa = qg < 200;
    float4 qr[8];
#pragma unroll
    for (int d = 0; d < 8; ++d) qr[d] = Qs[ql * 9 + d];
    float sc[13];
    float lm = -1e30f;
#pragma unroll
    for (int j = 0; j < 13; ++j) {
      int s = si + 16 * j;
      if (s < 200) {
        float acc = 0.f;
#pragma unroll
        for (int d = 0; d < 8; ++d) {
          float4 kk = Ks[s * 9 + d];
          acc += qr[d].x * kk.x + qr[d].y * kk.y + qr[d].z * kk.z + qr[d].w * kk.w;
        }
        float v = acc * scale;
        sc[j] = v;
        lm = fmaxf(lm, v);
      }
    }
    red[tid] = lm;
    __syncthreads();
    if (tid < 16) {
      float m = red[tid * 16];
#pragma unroll
      for (int k = 1; k < 16; ++k) m = fmaxf(m, red[tid * 16 + k]);
      mq_s[tid] = m;
    }
    __syncthreads();
    float mq = mq_s[ql];
    float ls = 0.f;
#pragma unroll
    for (int j = 0; j < 13; ++j) {
      int s = si + 16 * j;
      if (s < 200) {
        float e = expf(sc[j] - mq);
        Sc[ql * 200 + s] = e;
        ls += e;
      }
    }
    red[tid] = ls;
    __syncthreads();
    if (tid < 16) {
      float s = 0.f;
#pragma unroll
      for (int k = 0; k < 16; ++k) s += red[tid * 16 + k];
      linv_s[tid] = 1.f / s;
    }
    __syncthreads();
    // phase 3
    {
      const float* prow = &Sc[ql * 200];
      float4 o = make_float4(0.f, 0.f, 0.f, 0.f);
      int s0 = sh * 100;
#pragma unroll 4
      for (int s = s0; s < s0 + 100; ++s) {
        float p = prow[s];
        float4 vv = Vs[s * 9 + dd];
        o.x += p * vv.x; o.y += p * vv.y; o.z += p * vv.z; o.w += p * vv.w;
      }
      o.x += __shfl_xor(o.x, 1, 64);
      o.y += __shfl_xor(o.y, 1, 64);
      o.z += __shfl_xor(o.z, 1, 64);
      o.w += __shfl_xor(o.w, 1, 64);
      if (sh == 0 && qa) {
        float inv = linv_s[ql];
        float4 v;
        v.x = o.x * inv; v.y = o.y * inv; v.z = o.z * inv; v.w = o.w * inv;
        *(float4*)(ao + (size_t)(b * 200 + qg) * 256 + h * 32 + dd * 4) = v;
      }
    }
  }
}

// ---------------- cross-attention: phased, all 256 threads active ----------------
__global__ __launch_bounds__(256) void k_xattn(
    const float* __restrict__ Q, const float* __restrict__ Kb,
    const float* __restrict__ Vb, float* __restrict__ O)
{
  __shared__ float4 Ks[200 * 9];      // row stride 9 float4 (anti-bank-conflict pad)
  __shared__ float4 Vs[200 * 9];
  __shared__ float4 Qs[16 * 9];
  __shared__ float  Sc[16 * 209];     // scores, row stride 209
  __shared__ float  red[16 * 16];
  __shared__ float  mq_s[16], linv_s[16];
  int bh = blockIdx.x;
  int b = bh >> 3, h = bh & 7;
  int tid = threadIdx.x;
  for (int i = tid; i < 1600; i += 256) {
    int s = i >> 3, d = i & 7;
    Ks[s * 9 + d] = *(const float4*)(Kb + (size_t)(b * 200 + s) * 256 + h * 32 + d * 4);
    Vs[s * 9 + d] = *(const float4*)(Vb + (size_t)(b * 200 + s) * 256 + h * 32 + d * 4);
  }
  if (tid < 128) {
    int q = tid >> 3, d = tid & 7;
    Qs[q * 9 + d] = *(const float4*)(Q + (size_t)(b * 16 + q) * 256 + h * 32 + d * 4);
  }
  __syncthreads();

  const float scale = 0.17677669529663687f;   // 1/sqrt(32)
  int q = tid >> 4, si = tid & 15;
  float4 qr[8];
#pragma unroll
  for (int d = 0; d < 8; ++d) qr[d] = Qs[q * 9 + d];
  float sc[13];
  float lm = -1e30f;
#pragma unroll
  for (int j = 0; j < 13; ++j) {
    int s = si + 16 * j;
    if (s < 200) {
      float acc = 0.f;
#pragma unroll
      for (int d = 0; d < 8; ++d) {
        float4 kk = Ks[s * 9 + d];
        acc += qr[d].x * kk.x + qr[d].y * kk.y + qr[d].z * kk.z + qr[d].w * kk.w;
      }
      float v = acc * scale;
      sc[j] = v;
      lm = fmaxf(lm, v);
    }
  }
  red[q * 16 + si] = lm;
  __syncthreads();
  if (tid < 16) {
    float m = red[tid * 16];
#pragma unroll
    for (int k = 1; k < 16; ++k) m = fmaxf(m, red[tid * 16 + k]);
    mq_s[tid] = m;
  }
  __syncthreads();
  float mq = mq_s[q];
  float ls = 0.f;
#pragma unroll
  for (int j = 0; j < 13; ++j) {
    int s = si + 16 * j;
    if (s < 200) {
      float e = expf(sc[j] - mq);
      Sc[q * 209 + s] = e;
      ls += e;
    }
  }
  red[q * 16 + si] = ls;
  __syncthreads();
  if (tid < 16) {
    float s = 0.f;
#pragma unroll
    for (int k = 0; k < 16; ++k) s += red[tid * 16 + k];
    linv_s[tid] = 1.f / s;
  }
  __syncthreads();
  if (tid < 128) {
    int qq = tid >> 3, dd = tid & 7;
    float4 o = make_float4(0.f, 0.f, 0.f, 0.f);
    const float* prow = &Sc[qq * 209];
    for (int s = 0; s < 200; ++s) {
      float p = prow[s];
      float4 vv = Vs[s * 9 + dd];
      o.x += p * vv.x; o.y += p * vv.y; o.z += p * vv.z; o.w += p * vv.w;
    }
    float inv = linv_s[qq];
    o.x *= inv; o.y *= inv; o.z *= inv; o.w *= inv;
    *(float4*)(O + (size_t)(b * 16 + qq) * 256 + h * 32 + dd * 4) = o;
  }
}

// ---------------- LayerNorm (optional residual), one block per token ----------------
__global__ __launch_bounds__(256) void k_ln(
    const float* __restrict__ Xin, const float* __restrict__ R,
    const float* __restrict__ sc, const float* __restrict__ bi, float* __restrict__ Y)
{
  int t = blockIdx.x, d = threadIdx.x;
  size_t idx = (size_t)t * 256 + d;
  float v = Xin[idx];
  if (R) v += R[idx];
  __shared__ float red[8];
  int lane = d & 63, wid = d >> 6;
  float s = v;
#pragma unroll
  for (int off = 32; off > 0; off >>= 1) s += __shfl_xor(s, off, 64);
  if (lane == 0) red[wid] = s;
  __syncthreads();
  float mean = (red[0] + red[1] + red[2] + red[3]) * 0.00390625f;
  float dv = v - mean;
  float s2 = dv * dv;
#pragma unroll
  for (int off = 32; off > 0; off >>= 1) s2 += __shfl_xor(s2, off, 64);
  if (lane == 0) red[4 + wid] = s2;
  __syncthreads();
  float var = (red[4] + red[5] + red[6] + red[7]) * 0.00390625f;
  Y[idx] = dv * (1.0f / sqrtf(var + 1e-5f)) * sc[d] + bi[d];
}

// ---------------- fused MoE-combine + LayerNorm, one block per token ----------------
__global__ __launch_bounds__(256) void k_ln_comb(
    const float* __restrict__ Xin, const float* __restrict__ Yb,
    const int* __restrict__ slotmap, const float* __restrict__ tw,
    const float* __restrict__ sc, const float* __restrict__ bi, float* __restrict__ Y)
{
  int t = blockIdx.x, d = threadIdx.x;
  size_t idx = (size_t)t * 256 + d;
  int s0 = slotmap[2 * t], s1 = slotmap[2 * t + 1];
  float w0 = tw[2 * t], w1 = tw[2 * t + 1];
  float v = w0 * Yb[(size_t)s0 * 512 + d] + w1 * Yb[(size_t)s1 * 512 + d];
  if (Xin) v += Xin[idx];
  __shared__ float red[8];
  int lane = d & 63, wid = d >> 6;
  float s = v;
#pragma unroll
  for (int off = 32; off > 0; off >>= 1) s += __shfl_xor(s, off, 64);
  if (lane == 0) red[wid] = s;
  __syncthreads();
  float mean = (red[0] + red[1] + red[2] + red[3]) * 0.00390625f;
  float dv = v - mean;
  float s2 = dv * dv;
#pragma unroll
  for (int off = 32; off > 0; off >>= 1) s2 += __shfl_xor(s2, off, 64);
  if (lane == 0) red[4 + wid] = s2;
  __syncthreads();
  float var = (red[4] + red[5] + red[6] + red[7]) * 0.00390625f;
  Y[idx] = dv * (1.0f / sqrtf(var + 1e-5f)) * sc[d] + bi[d];
}

// ---------------- router: one wave per token (NO global atomics) ----------------
template <int E>
__global__ __launch_bounds__(256) void k_router(
    const float* __restrict__ X, int T,
    const float* __restrict__ gw, const float* __restrict__ gb,
    float* __restrict__ probs, int* __restrict__ ti, float* __restrict__ tw)
{
  int lane = threadIdx.x & 63, wid = threadIdx.x >> 6;
  int t = blockIdx.x * 4 + wid;
  if (t >= T) return;
  float4 x4 = *(const float4*)(X + (size_t)t * 256 + lane * 4);
  float p[E];
#pragma unroll
  for (int e = 0; e < E; ++e) {
    float4 g = *(const float4*)(gw + (size_t)e * 256 + lane * 4);
    float s = x4.x * g.x + x4.y * g.y + x4.z * g.z + x4.w * g.w;
#pragma unroll
    for (int off = 32; off > 0; off >>= 1) s += __shfl_xor(s, off, 64);
    p[e] = s + gb[e];
  }
  float m = p[0];
#pragma unroll
  for (int e = 1; e < E; ++e) m = fmaxf(m, p[e]);
  float sum = 0.f;
#pragma unroll
  for (int e = 0; e < E; ++e) { p[e] = expf(p[e] - m); sum += p[e]; }
  float inv = 1.f / sum;
#pragma unroll
  for (int e = 0; e < E; ++e) p[e] *= inv;
  if (lane < E) probs[(size_t)t * E + lane] = p[lane];
  if (lane == 0) {
    float v1 = p[0]; int i1 = 0;
#pragma unroll
    for (int e = 1; e < E; ++e) if (p[e] > v1) { v1 = p[e]; i1 = e; }
    float v2 = -1.f; int i2 = 0;
#pragma unroll
    for (int e = 0; e < E; ++e) if (e != i1 && p[e] > v2) { v2 = p[e]; i2 = e; }
    float s2 = v1 + v2;
    ti[t * 2] = i1; ti[t * 2 + 1] = i2;
    tw[t * 2] = v1 / s2; tw[t * 2 + 1] = v2 / s2;
  }
}

// ---------------- fused count + 64-aligned scan + padding init (one block) ----------------
template <int E>
__global__ __launch_bounds__(256) void k_count_scan(
    const int* __restrict__ ti, int T,
    int* __restrict__ offs, int* __restrict__ cnt2, int* __restrict__ tok)
{
  __shared__ int sc[8];
  __shared__ int soffs[9];
  __shared__ int scnt[8];
  int tid = threadIdx.x;
  if (tid < 8) { sc[tid] = 0; cnt2[tid] = 0; }
  __syncthreads();
  int c[E];
#pragma unroll
  for (int k = 0; k < E; ++k) c[k] = 0;
  for (int i = tid; i < 2 * T; i += 256) {
    int e = ti[i];
#pragma unroll
    for (int k = 0; k < E; ++k) c[k] += (e == k) ? 1 : 0;
  }
#pragma unroll
  for (int k = 0; k < E; ++k) {
    int v = c[k];
#pragma unroll
    for (int off = 32; off > 0; off >>= 1) v += __shfl_xor(v, off, 64);
    if ((tid & 63) == 0) atomicAdd(&sc[k], v);
  }
  __syncthreads();
  if (tid == 0) {
    int o = 0;
    for (int e = 0; e < E; ++e) {
      soffs[e] = o; scnt[e] = sc[e];
      o += (sc[e] + 63) & ~63;
    }
    soffs[E] = o;
  }
  __syncthreads();
  if (tid <= E) offs[tid] = soffs[tid];
  // -1 padding in the roundup tail of each expert region
  for (int e = 0; e < E; ++e) {
    int s0 = soffs[e] + scnt[e], s1 = soffs[e + 1];
    for (int i = s0 + tid; i < s1; i += 256) tok[i] = -1;
  }
}

// ---------------- fill expert slot lists + token->slot map ----------------
__global__ __launch_bounds__(256) void k_fill(
    const int* __restrict__ ti, int T,
    const int* __restrict__ offs, int* __restrict__ cnt2,
    int* __restrict__ tok, int* __restrict__ slotmap)
{
  __shared__ int lcnt[8];
  __shared__ int lbase[8];
  int tid = threadIdx.x;
  if (tid < 8) lcnt[tid] = 0;
  __syncthreads();
  int t = blockIdx.x * 256 + tid;
  int e0 = 0, e1 = 0, p0 = 0, p1 = 0;
  bool act = (t < T);
  if (act) {
    e0 = ti[t * 2]; e1 = ti[t * 2 + 1];
    p0 = atomicAdd(&lcnt[e0], 1);       // LDS atomic: cheap
    p1 = atomicAdd(&lcnt[e1], 1);
  }
  __syncthreads();
  if (tid < 8) lbase[tid] = atomicAdd(&cnt2[tid], lcnt[tid]);  // <=8 global atomics/block
  __syncthreads();
  if (act) {
    int s0 = offs[e0] + lbase[e0] + p0;
    tok[s0] = t; slotmap[t * 2] = s0;
    int s1 = offs[e1] + lbase[e1] + p1;
    tok[s1] = t; slotmap[t * 2 + 1] = s1;
  }
}

// ---------------- concat [taw | item] ----------------
__global__ __launch_bounds__(256) void k_concat(
    const float* __restrict__ A, const float* __restrict__ B, float* __restrict__ O, int total)
{
  int i = blockIdx.x * 256 + threadIdx.x;
  if (i >= total) return;
  int t = i >> 9, c = i & 511;
  O[i] = (c < 256) ? A[(size_t)t * 256 + c] : B[(size_t)t * 256 + c - 256];
}

// ---------------- final logits: dot(FH[t], fm_w2) + b ----------------
__global__ __launch_bounds__(256) void k_final(
    const float* __restrict__ FH, const float* __restrict__ w2,
    const float* __restrict__ b2, float* __restrict__ out, int T)
{
  int lane = threadIdx.x & 63, wid = threadIdx.x >> 6;
  int t = blockIdx.x * 4 + wid;
  if (t >= T) return;
  float4 h = *(const float4*)(FH + (size_t)t * 256 + lane * 4);
  float4 w = *(const float4*)(w2 + lane * 4);
  float s = h.x * w.x + h.y * w.y + h.z * w.z + h.w * w.w;
#pragma unroll
  for (int off = 32; off > 0; off >>= 1) s += __shfl_xor(s, off, 64);
  if (lane == 0) out[t] = s + b2[0];
}

// ---------------- aux load-balance loss (single block) ----------------
__global__ __launch_bounds__(256) void k_aux(
    const float* __restrict__ p0, const float* __restrict__ p1,
    const float* __restrict__ pi, float* __restrict__ out_aux)
{
  __shared__ float red[256];
  int tid = threadIdx.x;
  float aux = 0.f;
  for (int r = 0; r < 2; ++r) {
    const float* P = (r == 0) ? p0 : p1;
    float loc[4] = {0.f, 0.f, 0.f, 0.f};
    for (int t = tid; t < T_U; t += 256) {
#pragma unroll
      for (int e = 0; e < 4; ++e) loc[e] += P[t * 4 + e];
    }
    float contrib = 0.f;
    for (int e = 0; e < 4; ++e) {
      red[tid] = loc[e];
      __syncthreads();
      for (int s = 128; s > 0; s >>= 1) { if (tid < s) red[tid] += red[tid + s]; __syncthreads(); }
      if (tid == 0) { float d = red[0] * (1.f / T_U) - 0.125f; contrib += d * d; }
      __syncthreads();
    }
    if (tid == 0) aux += contrib * 0.25f;
  }
  {
    float loc[8] = {};
    for (int t = tid; t < T_I; t += 256) {
#pragma unroll
      for (int e = 0; e < 8; ++e) loc[e] += pi[t * 8 + e];
    }
    float contrib = 0.f;
    for (int e = 0; e < 8; ++e) {
      red[tid] = loc[e];
      __syncthreads();
      for (int s = 128; s > 0; s >>= 1) { if (tid < s) red[tid] += red[tid + s]; __syncthreads(); }
      if (tid == 0) { float d = red[0] * (1.f / T_I) - 0.125f; contrib += d * d; }
      __syncthreads();
    }
    if (tid == 0) aux += contrib * 0.125f;
  }
  if (tid == 0) *out_aux = aux;
}

// =======================================================================
extern "C" void kernel_launch(void* const* d_in, const int* in_sizes, int n_in,
                              void* d_out, int out_size, void* d_ws, size_t ws_size,
                              hipStream_t stream)
{
  (void)in_sizes; (void)n_in; (void)out_size;
  const int*   history  = (const int*)d_in[0];
  const int*   cand     = (const int*)d_in[1];
  const int*   catid    = (const int*)d_in[2];
  const float* item_emb = (const float*)d_in[3];
  const float* cat_emb  = (const float*)d_in[4];
  const float* ub_in_w  = (const float*)d_in[5];
  const float* ub_in_b  = (const float*)d_in[6];
  const float* ub_out_w = (const float*)d_in[7];
  const float* ub_out_b = (const float*)d_in[8];
  const float* ub_n1_s  = (const float*)d_in[9];
  const float* ub_n1_b  = (const float*)d_in[10];
  const float* ub_n2_s  = (const float*)d_in[11];
  const float* ub_n2_b  = (const float*)d_in[12];
  const float* ub_gate_w= (const float*)d_in[13];
  const float* ub_gate_b= (const float*)d_in[14];
  const float* ub_e_w1  = (const float*)d_in[15];
  const float* ub_e_b1  = (const float*)d_in[16];
  const float* ub_e_w2  = (const float*)d_in[17];
  const float* ub_e_b2  = (const float*)d_in[18];
  const float* un_s     = (const float*)d_in[19];
  const float* un_b     = (const float*)d_in[20];
  const float* im_gate_w= (const float*)d_in[21];
  const float* im_gate_b= (const float*)d_in[22];
  const float* im_e_w1  = (const float*)d_in[23];
  const float* im_e_b1  = (const float*)d_in[24];
  const float* im_e_w2  = (const float*)d_in[25];
  const float* im_e_b2  = (const float*)d_in[26];
  const float* in_s     = (const float*)d_in[27];
  const float* in_b     = (const float*)d_in[28];
  const float* ca_in_w  = (const float*)d_in[29];
  const float* ca_in_b  = (const float*)d_in[30];
  const float* ca_out_w = (const float*)d_in[31];
  const float* ca_out_b = (const float*)d_in[32];
  const float* fm_w1    = (const float*)d_in[33];
  const float* fm_b1    = (const float*)d_in[34];
  const float* fm_w2    = (const float*)d_in[35];
  const float* fm_b2    = (const float*)d_in[36];
  float* out = (float*)d_out;

  float* W = (float*)d_ws;
  size_t o = 0;
  auto alloc = [&](size_t n) { size_t r = o; o += (n + 63) & ~(size_t)63; return r; };
  const size_t oX    = alloc((size_t)T_U * 256);
  const size_t oQKV  = alloc((size_t)T_U * 768);   // region A (reused: Hbuf / Kbuf,Vbuf,HbufI)
  const size_t oAO   = alloc((size_t)T_U * 256);   // region B (Hbuf spillover)
  const size_t oEXT  = alloc(131072 + 64);         // region C (Hbuf tail)
  const size_t oTMP  = alloc((size_t)T_U * 256);
  const size_t oP0   = alloc((size_t)T_U * 4);
  const size_t oP1   = alloc((size_t)T_U * 4);
  const size_t oPI   = alloc((size_t)T_I * 8);
  const size_t oTW   = alloc((size_t)T_U * 2);
  const size_t oSM   = alloc((size_t)T_U * 2);     // int: token->slot map
  const size_t oTI   = alloc((size_t)T_U * 2);     // int
  const size_t oTOK  = alloc(CAP_U);               // int
  const size_t oCNT  = alloc(64);                  // int: cnt2[8]|offs[9]
  const size_t oIE   = alloc((size_t)T_I * 256);
  const size_t oITEM = alloc((size_t)T_I * 256);
  const size_t oQB   = alloc((size_t)T_I * 256);
  const size_t oOB   = alloc((size_t)T_I * 256);
  const size_t oTAW  = alloc((size_t)T_I * 256);
  const size_t oFUS  = alloc((size_t)T_I * 512);
  const size_t oFH   = alloc((size_t)T_I * 256);
  (void)oEXT;
  if (ws_size < o * sizeof(float)) {
    k_sentinel<<<1, 1, 0, stream>>>(out);
    return;
  }

  float* X    = W + oX;
  float* QKV  = W + oQKV;
  float* TMP  = W + oTMP;
  float* Hbuf = QKV;                               // spans A+B+C (>= CAP_U*512 floats)
  float* P0   = W + oP0;
  float* P1   = W + oP1;
  float* PI   = W + oPI;
  float* TWb  = W + oTW;
  int*   SLOT = (int*)(W + oSM);
  int*   TIb  = (int*)(W + oTI);
  int*   TOKb = (int*)(W + oTOK);
  int*   CNT  = (int*)(W + oCNT);
  int*   CNT2 = CNT;          // [0..7]
  int*   OFFS = CNT + 8;      // [8..16]
  float* IE   = W + oIE;
  float* ITEM = W + oITEM;
  float* QB   = W + oQB;
  float* OB   = W + oOB;
  float* TAW  = W + oTAW;
  float* FUS  = W + oFUS;
  float* FH   = W + oFH;
  float* Kbuf  = QKV;
  float* Vbuf  = QKV + (size_t)T_U * 256;
  float* HbufI = QKV + (size_t)2 * T_U * 256;

  // 1) embedding + rope
  k_embed_rope<<<T_U, 256, 0, stream>>>(history, item_emb, X);

  // 2) user transformer layers
  for (int l = 0; l < 2; ++l) {
    k_gemm<<<dim3(12, 200), 256, 0, stream>>>(X, ub_in_w + (size_t)l * 768 * 256,
        ub_in_b + (size_t)l * 768, QKV, T_U, 768, 256, 0);
    k_attn<<<512, 256, 0, stream>>>(QKV, W + oAO);
    k_gemm<<<dim3(4, 200), 256, 0, stream>>>(W + oAO, ub_out_w + (size_t)l * 256 * 256,
        ub_out_b + (size_t)l * 256, TMP, T_U, 256, 256, 0);
    k_ln<<<T_U, 256, 0, stream>>>(X, TMP, ub_n1_s + l * 256, ub_n1_b + l * 256, X);
    k_router<4><<<T_U / 4, 256, 0, stream>>>(X, T_U, ub_gate_w + (size_t)l * 4 * 256,
        ub_gate_b + l * 4, (l == 0) ? P0 : P1, TIb, TWb);
    k_count_scan<4><<<1, 256, 0, stream>>>(TIb, T_U, OFFS, CNT2, TOKb);
    k_fill<<<T_U / 256, 256, 0, stream>>>(TIb, T_U, OFFS, CNT2, TOKb, SLOT);
    // H[slot,0:512] = gelu(X[tok] @ W1^T + b1)
    k_moe_mm<<<dim3(2, CAP_U / 64), 256, 0, stream>>>(X, TOKb, OFFS, 4,
        ub_e_w1 + (size_t)l * 4 * 512 * 256, ub_e_b1 + (size_t)l * 4 * 512,
        Hbuf, 512, 256, 512, 1);
    // Y[slot,0:256] = H[slot] @ W2^T + b2  (stored into H cols 0:256, stride 512)
    k_moe_mm<<<dim3(1, CAP_U / 64), 256, 0, stream>>>(Hbuf, nullptr, OFFS, 4,
        ub_e_w2 + (size_t)l * 4 * 256 * 512, ub_e_b2 + (size_t)l * 4 * 256,
        Hbuf, 256, 512, 512, 0);
    k_ln_comb<<<T_U, 256, 0, stream>>>(X, Hbuf, SLOT, TWb,
        ub_n2_s + l * 256, ub_n2_b + l * 256, X);
  }

  // 3) history final LN
  k_ln<<<T_U, 256, 0, stream>>>(X, nullptr, un_s, un_b, X);

  // 4) item tower
  k_item_embed<<<T_I, 256, 0, stream>>>(cand, catid, item_emb, cat_emb, IE);
  k_router<8><<<T_I / 4, 256, 0, stream>>>(IE, T_I, im_gate_w, im_gate_b, PI, TIb, TWb);
  k_count_scan<8><<<1, 256, 0, stream>>>(TIb, T_I, OFFS, CNT2, TOKb);
  k_fill<<<T_I / 256, 256, 0, stream>>>(TIb, T_I, OFFS, CNT2, TOKb, SLOT);
  k_moe_mm<<<dim3(2, CAP_I / 64), 256, 0, stream>>>(IE, TOKb, OFFS, 8,
      im_e_w1, im_e_b1, HbufI, 512, 256, 512, 1);
  k_moe_mm<<<dim3(1, CAP_I / 64), 256, 0, stream>>>(HbufI, nullptr, OFFS, 8,
      im_e_w2, im_e_b2, HbufI, 256, 512, 512, 0);
  k_ln_comb<<<T_I, 256, 0, stream>>>(nullptr, HbufI, SLOT, TWb, in_s, in_b, ITEM);

  // 5) cross attention
  k_gemm<<<dim3(4, 16), 256, 0, stream>>>(ITEM, ca_in_w, ca_in_b, QB, T_I, 256, 256, 0);
  k_gemm<<<dim3(4, 200), 256, 0, stream>>>(X, ca_in_w + 256 * 256, ca_in_b + 256, Kbuf,
      T_U, 256, 256, 0);
  k_gemm<<<dim3(4, 200), 256, 0, stream>>>(X, ca_in_w + 512 * 256, ca_in_b + 512, Vbuf,
      T_U, 256, 256, 0);
  k_xattn<<<512, 256, 0, stream>>>(QB, Kbuf, Vbuf, OB);
  k_gemm<<<dim3(4, 16), 256, 0, stream>>>(OB, ca_out_w, ca_out_b, TAW, T_I, 256, 256, 0);

  // 6) fusion MLP + logits
  k_concat<<<(T_I * 512) / 256, 256, 0, stream>>>(TAW, ITEM, FUS, T_I * 512);
  k_gemm<<<dim3(4, 16), 256, 0, stream>>>(FUS, fm_w1, fm_b1, FH, T_I, 256, 512, 1);
  k_final<<<T_I / 4, 256, 0, stream>>>(FH, fm_w2, fm_b2, out, T_I);

  // 7) aux loss
  k_aux<<<1, 256, 0, stream>>>(P0, P1, PI, out + 1024);
}

// Round 7
// 1129.329 us; speedup vs baseline: 2.3693x; 1.3503x over previous
//
#include <hip/hip_runtime.h>
#include <cstddef>
#include <cstdint>

#define T_U   12800   // user tokens B*S
#define T_I   1024    // item tokens B*Nc
#define CAP_U 26112   // 2*T_U + 4*128 slot capacity (128-aligned per expert)
#define CAP_I 3072    // 2*T_I + 8*128

using short8 = __attribute__((ext_vector_type(8))) short;   // 8 bf16 (4 VGPRs)
using f32x4  = __attribute__((ext_vector_type(4))) float;

__device__ __forceinline__ float gelu_f(float x) {
  return 0.5f * x * (1.0f + erff(x * 0.7071067811865476f));
}

// split fp32 -> (hi, lo) bf16 with RNE; x ~= hi + lo to ~17 mantissa bits
__device__ __forceinline__ void bf16_split(float x, unsigned short& h, unsigned short& l) {
  unsigned int u = __float_as_uint(x);
  unsigned short hs = (unsigned short)((u + 0x7FFFu + ((u >> 16) & 1u)) >> 16);
  float hf = __uint_as_float(((unsigned int)hs) << 16);
  float r = x - hf;
  unsigned int u2 = __float_as_uint(r);
  unsigned short ls = (unsigned short)((u2 + 0x7FFFu + ((u2 >> 16) & 1u)) >> 16);
  h = hs; l = ls;
}

#define FMA16(a, b, acc)                                                        \
  acc[0][0] += a.x * b.x; acc[0][1] += a.x * b.y; acc[0][2] += a.x * b.z; acc[0][3] += a.x * b.w; \
  acc[1][0] += a.y * b.x; acc[1][1] += a.y * b.y; acc[1][2] += a.y * b.z; acc[1][3] += a.y * b.w; \
  acc[2][0] += a.z * b.x; acc[2][1] += a.z * b.y; acc[2][2] += a.z * b.z; acc[2][3] += a.z * b.w; \
  acc[3][0] += a.w * b.x; acc[3][1] += a.w * b.y; acc[3][2] += a.w * b.z; acc[3][3] += a.w * b.w;

// ---------------- sentinel (ws too small) ----------------
__global__ void k_sentinel(float* out) { out[0] = 1.0e9f; }

// ---------------- fp32 -> bf16 hi/lo planes ----------------
__global__ __launch_bounds__(256) void k_cvt(
    const float* __restrict__ in, unsigned short* __restrict__ hi,
    unsigned short* __restrict__ lo, int n4)
{
  int i = blockIdx.x * 256 + threadIdx.x;
  if (i >= n4) return;
  float4 v = ((const float4*)in)[i];
  ushort4 h, l;
  bf16_split(v.x, h.x, l.x);
  bf16_split(v.y, h.y, l.y);
  bf16_split(v.z, h.z, l.z);
  bf16_split(v.w, h.w, l.w);
  ((ushort4*)hi)[i] = h;
  ((ushort4*)lo)[i] = l;
}

// ---------------- embedding + (faithful) RoPE ----------------
__global__ __launch_bounds__(256) void k_embed_rope(
    const int* __restrict__ hist, const float* __restrict__ emb, float* __restrict__ X)
{
  int t = blockIdx.x;
  int s = t % 200;
  int d = threadIdx.x;
  const float* row = emb + (size_t)hist[t] * 256;
  float x0 = row[d];
  float x1 = row[(d + 1) & 255];
  int fi = d & 127;
  float inv = expf(-9.210340371976184f * ((float)fi * (1.0f / 128.0f)));
  float ang = (float)s * inv;
  X[(size_t)t * 256 + d] = x0 * cosf(ang) + x1 * sinf(ang);
}

// ---------------- item embedding sum ----------------
__global__ __launch_bounds__(256) void k_item_embed(
    const int* __restrict__ cand, const int* __restrict__ catid,
    const float* __restrict__ item_emb, const float* __restrict__ cat_emb,
    float* __restrict__ IE)
{
  int t = blockIdx.x, d = threadIdx.x;
  IE[(size_t)t * 256 + d] =
      item_emb[(size_t)cand[t] * 256 + d] + cat_emb[(size_t)catid[t] * 256 + d];
}

// ---------------- fp32 GEMM (kept for tiny T_I matmuls) ----------------
__global__ __launch_bounds__(256) void k_gemm(
    const float* __restrict__ A, const float* __restrict__ Wm,
    const float* __restrict__ bias, float* __restrict__ C,
    int M, int N, int K, int act)
{
  __shared__ float As[16][68];
  __shared__ float Ws[16][68];
  int tid = threadIdx.x;
  int row0 = blockIdx.y << 6;
  int col0 = blockIdx.x << 6;
  int lr = tid >> 2, lk = (tid & 3) << 2;
  int tx = tid & 15, ty = tid >> 4;
  const float* Aload = A + (size_t)(row0 + lr) * K + lk;
  const float* Wload = Wm + (size_t)(col0 + lr) * K + lk;
  float acc[4][4] = {};
  for (int k0 = 0; k0 < K; k0 += 16) {
    float4 av = *(const float4*)(Aload + k0);
    float4 wv = *(const float4*)(Wload + k0);
    As[lk][lr] = av.x; As[lk + 1][lr] = av.y; As[lk + 2][lr] = av.z; As[lk + 3][lr] = av.w;
    Ws[lk][lr] = wv.x; Ws[lk + 1][lr] = wv.y; Ws[lk + 2][lr] = wv.z; Ws[lk + 3][lr] = wv.w;
    __syncthreads();
#pragma unroll
    for (int k = 0; k < 16; ++k) {
      float4 a = *(const float4*)&As[k][ty << 2];
      float4 b = *(const float4*)&Ws[k][tx << 2];
      FMA16(a, b, acc);
    }
    __syncthreads();
  }
#pragma unroll
  for (int i = 0; i < 4; ++i) {
    int r = row0 + (ty << 2) + i;
    int c0 = col0 + (tx << 2);
    float4 v;
    v.x = acc[i][0]; v.y = acc[i][1]; v.z = acc[i][2]; v.w = acc[i][3];
    if (bias) { v.x += bias[c0]; v.y += bias[c0 + 1]; v.z += bias[c0 + 2]; v.w += bias[c0 + 3]; }
    if (act) { v.x = gelu_f(v.x); v.y = gelu_f(v.y); v.z = gelu_f(v.z); v.w = gelu_f(v.w); }
    *(float4*)(C + (size_t)r * N + c0) = v;
  }
}

// ---------------- MFMA GEMM, split-bf16 (3-product), 128x128 tile ----------------
// C[M,N] = act(A[M,K] @ W[N,K]^T + bias).  A,W planar bf16 hi/lo. tok: optional
// row gather. offs/E: optional MoE expert select. Output fp32 or split bf16.
// NOTE: output must NOT alias A when gridDim.x > 1 (cross-block RW race).
__global__ __launch_bounds__(256, 2) void k_mfmm(
    const unsigned short* __restrict__ Ahi, const unsigned short* __restrict__ Alo,
    const int* __restrict__ tok, const int* __restrict__ offs, int E,
    const unsigned short* __restrict__ Whi, const unsigned short* __restrict__ Wlo,
    const float* __restrict__ bias,
    float* __restrict__ OutF, unsigned short* __restrict__ OutHi,
    unsigned short* __restrict__ OutLo,
    int N, int K, int ldOut, int act)
{
  int row0 = blockIdx.y << 7;
  const float* bp = bias;
  const unsigned short* Wh = Whi;
  const unsigned short* Wl = Wlo;
  if (offs) {
    if (row0 >= offs[E]) return;
    int e = E - 1;
    while (e > 0 && offs[e] > row0) --e;
    Wh += (size_t)e * N * K;
    Wl += (size_t)e * N * K;
    bp += (size_t)e * N;
  }
  int col0 = blockIdx.x << 7;
  __shared__ unsigned short sAh[128 * 40];
  __shared__ unsigned short sAl[128 * 40];
  __shared__ unsigned short sWh[128 * 40];
  __shared__ unsigned short sWl[128 * 40];
  int tid = threadIdx.x;
  int R = tid >> 2, kc = tid & 3;      // staging: rows R and R+64, 8-bf16 chunk kc
  const unsigned short *pA0h, *pA0l, *pA1h, *pA1l;
  bool z0 = false, z1 = false;
  if (tok) {
    int t0 = tok[row0 + R];
    int t1 = tok[row0 + R + 64];
    if (t0 < 0) { z0 = true; pA0h = pA0l = Ahi; }
    else { pA0h = Ahi + (size_t)t0 * K; pA0l = Alo + (size_t)t0 * K; }
    if (t1 < 0) { z1 = true; pA1h = pA1l = Ahi; }
    else { pA1h = Ahi + (size_t)t1 * K; pA1l = Alo + (size_t)t1 * K; }
  } else {
    pA0h = Ahi + (size_t)(row0 + R) * K;      pA0l = Alo + (size_t)(row0 + R) * K;
    pA1h = Ahi + (size_t)(row0 + R + 64) * K; pA1l = Alo + (size_t)(row0 + R + 64) * K;
  }
  const unsigned short* pW0h = Wh + (size_t)(col0 + R) * K;
  const unsigned short* pW0l = Wl + (size_t)(col0 + R) * K;
  const unsigned short* pW1h = Wh + (size_t)(col0 + R + 64) * K;
  const unsigned short* pW1l = Wl + (size_t)(col0 + R + 64) * K;

  int wv = tid >> 6, lane = tid & 63;
  int wr = (wv & 1) << 6, wc = (wv >> 1) << 6;
  int fr = lane & 15, kg = (lane >> 4) << 3;   // frag row/col, k offset

  f32x4 acc[4][4] = {};
  const uint4 zero4 = make_uint4(0u, 0u, 0u, 0u);
  for (int k0 = 0; k0 < K; k0 += 32) {
    int go = k0 + kc * 8;
    uint4 a0h = z0 ? zero4 : *(const uint4*)(pA0h + go);
    uint4 a0l = z0 ? zero4 : *(const uint4*)(pA0l + go);
    uint4 a1h = z1 ? zero4 : *(const uint4*)(pA1h + go);
    uint4 a1l = z1 ? zero4 : *(const uint4*)(pA1l + go);
    uint4 w0h = *(const uint4*)(pW0h + go);
    uint4 w0l = *(const uint4*)(pW0l + go);
    uint4 w1h = *(const uint4*)(pW1h + go);
    uint4 w1l = *(const uint4*)(pW1l + go);
    __syncthreads();
    int so = R * 40 + kc * 8;
    *(uint4*)(sAh + so) = a0h;          *(uint4*)(sAl + so) = a0l;
    *(uint4*)(sAh + so + 64 * 40) = a1h; *(uint4*)(sAl + so + 64 * 40) = a1l;
    *(uint4*)(sWh + so) = w0h;          *(uint4*)(sWl + so) = w0l;
    *(uint4*)(sWh + so + 64 * 40) = w1h; *(uint4*)(sWl + so + 64 * 40) = w1l;
    __syncthreads();
    short8 ah[4], al[4], bh[4], bl[4];
#pragma unroll
    for (int mi = 0; mi < 4; ++mi) {
      int a = (wr + mi * 16 + fr) * 40 + kg;
      ah[mi] = *(const short8*)(sAh + a);
      al[mi] = *(const short8*)(sAl + a);
    }
#pragma unroll
    for (int ni = 0; ni < 4; ++ni) {
      int a = (wc + ni * 16 + fr) * 40 + kg;
      bh[ni] = *(const short8*)(sWh + a);
      bl[ni] = *(const short8*)(sWl + a);
    }
#pragma unroll
    for (int mi = 0; mi < 4; ++mi) {
#pragma unroll
      for (int ni = 0; ni < 4; ++ni) {
        acc[mi][ni] = __builtin_amdgcn_mfma_f32_16x16x32_bf16(ah[mi], bh[ni], acc[mi][ni], 0, 0, 0);
        acc[mi][ni] = __builtin_amdgcn_mfma_f32_16x16x32_bf16(ah[mi], bl[ni], acc[mi][ni], 0, 0, 0);
        acc[mi][ni] = __builtin_amdgcn_mfma_f32_16x16x32_bf16(al[mi], bh[ni], acc[mi][ni], 0, 0, 0);
      }
    }
  }
  // epilogue: C/D layout col=lane&15, row=(lane>>4)*4+reg
  int fr4 = (lane >> 4) << 2;
#pragma unroll
  for (int ni = 0; ni < 4; ++ni) {
    int gcol = col0 + wc + ni * 16 + fr;
    float bv = bp[gcol];
#pragma unroll
    for (int mi = 0; mi < 4; ++mi) {
#pragma unroll
      for (int r = 0; r < 4; ++r) {
        float v = acc[mi][ni][r] + bv;
        if (act) v = gelu_f(v);
        size_t grow = (size_t)(row0 + wr + mi * 16 + fr4 + r);
        if (OutF) {
          OutF[grow * ldOut + gcol] = v;
        } else {
          unsigned short h, l;
          bf16_split(v, h, l);
          OutHi[grow * ldOut + gcol] = h;
          OutLo[grow * ldOut + gcol] = l;
        }
      }
    }
  }
}

// ---------------- MFMA GEMM variant: 64 rows x 256 cols per block ----------------
// Single col-block per row-block -> sole reader AND writer of its A/out rows.
// Safe for the in-place H->Y aliasing in MoE gemm2. A dense (no tok), planar
// hi/lo with ld K. Out fp32 ld 256, no act.
__global__ __launch_bounds__(256, 2) void k_mfmm_y(
    const unsigned short* __restrict__ Ahi, const unsigned short* __restrict__ Alo,
    const int* __restrict__ offs, int E,
    const unsigned short* __restrict__ Whi, const unsigned short* __restrict__ Wlo,
    const float* __restrict__ bias, float* __restrict__ OutF, int K)
{
  const int N = 256;
  int row0 = blockIdx.y << 6;
  if (row0 >= offs[E]) return;
  int e = E - 1;
  while (e > 0 && offs[e] > row0) --e;
  const unsigned short* Wh = Whi + (size_t)e * N * K;
  const unsigned short* Wl = Wlo + (size_t)e * N * K;
  const float* bp = bias + (size_t)e * N;
  __shared__ unsigned short sAh[64 * 40];
  __shared__ unsigned short sAl[64 * 40];
  __shared__ unsigned short sWh[256 * 40];
  __shared__ unsigned short sWl[256 * 40];
  int tid = threadIdx.x;
  int R = tid >> 2, kc = tid & 3;
  const unsigned short* pAh = Ahi + (size_t)(row0 + R) * K;
  const unsigned short* pAl = Alo + (size_t)(row0 + R) * K;
  const unsigned short* pWh = Wh + (size_t)R * K;
  const unsigned short* pWl = Wl + (size_t)R * K;

  int wv = tid >> 6, lane = tid & 63;
  int wc = wv << 6;                       // wave covers cols [wc, wc+64)
  int fr = lane & 15, kg = (lane >> 4) << 3;

  f32x4 acc[4][4] = {};
  for (int k0 = 0; k0 < K; k0 += 32) {
    int go = k0 + kc * 8;
    uint4 a0h = *(const uint4*)(pAh + go);
    uint4 a0l = *(const uint4*)(pAl + go);
    uint4 w0h = *(const uint4*)(pWh + go);
    uint4 w0l = *(const uint4*)(pWl + go);
    uint4 w1h = *(const uint4*)(pWh + (size_t)64 * K + go);
    uint4 w1l = *(const uint4*)(pWl + (size_t)64 * K + go);
    uint4 w2h = *(const uint4*)(pWh + (size_t)128 * K + go);
    uint4 w2l = *(const uint4*)(pWl + (size_t)128 * K + go);
    uint4 w3h = *(const uint4*)(pWh + (size_t)192 * K + go);
    uint4 w3l = *(const uint4*)(pWl + (size_t)192 * K + go);
    __syncthreads();
    int so = R * 40 + kc * 8;
    *(uint4*)(sAh + so) = a0h;            *(uint4*)(sAl + so) = a0l;
    *(uint4*)(sWh + so) = w0h;            *(uint4*)(sWl + so) = w0l;
    *(uint4*)(sWh + so + 64 * 40) = w1h;  *(uint4*)(sWl + so + 64 * 40) = w1l;
    *(uint4*)(sWh + so + 128 * 40) = w2h; *(uint4*)(sWl + so + 128 * 40) = w2l;
    *(uint4*)(sWh + so + 192 * 40) = w3h; *(uint4*)(sWl + so + 192 * 40) = w3l;
    __syncthreads();
    short8 ah[4], al[4], bh[4], bl[4];
#pragma unroll
    for (int mi = 0; mi < 4; ++mi) {
      int a = (mi * 16 + fr) * 40 + kg;
      ah[mi] = *(const short8*)(sAh + a);
      al[mi] = *(const short8*)(sAl + a);
    }
#pragma unroll
    for (int ni = 0; ni < 4; ++ni) {
      int a = (wc + ni * 16 + fr) * 40 + kg;
      bh[ni] = *(const short8*)(sWh + a);
      bl[ni] = *(const short8*)(sWl + a);
    }
#pragma unroll
    for (int mi = 0; mi < 4; ++mi) {
#pragma unroll
      for (int ni = 0; ni < 4; ++ni) {
        acc[mi][ni] = __builtin_amdgcn_mfma_f32_16x16x32_bf16(ah[mi], bh[ni], acc[mi][ni], 0, 0, 0);
        acc[mi][ni] = __builtin_amdgcn_mfma_f32_16x16x32_bf16(ah[mi], bl[ni], acc[mi][ni], 0, 0, 0);
        acc[mi][ni] = __builtin_amdgcn_mfma_f32_16x16x32_bf16(al[mi], bh[ni], acc[mi][ni], 0, 0, 0);
      }
    }
  }
  int fr4 = (lane >> 4) << 2;
#pragma unroll
  for (int ni = 0; ni < 4; ++ni) {
    int gcol = wc + ni * 16 + fr;
    float bv = bp[gcol];
#pragma unroll
    for (int mi = 0; mi < 4; ++mi) {
#pragma unroll
      for (int r = 0; r < 4; ++r) {
        size_t grow = (size_t)(row0 + mi * 16 + fr4 + r);
        OutF[grow * 256 + gcol] = acc[mi][ni][r] + bv;
      }
    }
  }
}

// ---------------- self-attention: phased q-tiles ----------------
__global__ __launch_bounds__(256) void k_attn(const float* __restrict__ qkv, float* __restrict__ ao)
{
  __shared__ float4 Ks[200 * 9];
  __shared__ float4 Vs[200 * 9];
  __shared__ float4 Qs[16 * 9];
  __shared__ float  Sc[16 * 200];
  __shared__ float  red[16 * 16];
  __shared__ float  mq_s[16], linv_s[16];
  int bh = blockIdx.x;
  int b = bh >> 3, h = bh & 7;
  const float* base = qkv + (size_t)b * 200 * 768;
  int tid = threadIdx.x;
  for (int i = tid; i < 1600; i += 256) {
    int s = i >> 3, d = i & 7;
    Ks[s * 9 + d] = *(const float4*)(base + s * 768 + 256 + h * 32 + d * 4);
    Vs[s * 9 + d] = *(const float4*)(base + s * 768 + 512 + h * 32 + d * 4);
  }
  const float scale = 0.17677669529663687f;
  int ql = tid >> 4, si = tid & 15;
  int dd = (tid & 15) >> 1, sh = tid & 1;
  for (int tile = 0; tile < 13; ++tile) {
    __syncthreads();
    if (tid < 128) {
      int q = tile * 16 + (tid >> 3), d = tid & 7;
      if (q < 200)
        Qs[(tid >> 3) * 9 + d] = *(const float4*)(base + q * 768 + h * 32 + d * 4);
    }
    __syncthreads();
    int qg = tile * 16 + ql;
    bool qa = qg < 200;
    float4 qr[8];
#pragma unroll
    for (int d = 0; d < 8; ++d) qr[d] = Qs[ql * 9 + d];
    float sc[13];
    float lm = -1e30f;
#pragma unroll
    for (int j = 0; j < 13; ++j) {
      int s = si + 16 * j;
      if (s < 200) {
        float acc = 0.f;
#pragma unroll
        for (int d = 0; d < 8; ++d) {
          float4 kk = Ks[s * 9 + d];
          acc += qr[d].x * kk.x + qr[d].y * kk.y + qr[d].z * kk.z + qr[d].w * kk.w;
        }
        float v = acc * scale;
        sc[j] = v;
        lm = fmaxf(lm, v);
      }
    }
    red[tid] = lm;
    __syncthreads();
    if (tid < 16) {
      float m = red[tid * 16];
#pragma unroll
      for (int k = 1; k < 16; ++k) m = fmaxf(m, red[tid * 16 + k]);
      mq_s[tid] = m;
    }
    __syncthreads();
    float mq = mq_s[ql];
    float ls = 0.f;
#pragma unroll
    for (int j = 0; j < 13; ++j) {
      int s = si + 16 * j;
      if (s < 200) {
        float e = expf(sc[j] - mq);
        Sc[ql * 200 + s] = e;
        ls += e;
      }
    }
    red[tid] = ls;
    __syncthreads();
    if (tid < 16) {
      float s = 0.f;
#pragma unroll
      for (int k = 0; k < 16; ++k) s += red[tid * 16 + k];
      linv_s[tid] = 1.f / s;
    }
    __syncthreads();
    {
      const float* prow = &Sc[ql * 200];
      float4 o = make_float4(0.f, 0.f, 0.f, 0.f);
      int s0 = sh * 100;
#pragma unroll 4
      for (int s = s0; s < s0 + 100; ++s) {
        float p = prow[s];
        float4 vv = Vs[s * 9 + dd];
        o.x += p * vv.x; o.y += p * vv.y; o.z += p * vv.z; o.w += p * vv.w;
      }
      o.x += __shfl_xor(o.x, 1, 64);
      o.y += __shfl_xor(o.y, 1, 64);
      o.z += __shfl_xor(o.z, 1, 64);
      o.w += __shfl_xor(o.w, 1, 64);
      if (sh == 0 && qa) {
        float inv = linv_s[ql];
        float4 v;
        v.x = o.x * inv; v.y = o.y * inv; v.z = o.z * inv; v.w = o.w * inv;
        *(float4*)(ao + (size_t)(b * 200 + qg) * 256 + h * 32 + dd * 4) = v;
      }
    }
  }
}

// ---------------- cross-attention ----------------
__global__ __launch_bounds__(256) void k_xattn(
    const float* __restrict__ Q, const float* __restrict__ Kb,
    const float* __restrict__ Vb, float* __restrict__ O)
{
  __shared__ float4 Ks[200 * 9];
  __shared__ float4 Vs[200 * 9];
  __shared__ float4 Qs[16 * 9];
  __shared__ float  Sc[16 * 209];
  __shared__ float  red[16 * 16];
  __shared__ float  mq_s[16], linv_s[16];
  int bh = blockIdx.x;
  int b = bh >> 3, h = bh & 7;
  int tid = threadIdx.x;
  for (int i = tid; i < 1600; i += 256) {
    int s = i >> 3, d = i & 7;
    Ks[s * 9 + d] = *(const float4*)(Kb + (size_t)(b * 200 + s) * 256 + h * 32 + d * 4);
    Vs[s * 9 + d] = *(const float4*)(Vb + (size_t)(b * 200 + s) * 256 + h * 32 + d * 4);
  }
  if (tid < 128) {
    int q = tid >> 3, d = tid & 7;
    Qs[q * 9 + d] = *(const float4*)(Q + (size_t)(b * 16 + q) * 256 + h * 32 + d * 4);
  }
  __syncthreads();
  const float scale = 0.17677669529663687f;
  int q = tid >> 4, si = tid & 15;
  float4 qr[8];
#pragma unroll
  for (int d = 0; d < 8; ++d) qr[d] = Qs[q * 9 + d];
  float sc[13];
  float lm = -1e30f;
#pragma unroll
  for (int j = 0; j < 13; ++j) {
    int s = si + 16 * j;
    if (s < 200) {
      float acc = 0.f;
#pragma unroll
      for (int d = 0; d < 8; ++d) {
        float4 kk = Ks[s * 9 + d];
        acc += qr[d].x * kk.x + qr[d].y * kk.y + qr[d].z * kk.z + qr[d].w * kk.w;
      }
      float v = acc * scale;
      sc[j] = v;
      lm = fmaxf(lm, v);
    }
  }
  red[q * 16 + si] = lm;
  __syncthreads();
  if (tid < 16) {
    float m = red[tid * 16];
#pragma unroll
    for (int k = 1; k < 16; ++k) m = fmaxf(m, red[tid * 16 + k]);
    mq_s[tid] = m;
  }
  __syncthreads();
  float mq = mq_s[q];
  float ls = 0.f;
#pragma unroll
  for (int j = 0; j < 13; ++j) {
    int s = si + 16 * j;
    if (s < 200) {
      float e = expf(sc[j] - mq);
      Sc[q * 209 + s] = e;
      ls += e;
    }
  }
  red[q * 16 + si] = ls;
  __syncthreads();
  if (tid < 16) {
    float s = 0.f;
#pragma unroll
    for (int k = 0; k < 16; ++k) s += red[tid * 16 + k];
    linv_s[tid] = 1.f / s;
  }
  __syncthreads();
  if (tid < 128) {
    int qq = tid >> 3, dd = tid & 7;
    float4 o = make_float4(0.f, 0.f, 0.f, 0.f);
    const float* prow = &Sc[qq * 209];
    for (int s = 0; s < 200; ++s) {
      float p = prow[s];
      float4 vv = Vs[s * 9 + dd];
      o.x += p * vv.x; o.y += p * vv.y; o.z += p * vv.z; o.w += p * vv.w;
    }
    float inv = linv_s[qq];
    o.x *= inv; o.y *= inv; o.z *= inv; o.w *= inv;
    *(float4*)(O + (size_t)(b * 16 + qq) * 256 + h * 32 + dd * 4) = o;
  }
}

// ---------------- LayerNorm (optional residual) ----------------
__global__ __launch_bounds__(256) void k_ln(
    const float* __restrict__ Xin, const float* __restrict__ R,
    const float* __restrict__ sc, const float* __restrict__ bi, float* __restrict__ Y)
{
  int t = blockIdx.x, d = threadIdx.x;
  size_t idx = (size_t)t * 256 + d;
  float v = Xin[idx];
  if (R) v += R[idx];
  __shared__ float red[8];
  int lane = d & 63, wid = d >> 6;
  float s = v;
#pragma unroll
  for (int off = 32; off > 0; off >>= 1) s += __shfl_xor(s, off, 64);
  if (lane == 0) red[wid] = s;
  __syncthreads();
  float mean = (red[0] + red[1] + red[2] + red[3]) * 0.00390625f;
  float dv = v - mean;
  float s2 = dv * dv;
#pragma unroll
  for (int off = 32; off > 0; off >>= 1) s2 += __shfl_xor(s2, off, 64);
  if (lane == 0) red[4 + wid] = s2;
  __syncthreads();
  float var = (red[4] + red[5] + red[6] + red[7]) * 0.00390625f;
  Y[idx] = dv * (1.0f / sqrtf(var + 1e-5f)) * sc[d] + bi[d];
}

// ---------------- fused MoE-combine + LayerNorm ----------------
__global__ __launch_bounds__(256) void k_ln_comb(
    const float* __restrict__ Xin, const float* __restrict__ Yb, int ldY,
    const int* __restrict__ slotmap, const float* __restrict__ tw,
    const float* __restrict__ sc, const float* __restrict__ bi, float* __restrict__ Y)
{
  int t = blockIdx.x, d = threadIdx.x;
  size_t idx = (size_t)t * 256 + d;
  int s0 = slotmap[2 * t], s1 = slotmap[2 * t + 1];
  float w0 = tw[2 * t], w1 = tw[2 * t + 1];
  float v = w0 * Yb[(size_t)s0 * ldY + d] + w1 * Yb[(size_t)s1 * ldY + d];
  if (Xin) v += Xin[idx];
  __shared__ float red[8];
  int lane = d & 63, wid = d >> 6;
  float s = v;
#pragma unroll
  for (int off = 32; off > 0; off >>= 1) s += __shfl_xor(s, off, 64);
  if (lane == 0) red[wid] = s;
  __syncthreads();
  float mean = (red[0] + red[1] + red[2] + red[3]) * 0.00390625f;
  float dv = v - mean;
  float s2 = dv * dv;
#pragma unroll
  for (int off = 32; off > 0; off >>= 1) s2 += __shfl_xor(s2, off, 64);
  if (lane == 0) red[4 + wid] = s2;
  __syncthreads();
  float var = (red[4] + red[5] + red[6] + red[7]) * 0.00390625f;
  Y[idx] = dv * (1.0f / sqrtf(var + 1e-5f)) * sc[d] + bi[d];
}

// ---------------- router ----------------
template <int E>
__global__ __launch_bounds__(256) void k_router(
    const float* __restrict__ X, int T,
    const float* __restrict__ gw, const float* __restrict__ gb,
    float* __restrict__ probs, int* __restrict__ ti, float* __restrict__ tw)
{
  int lane = threadIdx.x & 63, wid = threadIdx.x >> 6;
  int t = blockIdx.x * 4 + wid;
  if (t >= T) return;
  float4 x4 = *(const float4*)(X + (size_t)t * 256 + lane * 4);
  float p[E];
#pragma unroll
  for (int e = 0; e < E; ++e) {
    float4 g = *(const float4*)(gw + (size_t)e * 256 + lane * 4);
    float s = x4.x * g.x + x4.y * g.y + x4.z * g.z + x4.w * g.w;
#pragma unroll
    for (int off = 32; off > 0; off >>= 1) s += __shfl_xor(s, off, 64);
    p[e] = s + gb[e];
  }
  float m = p[0];
#pragma unroll
  for (int e = 1; e < E; ++e) m = fmaxf(m, p[e]);
  float sum = 0.f;
#pragma unroll
  for (int e = 0; e < E; ++e) { p[e] = expf(p[e] - m); sum += p[e]; }
  float inv = 1.f / sum;
#pragma unroll
  for (int e = 0; e < E; ++e) p[e] *= inv;
  if (lane < E) probs[(size_t)t * E + lane] = p[lane];
  if (lane == 0) {
    float v1 = p[0]; int i1 = 0;
#pragma unroll
    for (int e = 1; e < E; ++e) if (p[e] > v1) { v1 = p[e]; i1 = e; }
    float v2 = -1.f; int i2 = 0;
#pragma unroll
    for (int e = 0; e < E; ++e) if (e != i1 && p[e] > v2) { v2 = p[e]; i2 = e; }
    float s2 = v1 + v2;
    ti[t * 2] = i1; ti[t * 2 + 1] = i2;
    tw[t * 2] = v1 / s2; tw[t * 2 + 1] = v2 / s2;
  }
}

// ---------------- count + 128-aligned scan + padding init ----------------
template <int E>
__global__ __launch_bounds__(256) void k_count_scan(
    const int* __restrict__ ti, int T,
    int* __restrict__ offs, int* __restrict__ cnt2, int* __restrict__ tok)
{
  __shared__ int sc[8];
  __shared__ int soffs[9];
  __shared__ int scnt[8];
  int tid = threadIdx.x;
  if (tid < 8) { sc[tid] = 0; cnt2[tid] = 0; }
  __syncthreads();
  int c[E];
#pragma unroll
  for (int k = 0; k < E; ++k) c[k] = 0;
  for (int i = tid; i < 2 * T; i += 256) {
    int e = ti[i];
#pragma unroll
    for (int k = 0; k < E; ++k) c[k] += (e == k) ? 1 : 0;
  }
#pragma unroll
  for (int k = 0; k < E; ++k) {
    int v = c[k];
#pragma unroll
    for (int off = 32; off > 0; off >>= 1) v += __shfl_xor(v, off, 64);
    if ((tid & 63) == 0) atomicAdd(&sc[k], v);
  }
  __syncthreads();
  if (tid == 0) {
    int o = 0;
    for (int e = 0; e < E; ++e) {
      soffs[e] = o; scnt[e] = sc[e];
      o += (sc[e] + 127) & ~127;          // 128-aligned for MFMA tiles
    }
    soffs[E] = o;
  }
  __syncthreads();
  if (tid <= E) offs[tid] = soffs[tid];
  for (int e = 0; e < E; ++e) {
    int s0 = soffs[e] + scnt[e], s1 = soffs[e + 1];
    for (int i = s0 + tid; i < s1; i += 256) tok[i] = -1;
  }
}

// ---------------- fill expert slot lists + token->slot map ----------------
__global__ __launch_bounds__(256) void k_fill(
    const int* __restrict__ ti, int T,
    const int* __restrict__ offs, int* __restrict__ cnt2,
    int* __restrict__ tok, int* __restrict__ slotmap)
{
  __shared__ int lcnt[8];
  __shared__ int lbase[8];
  int tid = threadIdx.x;
  if (tid < 8) lcnt[tid] = 0;
  __syncthreads();
  int t = blockIdx.x * 256 + tid;
  int e0 = 0, e1 = 0, p0 = 0, p1 = 0;
  bool act = (t < T);
  if (act) {
    e0 = ti[t * 2]; e1 = ti[t * 2 + 1];
    p0 = atomicAdd(&lcnt[e0], 1);
    p1 = atomicAdd(&lcnt[e1], 1);
  }
  __syncthreads();
  if (tid < 8) lbase[tid] = atomicAdd(&cnt2[tid], lcnt[tid]);
  __syncthreads();
  if (act) {
    int s0 = offs[e0] + lbase[e0] + p0;
    tok[s0] = t; slotmap[t * 2] = s0;
    int s1 = offs[e1] + lbase[e1] + p1;
    tok[s1] = t; slotmap[t * 2 + 1] = s1;
  }
}

// ---------------- concat [taw | item] ----------------
__global__ __launch_bounds__(256) void k_concat(
    const float* __restrict__ A, const float* __restrict__ B, float* __restrict__ O, int total)
{
  int i = blockIdx.x * 256 + threadIdx.x;
  if (i >= total) return;
  int t = i >> 9, c = i & 511;
  O[i] = (c < 256) ? A[(size_t)t * 256 + c] : B[(size_t)t * 256 + c - 256];
}

// ---------------- final logits ----------------
__global__ __launch_bounds__(256) void k_final(
    const float* __restrict__ FH, const float* __restrict__ w2,
    const float* __restrict__ b2, float* __restrict__ out, int T)
{
  int lane = threadIdx.x & 63, wid = threadIdx.x >> 6;
  int t = blockIdx.x * 4 + wid;
  if (t >= T) return;
  float4 h = *(const float4*)(FH + (size_t)t * 256 + lane * 4);
  float4 w = *(const float4*)(w2 + lane * 4);
  float s = h.x * w.x + h.y * w.y + h.z * w.z + h.w * w.w;
#pragma unroll
  for (int off = 32; off > 0; off >>= 1) s += __shfl_xor(s, off, 64);
  if (lane == 0) out[t] = s + b2[0];
}

// ---------------- aux load-balance loss ----------------
__global__ __launch_bounds__(256) void k_aux(
    const float* __restrict__ p0, const float* __restrict__ p1,
    const float* __restrict__ pi, float* __restrict__ out_aux)
{
  __shared__ float red[256];
  int tid = threadIdx.x;
  float aux = 0.f;
  for (int r = 0; r < 2; ++r) {
    const float* P = (r == 0) ? p0 : p1;
    float loc[4] = {0.f, 0.f, 0.f, 0.f};
    for (int t = tid; t < T_U; t += 256) {
#pragma unroll
      for (int e = 0; e < 4; ++e) loc[e] += P[t * 4 + e];
    }
    float contrib = 0.f;
    for (int e = 0; e < 4; ++e) {
      red[tid] = loc[e];
      __syncthreads();
      for (int s = 128; s > 0; s >>= 1) { if (tid < s) red[tid] += red[tid + s]; __syncthreads(); }
      if (tid == 0) { float d = red[0] * (1.f / T_U) - 0.125f; contrib += d * d; }
      __syncthreads();
    }
    if (tid == 0) aux += contrib * 0.25f;
  }
  {
    float loc[8] = {};
    for (int t = tid; t < T_I; t += 256) {
#pragma unroll
      for (int e = 0; e < 8; ++e) loc[e] += pi[t * 8 + e];
    }
    float contrib = 0.f;
    for (int e = 0; e < 8; ++e) {
      red[tid] = loc[e];
      __syncthreads();
      for (int s = 128; s > 0; s >>= 1) { if (tid < s) red[tid] += red[tid + s]; __syncthreads(); }
      if (tid == 0) { float d = red[0] * (1.f / T_I) - 0.125f; contrib += d * d; }
      __syncthreads();
    }
    if (tid == 0) aux += contrib * 0.125f;
  }
  if (tid == 0) *out_aux = aux;
}

// =======================================================================
extern "C" void kernel_launch(void* const* d_in, const int* in_sizes, int n_in,
                              void* d_out, int out_size, void* d_ws, size_t ws_size,
                              hipStream_t stream)
{
  (void)in_sizes; (void)n_in; (void)out_size;
  const int*   history  = (const int*)d_in[0];
  const int*   cand     = (const int*)d_in[1];
  const int*   catid    = (const int*)d_in[2];
  const float* item_emb = (const float*)d_in[3];
  const float* cat_emb  = (const float*)d_in[4];
  const float* ub_in_w  = (const float*)d_in[5];
  const float* ub_in_b  = (const float*)d_in[6];
  const float* ub_out_w = (const float*)d_in[7];
  const float* ub_out_b = (const float*)d_in[8];
  const float* ub_n1_s  = (const float*)d_in[9];
  const float* ub_n1_b  = (const float*)d_in[10];
  const float* ub_n2_s  = (const float*)d_in[11];
  const float* ub_n2_b  = (const float*)d_in[12];
  const float* ub_gate_w= (const float*)d_in[13];
  const float* ub_gate_b= (const float*)d_in[14];
  const float* ub_e_w1  = (const float*)d_in[15];
  const float* ub_e_b1  = (const float*)d_in[16];
  const float* ub_e_w2  = (const float*)d_in[17];
  const float* ub_e_b2  = (const float*)d_in[18];
  const float* un_s     = (const float*)d_in[19];
  const float* un_b     = (const float*)d_in[20];
  const float* im_gate_w= (const float*)d_in[21];
  const float* im_gate_b= (const float*)d_in[22];
  const float* im_e_w1  = (const float*)d_in[23];
  const float* im_e_b1  = (const float*)d_in[24];
  const float* im_e_w2  = (const float*)d_in[25];
  const float* im_e_b2  = (const float*)d_in[26];
  const float* in_s     = (const float*)d_in[27];
  const float* in_b     = (const float*)d_in[28];
  const float* ca_in_w  = (const float*)d_in[29];
  const float* ca_in_b  = (const float*)d_in[30];
  const float* ca_out_w = (const float*)d_in[31];
  const float* ca_out_b = (const float*)d_in[32];
  const float* fm_w1    = (const float*)d_in[33];
  const float* fm_b1    = (const float*)d_in[34];
  const float* fm_w2    = (const float*)d_in[35];
  const float* fm_b2    = (const float*)d_in[36];
  float* out = (float*)d_out;

  float* W = (float*)d_ws;
  size_t o = 0;
  auto alloc = [&](size_t n) { size_t r = o; o += (n + 63) & ~(size_t)63; return r; };
  const size_t oX    = alloc((size_t)T_U * 256);
  const size_t oQKV  = alloc((size_t)T_U * 768);   // region A (reuse: H planes / Kbuf,Vbuf)
  const size_t oAO   = alloc((size_t)T_U * 256);   // region B (H spillover)
  const size_t oEXT  = alloc(300000);              // region C (H tail)
  const size_t oTMP  = alloc((size_t)T_U * 256);
  const size_t oP0   = alloc((size_t)T_U * 4);
  const size_t oP1   = alloc((size_t)T_U * 4);
  const size_t oPI   = alloc((size_t)T_I * 8);
  const size_t oTW   = alloc((size_t)T_U * 2);
  const size_t oSM   = alloc((size_t)T_U * 2);     // int slotmap
  const size_t oTI   = alloc((size_t)T_U * 2);     // int
  const size_t oTOK  = alloc(CAP_U);               // int
  const size_t oCNT  = alloc(64);                  // int cnt2[8]|offs[9]
  const size_t oIE   = alloc((size_t)T_I * 256);
  const size_t oITEM = alloc((size_t)T_I * 256);
  const size_t oQB   = alloc((size_t)T_I * 256);
  const size_t oOB   = alloc((size_t)T_I * 256);
  const size_t oTAW  = alloc((size_t)T_I * 256);
  const size_t oFUS  = alloc((size_t)T_I * 512);
  const size_t oFH   = alloc((size_t)T_I * 256);
  const size_t oWB   = alloc(4915200);             // bf16 weight arena: 2 planes x 4,915,200 shorts
  const size_t oCVT  = alloc((size_t)T_U * 256);   // activation hi/lo planes
  (void)oEXT;
  if (ws_size < o * sizeof(float)) {
    k_sentinel<<<1, 1, 0, stream>>>(out);
    return;
  }

  float* X    = W + oX;
  float* QKV  = W + oQKV;
  float* AO   = W + oAO;
  float* TMP  = W + oTMP;
  float* P0   = W + oP0;
  float* P1   = W + oP1;
  float* PI   = W + oPI;
  float* TWb  = W + oTW;
  int*   SLOT = (int*)(W + oSM);
  int*   TIb  = (int*)(W + oTI);
  int*   TOKb = (int*)(W + oTOK);
  int*   CNT  = (int*)(W + oCNT);
  int*   CNT2 = CNT;
  int*   OFFS = CNT + 8;
  float* IE   = W + oIE;
  float* ITEM = W + oITEM;
  float* QB   = W + oQB;
  float* OB   = W + oOB;
  float* TAW  = W + oTAW;
  float* FUS  = W + oFUS;
  float* FH   = W + oFH;
  float* Kbuf = QKV;
  float* Vbuf = QKV + (size_t)T_U * 256;

  // bf16 weight arena (per-plane short offsets)
  unsigned short* WH = (unsigned short*)(W + oWB);
  unsigned short* WL = WH + 4915200;
  const size_t off_in = 0, off_out = 393216, off_ew1 = 524288, off_ew2 = 1572864,
               off_iw1 = 2621440, off_iw2 = 3670016, off_ca = 4718592;
  // activation cvt planes
  unsigned short* CVH = (unsigned short*)(W + oCVT);
  unsigned short* CVL = CVH + (size_t)T_U * 256;
  // H planes (user MoE) alias region A+B+C; Y fp32 aliases the Hlo plane.
  // Safe ONLY with k_mfmm_y (one block owns its rows end-to-end).
  unsigned short* Hhi = (unsigned short*)(W + oQKV);
  unsigned short* Hlo = Hhi + (size_t)CAP_U * 512;
  float* Yu = (float*)Hlo;                          // CAP_U x 256 fp32
  unsigned short* iHhi = (unsigned short*)(W + oQKV);
  unsigned short* iHlo = iHhi + (size_t)CAP_I * 512;
  float* Yi = (float*)iHlo;                         // CAP_I x 256 fp32

  // 0) weight conversions (every call; ~20 MB traffic)
  k_cvt<<<384, 256, 0, stream>>>(ub_in_w,  WH + off_in,  WL + off_in,  393216 / 4);
  k_cvt<<<128, 256, 0, stream>>>(ub_out_w, WH + off_out, WL + off_out, 131072 / 4);
  k_cvt<<<1024, 256, 0, stream>>>(ub_e_w1, WH + off_ew1, WL + off_ew1, 1048576 / 4);
  k_cvt<<<1024, 256, 0, stream>>>(ub_e_w2, WH + off_ew2, WL + off_ew2, 1048576 / 4);
  k_cvt<<<1024, 256, 0, stream>>>(im_e_w1, WH + off_iw1, WL + off_iw1, 1048576 / 4);
  k_cvt<<<1024, 256, 0, stream>>>(im_e_w2, WH + off_iw2, WL + off_iw2, 1048576 / 4);
  k_cvt<<<192, 256, 0, stream>>>(ca_in_w,  WH + off_ca,  WL + off_ca,  196608 / 4);

  // 1) embedding + rope
  k_embed_rope<<<T_U, 256, 0, stream>>>(history, item_emb, X);

  // 2) user transformer layers
  for (int l = 0; l < 2; ++l) {
    k_cvt<<<3200, 256, 0, stream>>>(X, CVH, CVL, T_U * 256 / 4);
    k_mfmm<<<dim3(6, 100), 256, 0, stream>>>(CVH, CVL, nullptr, nullptr, 0,
        WH + off_in + (size_t)l * 196608, WL + off_in + (size_t)l * 196608,
        ub_in_b + l * 768, QKV, nullptr, nullptr, 768, 256, 768, 0);
    k_attn<<<512, 256, 0, stream>>>(QKV, AO);
    k_cvt<<<3200, 256, 0, stream>>>(AO, CVH, CVL, T_U * 256 / 4);
    k_mfmm<<<dim3(2, 100), 256, 0, stream>>>(CVH, CVL, nullptr, nullptr, 0,
        WH + off_out + (size_t)l * 65536, WL + off_out + (size_t)l * 65536,
        ub_out_b + l * 256, TMP, nullptr, nullptr, 256, 256, 256, 0);
    k_ln<<<T_U, 256, 0, stream>>>(X, TMP, ub_n1_s + l * 256, ub_n1_b + l * 256, X);
    k_router<4><<<T_U / 4, 256, 0, stream>>>(X, T_U, ub_gate_w + (size_t)l * 4 * 256,
        ub_gate_b + l * 4, (l == 0) ? P0 : P1, TIb, TWb);
    k_count_scan<4><<<1, 256, 0, stream>>>(TIb, T_U, OFFS, CNT2, TOKb);
    k_fill<<<T_U / 256, 256, 0, stream>>>(TIb, T_U, OFFS, CNT2, TOKb, SLOT);
    k_cvt<<<3200, 256, 0, stream>>>(X, CVH, CVL, T_U * 256 / 4);
    // H[slot] = gelu(X[tok] @ W1^T + b1) -> split bf16 planes
    k_mfmm<<<dim3(4, CAP_U / 128), 256, 0, stream>>>(CVH, CVL, TOKb, OFFS, 4,
        WH + off_ew1 + (size_t)l * 524288, WL + off_ew1 + (size_t)l * 524288,
        ub_e_b1 + (size_t)l * 2048, nullptr, Hhi, Hlo, 512, 256, 512, 1);
    // Y[slot] = H @ W2^T + b2 (fp32 into Hlo plane) — race-free: 64-row blocks
    // own ALL 256 cols, sole reader+writer of their rows.
    k_mfmm_y<<<dim3(1, CAP_U / 64), 256, 0, stream>>>(Hhi, Hlo, OFFS, 4,
        WH + off_ew2 + (size_t)l * 524288, WL + off_ew2 + (size_t)l * 524288,
        ub_e_b2 + (size_t)l * 1024, Yu, 512);
    k_ln_comb<<<T_U, 256, 0, stream>>>(X, Yu, 256, SLOT, TWb,
        ub_n2_s + l * 256, ub_n2_b + l * 256, X);
  }

  // 3) history final LN
  k_ln<<<T_U, 256, 0, stream>>>(X, nullptr, un_s, un_b, X);

  // 4) item tower
  k_item_embed<<<T_I, 256, 0, stream>>>(cand, catid, item_emb, cat_emb, IE);
  k_router<8><<<T_I / 4, 256, 0, stream>>>(IE, T_I, im_gate_w, im_gate_b, PI, TIb, TWb);
  k_count_scan<8><<<1, 256, 0, stream>>>(TIb, T_I, OFFS, CNT2, TOKb);
  k_fill<<<T_I / 256, 256, 0, stream>>>(TIb, T_I, OFFS, CNT2, TOKb, SLOT);
  k_cvt<<<256, 256, 0, stream>>>(IE, CVH, CVL, T_I * 256 / 4);
  k_mfmm<<<dim3(4, CAP_I / 128), 256, 0, stream>>>(CVH, CVL, TOKb, OFFS, 8,
      WH + off_iw1, WL + off_iw1, im_e_b1, nullptr, iHhi, iHlo, 512, 256, 512, 1);
  k_mfmm_y<<<dim3(1, CAP_I / 64), 256, 0, stream>>>(iHhi, iHlo, OFFS, 8,
      WH + off_iw2, WL + off_iw2, im_e_b2, Yi, 512);
  k_ln_comb<<<T_I, 256, 0, stream>>>(nullptr, Yi, 256, SLOT, TWb, in_s, in_b, ITEM);

  // 5) cross attention
  k_gemm<<<dim3(4, 16), 256, 0, stream>>>(ITEM, ca_in_w, ca_in_b, QB, T_I, 256, 256, 0);
  k_cvt<<<3200, 256, 0, stream>>>(X, CVH, CVL, T_U * 256 / 4);
  k_mfmm<<<dim3(2, 100), 256, 0, stream>>>(CVH, CVL, nullptr, nullptr, 0,
      WH + off_ca + 65536, WL + off_ca + 65536, ca_in_b + 256,
      Kbuf, nullptr, nullptr, 256, 256, 256, 0);
  k_mfmm<<<dim3(2, 100), 256, 0, stream>>>(CVH, CVL, nullptr, nullptr, 0,
      WH + off_ca + 131072, WL + off_ca + 131072, ca_in_b + 512,
      Vbuf, nullptr, nullptr, 256, 256, 256, 0);
  k_xattn<<<512, 256, 0, stream>>>(QB, Kbuf, Vbuf, OB);
  k_gemm<<<dim3(4, 16), 256, 0, stream>>>(OB, ca_out_w, ca_out_b, TAW, T_I, 256, 256, 0);

  // 6) fusion MLP + logits
  k_concat<<<(T_I * 512) / 256, 256, 0, stream>>>(TAW, ITEM, FUS, T_I * 512);
  k_gemm<<<dim3(4, 16), 256, 0, stream>>>(FUS, fm_w1, fm_b1, FH, T_I, 256, 512, 1);
  k_final<<<T_I / 4, 256, 0, stream>>>(FH, fm_w2, fm_b2, out, T_I);

  // 7) aux loss
  k_aux<<<1, 256, 0, stream>>>(P0, P1, PI, out + 1024);
}